// Round 1
// baseline (17925.575 us; speedup 1.0000x reference)
//
#include <hip/hip_runtime.h>
#include <hip/hip_bf16.h>
#include <math.h>

#define B_ 16
#define N_ 128
#define S_ 129
#define HID_ 768
#define H_ 32
#define D_ 24
#define FFN_ 3072
#define L_ 12

// ============================================================
// gab base: gab[b,hh,qi,kj] = 2*ab + spatial(qi>0,kj>0) + t(qi==0||kj==0)
// ============================================================
__global__ __launch_bounds__(256) void gab_base_kernel(
    const float* __restrict__ ab, const int* __restrict__ spos,
    const float* __restrict__ spemb, const float* __restrict__ gtvd,
    float* __restrict__ gab)
{
  int idx = blockIdx.x * 256 + threadIdx.x;
  if (idx >= B_*H_*S_*S_) return;
  int kj = idx % S_;
  int qi = (idx / S_) % S_;
  int hh = (idx / (S_*S_)) % H_;
  int b  = idx / (S_*S_*H_);
  float v = 2.0f * ab[(b*S_ + qi)*S_ + kj];
  if (qi > 0 && kj > 0)
    v += spemb[spos[(b*N_ + (qi-1))*N_ + (kj-1)]*H_ + hh];
  if (qi == 0 || kj == 0) v += gtvd[hh];
  gab[idx] = v;
}

// ============================================================
// edge encoding: gab[b,hh,1+i,1+j] += (1/sp) * sum_d sum_h' m[d][h'] * W[d][h'][hh]
//   m[d][h'] = mean_e edge_emb[edge_input[b,i,j,d,e]][h']
// block = 256 threads: 8 j-cells x 32 hh lanes
// ============================================================
__global__ __launch_bounds__(256) void edge_kernel(
    const int* __restrict__ eidx, const float* __restrict__ eemb,
    const float* __restrict__ edis, const int* __restrict__ spos,
    float* __restrict__ gab)
{
  __shared__ float ml[8][5][32];
  int tid = threadIdx.x;
  int jl = tid / 32, hh = tid % 32;
  int lin = blockIdx.x * 8 + jl;
  int j = lin % N_;
  int i = (lin / N_) % N_;
  int b = lin / (N_*N_);
  const int* er = eidx + ((long)(b*N_ + i)*N_ + j) * 15;
#pragma unroll
  for (int d = 0; d < 5; ++d) {
    float m = (eemb[er[d*3+0]*H_ + hh] + eemb[er[d*3+1]*H_ + hh] +
               eemb[er[d*3+2]*H_ + hh]) * (1.0f/3.0f);
    ml[jl][d][hh] = m;
  }
  __syncthreads();
  float acc = 0.0f;
#pragma unroll
  for (int d = 0; d < 5; ++d)
#pragma unroll
    for (int hp = 0; hp < 32; ++hp)
      acc += ml[jl][d][hp] * edis[d*1024 + hp*32 + hh];
  int sp0 = spos[(b*N_ + i)*N_ + j];
  int sp = (sp0 == 0) ? 1 : sp0;
  if (sp > 1) sp -= 1;
  if (sp > 5) sp = 5;
  long gidx = ((long)(b*H_ + hh)*S_ + (i+1))*S_ + (j+1);
  gab[gidx] += acc / (float)sp;
}

// ============================================================
// node features -> h (B,S,HID)
// ============================================================
__global__ __launch_bounds__(256) void nodefeat_kernel(
    const int* __restrict__ x, const int* __restrict__ indeg,
    const int* __restrict__ outdeg, const float* __restrict__ atom_emb,
    const float* __restrict__ in_emb, const float* __restrict__ out_emb,
    const float* __restrict__ gtok, float* __restrict__ h)
{
  int idx = blockIdx.x * 256 + threadIdx.x;
  if (idx >= B_*S_*HID_) return;
  int c = idx % HID_;
  int s = (idx / HID_) % S_;
  int b = idx / (HID_*S_);
  float v;
  if (s == 0) {
    v = gtok[c];
  } else {
    int n = s - 1;
    v = in_emb[indeg[b*N_ + n]*HID_ + c] + out_emb[outdeg[b*N_ + n]*HID_ + c];
    const int* xr = x + (b*N_ + n)*9;
#pragma unroll
    for (int e = 0; e < 9; ++e) v += atom_emb[(long)xr[e]*HID_ + c];
  }
  h[idx] = v;
}

// ============================================================
// LayerNorm over last dim (768): one block per row
// ============================================================
__global__ __launch_bounds__(256) void ln_kernel(
    const float* __restrict__ in, const float* __restrict__ g,
    const float* __restrict__ bta, float* __restrict__ out)
{
  int row = blockIdx.x;
  int tid = threadIdx.x;
  const float* xr = in + (long)row * HID_;
  float x0 = xr[tid], x1 = xr[tid + 256], x2 = xr[tid + 512];
  float s = x0 + x1 + x2;
  float ss = x0*x0 + x1*x1 + x2*x2;
  for (int off = 32; off > 0; off >>= 1) {
    s  += __shfl_xor(s, off);
    ss += __shfl_xor(ss, off);
  }
  __shared__ float rs[4], rss[4];
  int w = tid / 64;
  if ((tid & 63) == 0) { rs[w] = s; rss[w] = ss; }
  __syncthreads();
  s  = rs[0] + rs[1] + rs[2] + rs[3];
  ss = rss[0] + rss[1] + rss[2] + rss[3];
  float mean = s * (1.0f/768.0f);
  float var  = ss * (1.0f/768.0f) - mean*mean;
  float rstd = rsqrtf(var + 1e-5f);
  float* orow = out + (long)row * HID_;
  orow[tid]       = (x0 - mean)*rstd*g[tid]       + bta[tid];
  orow[tid + 256] = (x1 - mean)*rstd*g[tid + 256] + bta[tid + 256];
  orow[tid + 512] = (x2 - mean)*rstd*g[tid + 512] + bta[tid + 512];
}

// ============================================================
// fp32 tiled GEMM: C[M,N] = epilogue(A[M,K] @ W[K,N] + bias)
// mode bit0: *scale ; bit1: gelu(exact) ; bit2: += resid
// BM=64 BN=64 BK=16, 256 threads, 4x4 per thread
// ============================================================
__global__ __launch_bounds__(256) void gemm_kernel(
    const float* __restrict__ A, const float* __restrict__ W,
    const float* __restrict__ bias, const float* __restrict__ resid,
    float* __restrict__ C, int M, int N, int K, float scale, int mode)
{
  __shared__ float As[16][65];   // [k][m], padded
  __shared__ float Bs[16][64];   // [k][n]
  int tid = threadIdx.x;
  int bm = blockIdx.y * 64;
  int bn = blockIdx.x * 64;
  int tx = tid % 16, ty = tid / 16;
  float acc[4][4] = {};
  for (int k0 = 0; k0 < K; k0 += 16) {
    // A tile: 64 rows x 16 k
    for (int idx = tid; idx < 64*16; idx += 256) {
      int r = idx / 16, c = idx % 16;
      int gr = bm + r; if (gr >= M) gr = M - 1;
      As[c][r] = A[(long)gr*K + k0 + c];
    }
    // B tile: 16 k x 64 n
    for (int idx = tid; idx < 16*64; idx += 256) {
      int r = idx / 64, c = idx % 64;
      Bs[r][c] = W[(long)(k0 + r)*N + bn + c];
    }
    __syncthreads();
#pragma unroll
    for (int kk = 0; kk < 16; ++kk) {
      float a0 = As[kk][ty*4+0], a1 = As[kk][ty*4+1];
      float a2 = As[kk][ty*4+2], a3 = As[kk][ty*4+3];
      float4 bv = *reinterpret_cast<const float4*>(&Bs[kk][tx*4]);
      acc[0][0] += a0*bv.x; acc[0][1] += a0*bv.y; acc[0][2] += a0*bv.z; acc[0][3] += a0*bv.w;
      acc[1][0] += a1*bv.x; acc[1][1] += a1*bv.y; acc[1][2] += a1*bv.z; acc[1][3] += a1*bv.w;
      acc[2][0] += a2*bv.x; acc[2][1] += a2*bv.y; acc[2][2] += a2*bv.z; acc[2][3] += a2*bv.w;
      acc[3][0] += a3*bv.x; acc[3][1] += a3*bv.y; acc[3][2] += a3*bv.z; acc[3][3] += a3*bv.w;
    }
    __syncthreads();
  }
#pragma unroll
  for (int i = 0; i < 4; ++i) {
    int m = bm + ty*4 + i;
    if (m >= M) continue;
#pragma unroll
    for (int j = 0; j < 4; ++j) {
      int n = bn + tx*4 + j;
      float v = acc[i][j] + bias[n];
      if (mode & 1) v *= scale;
      if (mode & 2) v = 0.5f * v * (1.0f + erff(v * 0.70710678118654752f));
      if (mode & 4) v += resid[(long)m*N + n];
      C[(long)m*N + n] = v;
    }
  }
}

// ============================================================
// fused attention per (b, head): scores(+gab) -> softmax -> @V
// block = 256 (4 waves); wave w handles q-rows w, w+4, ...
// ============================================================
__global__ __launch_bounds__(256) void attn_kernel(
    const float* __restrict__ q, const float* __restrict__ k,
    const float* __restrict__ v, const float* __restrict__ gab,
    float* __restrict__ out)
{
  int bh = blockIdx.x;
  int b = bh / H_, hh = bh % H_;
  __shared__ float ql[S_*25], kl[S_*25], vl[S_*25];
  __shared__ float pl[4][132];
  int tid = threadIdx.x;
  for (int idx = tid; idx < S_*D_; idx += 256) {
    int s = idx / D_, c = idx % D_;
    long g = (long)(b*S_ + s)*HID_ + hh*D_ + c;
    ql[s*25 + c] = q[g];
    kl[s*25 + c] = k[g];
    vl[s*25 + c] = v[g];
  }
  __syncthreads();
  int w = tid / 64, lane = tid % 64;
  for (int qi = w; qi < S_; qi += 4) {
    const float* grow = gab + ((long)(b*H_ + hh)*S_ + qi)*S_;
    float sv[3];
    float mx = -1e30f;
#pragma unroll
    for (int t3 = 0; t3 < 3; ++t3) {
      int j = lane + t3*64;
      float sc = -1e30f;
      if (j < S_) {
        float dot = 0.0f;
#pragma unroll
        for (int c = 0; c < D_; ++c) dot += ql[qi*25 + c] * kl[j*25 + c];
        sc = dot + grow[j];
      }
      sv[t3] = sc;
      mx = fmaxf(mx, sc);
    }
    for (int off = 32; off > 0; off >>= 1) mx = fmaxf(mx, __shfl_xor(mx, off));
    float sum = 0.0f;
#pragma unroll
    for (int t3 = 0; t3 < 3; ++t3) {
      int j = lane + t3*64;
      float e = (j < S_) ? __expf(sv[t3] - mx) : 0.0f;
      sum += e;
      if (j < S_) pl[w][j] = e;
    }
    for (int off = 32; off > 0; off >>= 1) sum += __shfl_xor(sum, off);
    float inv = 1.0f / sum;
    if (lane < D_) {
      float acc = 0.0f;
      for (int j = 0; j < S_; ++j) acc += pl[w][j] * vl[j*25 + lane];
      out[(long)(b*S_ + qi)*HID_ + hh*D_ + lane] = acc * inv;
    }
  }
}

// ============================================================
// final: LN(h[b,0,:]) @ proj_w + proj_b  -> out[b]
// ============================================================
__global__ __launch_bounds__(256) void final_kernel(
    const float* __restrict__ h, const float* __restrict__ fg,
    const float* __restrict__ fb, const float* __restrict__ pw,
    const float* __restrict__ pb, float* __restrict__ out)
{
  int b = blockIdx.x;
  int tid = threadIdx.x;
  const float* xr = h + (long)b * S_ * HID_;   // row s=0
  float x0 = xr[tid], x1 = xr[tid + 256], x2 = xr[tid + 512];
  float s = x0 + x1 + x2;
  float ss = x0*x0 + x1*x1 + x2*x2;
  for (int off = 32; off > 0; off >>= 1) {
    s  += __shfl_xor(s, off);
    ss += __shfl_xor(ss, off);
  }
  __shared__ float rs[4], rss[4], rd[4];
  int w = tid / 64;
  if ((tid & 63) == 0) { rs[w] = s; rss[w] = ss; }
  __syncthreads();
  s  = rs[0] + rs[1] + rs[2] + rs[3];
  ss = rss[0] + rss[1] + rss[2] + rss[3];
  float mean = s * (1.0f/768.0f);
  float var  = ss * (1.0f/768.0f) - mean*mean;
  float rstd = rsqrtf(var + 1e-5f);
  float d0 = ((x0 - mean)*rstd*fg[tid]       + fb[tid])       * pw[tid];
  float d1 = ((x1 - mean)*rstd*fg[tid + 256] + fb[tid + 256]) * pw[tid + 256];
  float d2 = ((x2 - mean)*rstd*fg[tid + 512] + fb[tid + 512]) * pw[tid + 512];
  float pd = d0 + d1 + d2;
  for (int off = 32; off > 0; off >>= 1) pd += __shfl_xor(pd, off);
  if ((tid & 63) == 0) rd[w] = pd;
  __syncthreads();
  if (tid == 0) out[b] = rd[0] + rd[1] + rd[2] + rd[3] + pb[0];
}

// ============================================================
extern "C" void kernel_launch(void* const* d_in, const int* in_sizes, int n_in,
                              void* d_out, int out_size, void* d_ws, size_t ws_size,
                              hipStream_t stream)
{
  const float* attn_bias   = (const float*)d_in[0];
  const int*   spatial_pos = (const int*)d_in[1];
  const int*   x           = (const int*)d_in[2];
  const int*   in_degree   = (const int*)d_in[3];
  const int*   out_degree  = (const int*)d_in[4];
  const int*   edge_input  = (const int*)d_in[5];
  const float* atom_emb    = (const float*)d_in[6];
  const float* edge_emb    = (const float*)d_in[7];
  const float* edge_dis    = (const float*)d_in[8];
  const float* spatial_emb = (const float*)d_in[9];
  const float* in_deg_emb  = (const float*)d_in[10];
  const float* out_deg_emb = (const float*)d_in[11];
  const float* graph_token = (const float*)d_in[12];
  const float* gt_vd       = (const float*)d_in[13];
  const float* ln1_g = (const float*)d_in[14];
  const float* ln1_b = (const float*)d_in[15];
  const float* wq = (const float*)d_in[16];
  const float* bq = (const float*)d_in[17];
  const float* wk = (const float*)d_in[18];
  const float* bk = (const float*)d_in[19];
  const float* wv = (const float*)d_in[20];
  const float* bv = (const float*)d_in[21];
  const float* wo = (const float*)d_in[22];
  const float* bo = (const float*)d_in[23];
  const float* ln2_g = (const float*)d_in[24];
  const float* ln2_b = (const float*)d_in[25];
  const float* w1 = (const float*)d_in[26];
  const float* b1 = (const float*)d_in[27];
  const float* w2 = (const float*)d_in[28];
  const float* b2 = (const float*)d_in[29];
  const float* final_g = (const float*)d_in[30];
  const float* final_b = (const float*)d_in[31];
  const float* proj_w  = (const float*)d_in[32];
  const float* proj_b  = (const float*)d_in[33];

  float* out = (float*)d_out;
  float* ws  = (float*)d_ws;

  const long GAB_N = (long)B_*H_*S_*S_;          // 8,520,192
  const long ROW_N = (long)B_*S_*HID_;           // 1,585,152

  float* gab = ws;
  float* h   = gab + GAB_N;
  float* y   = h + ROW_N;
  float* qb  = y + ROW_N;
  float* kb  = qb + ROW_N;
  float* vb  = kb + ROW_N;
  float* ob  = vb + ROW_N;     // attention output (pre-Wo)
  float* ffn = qb;             // alias over q,k,v,ob: 4*ROW_N = 6,340,608 >= B*S*FFN

  const int M = B_ * S_;       // 2064
  const float scale = 0.20412414523193154f;  // 24^-0.5

  // gab precompute
  gab_base_kernel<<<(int)((GAB_N + 255)/256), 256, 0, stream>>>(
      attn_bias, spatial_pos, spatial_emb, gt_vd, gab);
  edge_kernel<<<B_*N_*N_/8, 256, 0, stream>>>(
      edge_input, edge_emb, edge_dis, spatial_pos, gab);

  // node features
  nodefeat_kernel<<<(int)((ROW_N + 255)/256), 256, 0, stream>>>(
      x, in_degree, out_degree, atom_emb, in_deg_emb, out_deg_emb, graph_token, h);

  dim3 g768(768/64, (M + 63)/64);
  dim3 g3072(3072/64, (M + 63)/64);

  for (int l = 0; l < L_; ++l) {
    const float* Wq = wq + (size_t)l*HID_*HID_;
    const float* Wk = wk + (size_t)l*HID_*HID_;
    const float* Wv = wv + (size_t)l*HID_*HID_;
    const float* Wo = wo + (size_t)l*HID_*HID_;
    const float* W1 = w1 + (size_t)l*HID_*FFN_;
    const float* W2 = w2 + (size_t)l*FFN_*HID_;

    ln_kernel<<<M, 256, 0, stream>>>(h, ln1_g + l*HID_, ln1_b + l*HID_, y);
    gemm_kernel<<<g768, 256, 0, stream>>>(y, Wq, bq + l*HID_, nullptr, qb,
                                          M, HID_, HID_, scale, 1);
    gemm_kernel<<<g768, 256, 0, stream>>>(y, Wk, bk + l*HID_, nullptr, kb,
                                          M, HID_, HID_, 1.0f, 0);
    gemm_kernel<<<g768, 256, 0, stream>>>(y, Wv, bv + l*HID_, nullptr, vb,
                                          M, HID_, HID_, 1.0f, 0);
    attn_kernel<<<B_*H_, 256, 0, stream>>>(qb, kb, vb, gab, ob);
    gemm_kernel<<<g768, 256, 0, stream>>>(ob, Wo, bo + l*HID_, h, h,
                                          M, HID_, HID_, 1.0f, 4);
    ln_kernel<<<M, 256, 0, stream>>>(h, ln2_g + l*HID_, ln2_b + l*HID_, y);
    gemm_kernel<<<g3072, 256, 0, stream>>>(y, W1, b1 + l*FFN_, nullptr, ffn,
                                           M, FFN_, HID_, 1.0f, 2);
    gemm_kernel<<<g768, 256, 0, stream>>>(ffn, W2, b2 + l*HID_, h, h,
                                          M, HID_, FFN_, 1.0f, 4);
  }

  final_kernel<<<B_, 256, 0, stream>>>(h, final_g, final_b, proj_w, proj_b, out);
}

// Round 2
// 4197.541 us; speedup vs baseline: 4.2705x; 4.2705x over previous
//
#include <hip/hip_runtime.h>
#include <hip/hip_bf16.h>
#include <math.h>

#define B_ 16
#define N_ 128
#define S_ 129
#define HID_ 768
#define H_ 32
#define D_ 24
#define FFN_ 3072
#define L_ 12
#define M_ (B_*S_)   // 2064

typedef __attribute__((ext_vector_type(8))) short short8;
typedef __attribute__((ext_vector_type(4))) float f32x4;
typedef __hip_bfloat16 bf16;

__device__ __forceinline__ void gload_lds16(const void* g, void* l) {
  __builtin_amdgcn_global_load_lds(
      (const __attribute__((address_space(1))) void*)g,
      (__attribute__((address_space(3))) void*)l, 16, 0, 0);
}

// ============================================================
// gab base: gab[b,hh,qi,kj] = 2*ab + spatial(qi>0,kj>0) + t(qi==0||kj==0)
// ============================================================
__global__ __launch_bounds__(256) void gab_base_kernel(
    const float* __restrict__ ab, const int* __restrict__ spos,
    const float* __restrict__ spemb, const float* __restrict__ gtvd,
    float* __restrict__ gab)
{
  int idx = blockIdx.x * 256 + threadIdx.x;
  if (idx >= B_*H_*S_*S_) return;
  int kj = idx % S_;
  int qi = (idx / S_) % S_;
  int hh = (idx / (S_*S_)) % H_;
  int b  = idx / (S_*S_*H_);
  float v = 2.0f * ab[(b*S_ + qi)*S_ + kj];
  if (qi > 0 && kj > 0)
    v += spemb[spos[(b*N_ + (qi-1))*N_ + (kj-1)]*H_ + hh];
  if (qi == 0 || kj == 0) v += gtvd[hh];
  gab[idx] = v;
}

// ============================================================
// edge encoding add into gab
// ============================================================
__global__ __launch_bounds__(256) void edge_kernel(
    const int* __restrict__ eidx, const float* __restrict__ eemb,
    const float* __restrict__ edis, const int* __restrict__ spos,
    float* __restrict__ gab)
{
  __shared__ float ml[8][5][32];
  int tid = threadIdx.x;
  int jl = tid / 32, hh = tid % 32;
  int lin = blockIdx.x * 8 + jl;
  int j = lin % N_;
  int i = (lin / N_) % N_;
  int b = lin / (N_*N_);
  const int* er = eidx + ((long)(b*N_ + i)*N_ + j) * 15;
#pragma unroll
  for (int d = 0; d < 5; ++d) {
    float m = (eemb[er[d*3+0]*H_ + hh] + eemb[er[d*3+1]*H_ + hh] +
               eemb[er[d*3+2]*H_ + hh]) * (1.0f/3.0f);
    ml[jl][d][hh] = m;
  }
  __syncthreads();
  float acc = 0.0f;
#pragma unroll
  for (int d = 0; d < 5; ++d)
#pragma unroll
    for (int hp = 0; hp < 32; ++hp)
      acc += ml[jl][d][hp] * edis[d*1024 + hp*32 + hh];
  int sp0 = spos[(b*N_ + i)*N_ + j];
  int sp = (sp0 == 0) ? 1 : sp0;
  if (sp > 1) sp -= 1;
  if (sp > 5) sp = 5;
  long gidx = ((long)(b*H_ + hh)*S_ + (i+1))*S_ + (j+1);
  gab[gidx] += acc / (float)sp;
}

// ============================================================
// node features -> h (B,S,HID) fp32
// ============================================================
__global__ __launch_bounds__(256) void nodefeat_kernel(
    const int* __restrict__ x, const int* __restrict__ indeg,
    const int* __restrict__ outdeg, const float* __restrict__ atom_emb,
    const float* __restrict__ in_emb, const float* __restrict__ out_emb,
    const float* __restrict__ gtok, float* __restrict__ h)
{
  int idx = blockIdx.x * 256 + threadIdx.x;
  if (idx >= M_*HID_) return;
  int c = idx % HID_;
  int s = (idx / HID_) % S_;
  int b = idx / (HID_*S_);
  float v;
  if (s == 0) {
    v = gtok[c];
  } else {
    int n = s - 1;
    v = in_emb[indeg[b*N_ + n]*HID_ + c] + out_emb[outdeg[b*N_ + n]*HID_ + c];
    const int* xr = x + (b*N_ + n)*9;
#pragma unroll
    for (int e = 0; e < 9; ++e) v += atom_emb[(long)xr[e]*HID_ + c];
  }
  h[idx] = v;
}

// ============================================================
// LayerNorm (768) fp32 in -> bf16 out
// ============================================================
__global__ __launch_bounds__(256) void ln_kernel(
    const float* __restrict__ in, const float* __restrict__ g,
    const float* __restrict__ bta, bf16* __restrict__ out)
{
  int row = blockIdx.x;
  int tid = threadIdx.x;
  const float* xr = in + (long)row * HID_;
  float x0 = xr[tid], x1 = xr[tid + 256], x2 = xr[tid + 512];
  float s = x0 + x1 + x2;
  float ss = x0*x0 + x1*x1 + x2*x2;
  for (int off = 32; off > 0; off >>= 1) {
    s  += __shfl_xor(s, off);
    ss += __shfl_xor(ss, off);
  }
  __shared__ float rs[4], rss[4];
  int w = tid / 64;
  if ((tid & 63) == 0) { rs[w] = s; rss[w] = ss; }
  __syncthreads();
  s  = rs[0] + rs[1] + rs[2] + rs[3];
  ss = rss[0] + rss[1] + rss[2] + rss[3];
  float mean = s * (1.0f/768.0f);
  float var  = ss * (1.0f/768.0f) - mean*mean;
  float rstd = rsqrtf(var + 1e-5f);
  bf16* orow = out + (long)row * HID_;
  orow[tid]       = __float2bfloat16((x0 - mean)*rstd*g[tid]       + bta[tid]);
  orow[tid + 256] = __float2bfloat16((x1 - mean)*rstd*g[tid + 256] + bta[tid + 256]);
  orow[tid + 512] = __float2bfloat16((x2 - mean)*rstd*g[tid + 512] + bta[tid + 512]);
}

// ============================================================
// weight convert: W[K][N] fp32 -> Out[N][K] bf16 (*scale), 32x32 LDS tiles
// ============================================================
__global__ __launch_bounds__(256) void wconv_kernel(
    const float* __restrict__ W, bf16* __restrict__ Out,
    int K, int N, float scale)
{
  __shared__ float tile[32][33];
  int bx = blockIdx.x * 32;  // n
  int by = blockIdx.y * 32;  // k
  int tx = threadIdx.x & 31, ty = threadIdx.x >> 5;
#pragma unroll
  for (int r = 0; r < 32; r += 8)
    tile[ty + r][tx] = W[(long)(by + ty + r)*N + bx + tx];
  __syncthreads();
#pragma unroll
  for (int r = 0; r < 32; r += 8)
    Out[(long)(bx + ty + r)*K + by + tx] = __float2bfloat16(tile[tx][ty + r] * scale);
}

// qkv combined: wq/wk/wv [768][768] -> Out[(z*768+n)][768], q scaled
__global__ __launch_bounds__(256) void qkvconv_kernel(
    const float* __restrict__ wq, const float* __restrict__ wk,
    const float* __restrict__ wv, bf16* __restrict__ Out, float scale)
{
  const float* W = blockIdx.z == 0 ? wq : blockIdx.z == 1 ? wk : wv;
  float sc = blockIdx.z == 0 ? scale : 1.0f;
  __shared__ float tile[32][33];
  int bx = blockIdx.x * 32;
  int by = blockIdx.y * 32;
  int tx = threadIdx.x & 31, ty = threadIdx.x >> 5;
#pragma unroll
  for (int r = 0; r < 32; r += 8)
    tile[ty + r][tx] = W[(long)(by + ty + r)*768 + bx + tx];
  __syncthreads();
  bf16* O = Out + (long)blockIdx.z * 768 * 768;
#pragma unroll
  for (int r = 0; r < 32; r += 8)
    O[(long)(bx + ty + r)*768 + by + tx] = __float2bfloat16(tile[tx][ty + r] * sc);
}

// concat+scale qkv biases for all layers: bqkv[l][0:768]=bq*scale, [768:1536]=bk, [1536:2304]=bv
__global__ __launch_bounds__(256) void biasqkv_kernel(
    const float* __restrict__ bq, const float* __restrict__ bk,
    const float* __restrict__ bv, float* __restrict__ bqkv, float scale)
{
  int idx = blockIdx.x * 256 + threadIdx.x;
  if (idx >= L_*2304) return;
  int l = idx / 2304, n = idx % 2304;
  int p = n / 768, nn = n % 768;
  float v = (p == 0) ? bq[l*768 + nn]*scale : (p == 1) ? bk[l*768 + nn] : bv[l*768 + nn];
  bqkv[idx] = v;
}

// ============================================================
// bf16 MFMA GEMM: C = epi(A[M,K] @ Wt[N,K]^T + bias)
// BM=BN=128, BK=32, 256 threads (4 waves, 2x2), 4x4 16x16 frags/wave
// mode 0: bf16 out; 1: gelu -> bf16 out; 2: +resid -> fp32 out
// LDS k-chunk XOR swizzle (chunk ^= (row>>1)&3): linear gload_lds dest,
// inverse-swizzled global source, swizzled ds_read -> 2-way (free)
// ============================================================
__global__ __launch_bounds__(256) void mfma_gemm_kernel(
    const bf16* __restrict__ A, const bf16* __restrict__ Wt,
    const float* __restrict__ bias, const float* __restrict__ resid,
    void* __restrict__ Cout, int M, int N, int K, int mode)
{
  __shared__ bf16 Als[128*32];
  __shared__ bf16 Bls[128*32];
  int tid = threadIdx.x;
  int wid = tid >> 6, lane = tid & 63;
  int bm = blockIdx.y * 128, bn = blockIdx.x * 128;
  int wr = wid >> 1, wc = wid & 1;
  int lr = lane & 15, kg = lane >> 4;

  const short8* aptr[4];
  const short8* bptr[4];
#pragma unroll
  for (int m = 0; m < 4; ++m) {
    int row = wr*64 + m*16 + lr;
    aptr[m] = (const short8*)&Als[(row*4 + (kg ^ ((row>>1)&3)))*8];
    int col = wc*64 + m*16 + lr;
    bptr[m] = (const short8*)&Bls[(col*4 + (kg ^ ((col>>1)&3)))*8];
  }

  f32x4 acc[4][4];
#pragma unroll
  for (int m = 0; m < 4; ++m)
#pragma unroll
    for (int n = 0; n < 4; ++n)
      acc[m][n] = (f32x4){0.0f, 0.0f, 0.0f, 0.0f};

  for (int k0 = 0; k0 < K; k0 += 32) {
#pragma unroll
    for (int it = 0; it < 2; ++it) {
      int c = it*256 + wid*64 + lane;
      int row = c >> 2, kc = c & 3;
      int kcs = kc ^ ((row >> 1) & 3);
      int grow = bm + row; if (grow >= M) grow = M - 1;
      gload_lds16(A + (long)grow*K + k0 + kcs*8, &Als[(it*256 + wid*64)*8]);
      gload_lds16(Wt + (long)(bn + row)*K + k0 + kcs*8, &Bls[(it*256 + wid*64)*8]);
    }
    __syncthreads();
    short8 av[4], bv4[4];
#pragma unroll
    for (int m = 0; m < 4; ++m) av[m] = *aptr[m];
#pragma unroll
    for (int n = 0; n < 4; ++n) bv4[n] = *bptr[n];
#pragma unroll
    for (int m = 0; m < 4; ++m)
#pragma unroll
      for (int n = 0; n < 4; ++n)
        acc[m][n] = __builtin_amdgcn_mfma_f32_16x16x32_bf16(av[m], bv4[n], acc[m][n], 0, 0, 0);
    __syncthreads();
  }

#pragma unroll
  for (int n = 0; n < 4; ++n) {
    int col = bn + wc*64 + n*16 + lr;
    float bcol = bias[col];
#pragma unroll
    for (int m = 0; m < 4; ++m) {
      f32x4 a = acc[m][n];
#pragma unroll
      for (int i = 0; i < 4; ++i) {
        int row = bm + wr*64 + m*16 + kg*4 + i;
        if (row < M) {
          float v = a[i] + bcol;
          if (mode == 1) v = 0.5f * v * (1.0f + erff(v * 0.70710678118654752f));
          if (mode == 2)
            ((float*)Cout)[(long)row*N + col] = v + resid[(long)row*N + col];
          else
            ((bf16*)Cout)[(long)row*N + col] = __float2bfloat16(v);
        }
      }
    }
  }
}

// ============================================================
// fused attention per (b, head): bf16 qkv in, bf16 out
// ============================================================
__global__ __launch_bounds__(256) void attn_kernel(
    const bf16* __restrict__ qkv, const float* __restrict__ gab,
    bf16* __restrict__ ob)
{
  int bh = blockIdx.x;
  int b = bh >> 5, hh = bh & 31;
  __shared__ float ql[S_*25], kl[S_*25], vl[S_*25];
  __shared__ float pl[4][132];
  int tid = threadIdx.x;
  for (int idx = tid; idx < S_*D_; idx += 256) {
    int s = idx / D_, c = idx % D_;
    long g = (long)(b*S_ + s)*2304 + hh*D_ + c;
    ql[s*25 + c] = __bfloat162float(qkv[g]);
    kl[s*25 + c] = __bfloat162float(qkv[g + 768]);
    vl[s*25 + c] = __bfloat162float(qkv[g + 1536]);
  }
  __syncthreads();
  int w = tid / 64, lane = tid % 64;
  for (int qi = w; qi < S_; qi += 4) {
    const float* grow = gab + ((long)(b*H_ + hh)*S_ + qi)*S_;
    float sv[3];
    float mx = -1e30f;
#pragma unroll
    for (int t3 = 0; t3 < 3; ++t3) {
      int j = lane + t3*64;
      float sc = -1e30f;
      if (j < S_) {
        float dot = 0.0f;
#pragma unroll
        for (int c = 0; c < D_; ++c) dot += ql[qi*25 + c] * kl[j*25 + c];
        sc = dot + grow[j];
      }
      sv[t3] = sc;
      mx = fmaxf(mx, sc);
    }
    for (int off = 32; off > 0; off >>= 1) mx = fmaxf(mx, __shfl_xor(mx, off));
    float sum = 0.0f;
#pragma unroll
    for (int t3 = 0; t3 < 3; ++t3) {
      int j = lane + t3*64;
      float e = (j < S_) ? __expf(sv[t3] - mx) : 0.0f;
      sum += e;
      if (j < S_) pl[w][j] = e;
    }
    for (int off = 32; off > 0; off >>= 1) sum += __shfl_xor(sum, off);
    float inv = 1.0f / sum;
    if (lane < D_) {
      float acc = 0.0f;
      for (int j = 0; j < S_; ++j) acc += pl[w][j] * vl[j*25 + lane];
      ob[(long)(b*S_ + qi)*HID_ + hh*D_ + lane] = __float2bfloat16(acc * inv);
    }
  }
}

// ============================================================
// final: LN(h[b,0,:]) @ proj_w + proj_b -> out[b]
// ============================================================
__global__ __launch_bounds__(256) void final_kernel(
    const float* __restrict__ h, const float* __restrict__ fg,
    const float* __restrict__ fb, const float* __restrict__ pw,
    const float* __restrict__ pb, float* __restrict__ out)
{
  int b = blockIdx.x;
  int tid = threadIdx.x;
  const float* xr = h + (long)b * S_ * HID_;
  float x0 = xr[tid], x1 = xr[tid + 256], x2 = xr[tid + 512];
  float s = x0 + x1 + x2;
  float ss = x0*x0 + x1*x1 + x2*x2;
  for (int off = 32; off > 0; off >>= 1) {
    s  += __shfl_xor(s, off);
    ss += __shfl_xor(ss, off);
  }
  __shared__ float rs[4], rss[4], rd[4];
  int w = tid / 64;
  if ((tid & 63) == 0) { rs[w] = s; rss[w] = ss; }
  __syncthreads();
  s  = rs[0] + rs[1] + rs[2] + rs[3];
  ss = rss[0] + rss[1] + rss[2] + rss[3];
  float mean = s * (1.0f/768.0f);
  float var  = ss * (1.0f/768.0f) - mean*mean;
  float rstd = rsqrtf(var + 1e-5f);
  float d0 = ((x0 - mean)*rstd*fg[tid]       + fb[tid])       * pw[tid];
  float d1 = ((x1 - mean)*rstd*fg[tid + 256] + fb[tid + 256]) * pw[tid + 256];
  float d2 = ((x2 - mean)*rstd*fg[tid + 512] + fb[tid + 512]) * pw[tid + 512];
  float pd = d0 + d1 + d2;
  for (int off = 32; off > 0; off >>= 1) pd += __shfl_xor(pd, off);
  if ((tid & 63) == 0) rd[w] = pd;
  __syncthreads();
  if (tid == 0) out[b] = rd[0] + rd[1] + rd[2] + rd[3] + pb[0];
}

// ============================================================
extern "C" void kernel_launch(void* const* d_in, const int* in_sizes, int n_in,
                              void* d_out, int out_size, void* d_ws, size_t ws_size,
                              hipStream_t stream)
{
  const float* attn_bias   = (const float*)d_in[0];
  const int*   spatial_pos = (const int*)d_in[1];
  const int*   x           = (const int*)d_in[2];
  const int*   in_degree   = (const int*)d_in[3];
  const int*   out_degree  = (const int*)d_in[4];
  const int*   edge_input  = (const int*)d_in[5];
  const float* atom_emb    = (const float*)d_in[6];
  const float* edge_emb    = (const float*)d_in[7];
  const float* edge_dis    = (const float*)d_in[8];
  const float* spatial_emb = (const float*)d_in[9];
  const float* in_deg_emb  = (const float*)d_in[10];
  const float* out_deg_emb = (const float*)d_in[11];
  const float* graph_token = (const float*)d_in[12];
  const float* gt_vd       = (const float*)d_in[13];
  const float* ln1_g = (const float*)d_in[14];
  const float* ln1_b = (const float*)d_in[15];
  const float* wq = (const float*)d_in[16];
  const float* bq = (const float*)d_in[17];
  const float* wk = (const float*)d_in[18];
  const float* bk = (const float*)d_in[19];
  const float* wv = (const float*)d_in[20];
  const float* bv = (const float*)d_in[21];
  const float* wo = (const float*)d_in[22];
  const float* bo = (const float*)d_in[23];
  const float* ln2_g = (const float*)d_in[24];
  const float* ln2_b = (const float*)d_in[25];
  const float* w1 = (const float*)d_in[26];
  const float* b1 = (const float*)d_in[27];
  const float* w2 = (const float*)d_in[28];
  const float* b2 = (const float*)d_in[29];
  const float* final_g = (const float*)d_in[30];
  const float* final_b = (const float*)d_in[31];
  const float* proj_w  = (const float*)d_in[32];
  const float* proj_b  = (const float*)d_in[33];

  float* out = (float*)d_out;

  const float scale = 0.20412414523193154f;  // 24^-0.5
  const long GAB_N = (long)B_*H_*S_*S_;      // 8,520,192

  char* p = (char*)d_ws;
  float* gab  = (float*)p;  p += GAB_N*4;
  float* h    = (float*)p;  p += (long)M_*HID_*4;
  bf16*  y    = (bf16*)p;   p += (long)M_*HID_*2;
  bf16*  qkv  = (bf16*)p;   // ffn aliases qkv+ob (12,681,216 B exactly)
  bf16*  ffn  = qkv;
  p += (long)M_*2304*2;
  bf16*  ob   = (bf16*)p;   p += (long)M_*HID_*2;
  bf16*  Wqkvt= (bf16*)p;   p += (long)2304*768*2;
  bf16*  Wot  = (bf16*)p;   p += (long)768*768*2;
  bf16*  W1t  = (bf16*)p;   p += (long)3072*768*2;
  bf16*  W2t  = (bf16*)p;   p += (long)768*3072*2;
  float* bqkv = (float*)p;  p += (long)L_*2304*4;

  // ---- setup ----
  gab_base_kernel<<<(int)((GAB_N + 255)/256), 256, 0, stream>>>(
      attn_bias, spatial_pos, spatial_emb, gt_vd, gab);
  edge_kernel<<<B_*N_*N_/8, 256, 0, stream>>>(
      edge_input, edge_emb, edge_dis, spatial_pos, gab);
  nodefeat_kernel<<<(M_*HID_ + 255)/256, 256, 0, stream>>>(
      x, in_degree, out_degree, atom_emb, in_deg_emb, out_deg_emb, graph_token, h);
  biasqkv_kernel<<<(L_*2304 + 255)/256, 256, 0, stream>>>(bq, bk, bv, bqkv, scale);

  dim3 gQKV(2304/128, (M_ + 127)/128);   // 18 x 17
  dim3 gO  (768/128,  (M_ + 127)/128);   //  6 x 17
  dim3 gF1 (3072/128, (M_ + 127)/128);   // 24 x 17
  dim3 cQKV(768/32, 768/32, 3);
  dim3 cO  (768/32, 768/32);
  dim3 cW1 (3072/32, 768/32);
  dim3 cW2 (768/32, 3072/32);

  for (int l = 0; l < L_; ++l) {
    ln_kernel<<<M_, 256, 0, stream>>>(h, ln1_g + l*HID_, ln1_b + l*HID_, y);

    qkvconv_kernel<<<cQKV, 256, 0, stream>>>(
        wq + (size_t)l*HID_*HID_, wk + (size_t)l*HID_*HID_, wv + (size_t)l*HID_*HID_,
        Wqkvt, scale);
    mfma_gemm_kernel<<<gQKV, 256, 0, stream>>>(
        y, Wqkvt, bqkv + l*2304, nullptr, qkv, M_, 2304, 768, 0);

    attn_kernel<<<B_*H_, 256, 0, stream>>>(qkv, gab, ob);

    wconv_kernel<<<cO, 256, 0, stream>>>(wo + (size_t)l*HID_*HID_, Wot, 768, 768, 1.0f);
    mfma_gemm_kernel<<<gO, 256, 0, stream>>>(
        ob, Wot, bo + l*HID_, h, h, M_, 768, 768, 2);

    ln_kernel<<<M_, 256, 0, stream>>>(h, ln2_g + l*HID_, ln2_b + l*HID_, y);

    wconv_kernel<<<cW1, 256, 0, stream>>>(w1 + (size_t)l*HID_*FFN_, W1t, 768, 3072, 1.0f);
    mfma_gemm_kernel<<<gF1, 256, 0, stream>>>(
        y, W1t, b1 + l*FFN_, nullptr, ffn, M_, 3072, 768, 1);

    wconv_kernel<<<cW2, 256, 0, stream>>>(w2 + (size_t)l*FFN_*HID_, W2t, 3072, 768, 1.0f);
    mfma_gemm_kernel<<<gO, 256, 0, stream>>>(
        ffn, W2t, b2 + l*HID_, h, h, M_, 768, 3072, 2);
  }

  final_kernel<<<B_, 256, 0, stream>>>(h, final_g, final_b, proj_w, proj_b, out);
}

// Round 3
// 3073.143 us; speedup vs baseline: 5.8330x; 1.3659x over previous
//
#include <hip/hip_runtime.h>
#include <hip/hip_bf16.h>
#include <math.h>

#define B_ 16
#define N_ 128
#define S_ 129
#define HID_ 768
#define H_ 32
#define D_ 24
#define FFN_ 3072
#define L_ 12
#define M_ (B_*S_)   // 2064
#define SP_ 144      // padded S for q/k rows (9 x 16)
#define KP_ 160      // padded kj for P rows / vt cols (5 x 32)

typedef __attribute__((ext_vector_type(8))) short short8;
typedef __attribute__((ext_vector_type(4))) float f32x4;
typedef __hip_bfloat16 bf16;

__device__ __forceinline__ void gload_lds16(const void* g, void* l) {
  __builtin_amdgcn_global_load_lds(
      (const __attribute__((address_space(1))) void*)g,
      (__attribute__((address_space(3))) void*)l, 16, 0, 0);
}

// ============================================================
// gab base: gab[b,hh,qi,kj] = 2*ab + spatial(qi>0,kj>0) + t(qi==0||kj==0)
// ============================================================
__global__ __launch_bounds__(256) void gab_base_kernel(
    const float* __restrict__ ab, const int* __restrict__ spos,
    const float* __restrict__ spemb, const float* __restrict__ gtvd,
    float* __restrict__ gab)
{
  int idx = blockIdx.x * 256 + threadIdx.x;
  if (idx >= B_*H_*S_*S_) return;
  int kj = idx % S_;
  int qi = (idx / S_) % S_;
  int hh = (idx / (S_*S_)) % H_;
  int b  = idx / (S_*S_*H_);
  float v = 2.0f * ab[(b*S_ + qi)*S_ + kj];
  if (qi > 0 && kj > 0)
    v += spemb[spos[(b*N_ + (qi-1))*N_ + (kj-1)]*H_ + hh];
  if (qi == 0 || kj == 0) v += gtvd[hh];
  gab[idx] = v;
}

// ============================================================
// F table: F[d][idx][hh] = (1/3) * sum_hp eemb[idx][hp] * edis[d][hp][hh]
// pairs p = d*1537 + idx (7685 total), 8 pairs x 32 hh per block
// ============================================================
__global__ __launch_bounds__(256) void ftab_kernel(
    const float* __restrict__ eemb, const float* __restrict__ edis,
    float* __restrict__ F)
{
  __shared__ float em[8][32];
  int tid = threadIdx.x;
  int jl = tid >> 5, hh = tid & 31;
  int p = blockIdx.x * 8 + jl;
  bool valid = p < 5*1537;
  int d = valid ? p / 1537 : 0;
  int idx = valid ? p % 1537 : 0;
  em[jl][hh] = eemb[idx*32 + hh];   // wave-local write/read, no barrier
  float acc = 0.f;
#pragma unroll
  for (int hp = 0; hp < 32; ++hp)
    acc += em[jl][hp] * edis[d*1024 + hp*32 + hh];
  if (valid) F[(long)p*32 + hh] = acc * (1.0f/3.0f);
}

// ============================================================
// edge encoding: block = (b,i) row; 15 F-gathers + adds per cell;
// coalesced gab RMW via LDS transpose
// ============================================================
__global__ __launch_bounds__(256) void edge_kernel(
    const int* __restrict__ eidx, const float* __restrict__ F,
    const int* __restrict__ spos, float* __restrict__ gab)
{
  __shared__ float outj[128][33];
  int tid = threadIdx.x;
  int jl = tid >> 5, hh = tid & 31;
  int bi = blockIdx.x;
  int b = bi >> 7, i = bi & 127;
  for (int ch = 0; ch < 16; ++ch) {
    int j = ch*8 + jl;
    const int* er = eidx + ((long)((b*N_ + i)*N_ + j)) * 15;
    float acc = 0.f;
#pragma unroll
    for (int t = 0; t < 15; ++t) {
      int d = t / 3;
      acc += F[((long)(d*1537 + er[t]))*32 + hh];
    }
    int sp0 = spos[(b*N_ + i)*N_ + j];
    int sp = (sp0 == 0) ? 1 : sp0;
    if (sp > 1) sp -= 1;
    if (sp > 5) sp = 5;
    outj[j][hh] = acc / (float)sp;
  }
  __syncthreads();
  // RMW gab rows: 2 hh-rows x 128 cols per iteration, coalesced
  for (int it = 0; it < 16; ++it) {
    int r = it*2 + (tid >> 7);
    int c = tid & 127;
    long g = ((long)(b*H_ + r)*S_ + (i+1))*S_ + 1 + c;
    gab[g] += outj[c][r];
  }
}

// ============================================================
// node features -> h (B,S,HID) fp32
// ============================================================
__global__ __launch_bounds__(256) void nodefeat_kernel(
    const int* __restrict__ x, const int* __restrict__ indeg,
    const int* __restrict__ outdeg, const float* __restrict__ atom_emb,
    const float* __restrict__ in_emb, const float* __restrict__ out_emb,
    const float* __restrict__ gtok, float* __restrict__ h)
{
  int idx = blockIdx.x * 256 + threadIdx.x;
  if (idx >= M_*HID_) return;
  int c = idx % HID_;
  int s = (idx / HID_) % S_;
  int b = idx / (HID_*S_);
  float v;
  if (s == 0) {
    v = gtok[c];
  } else {
    int n = s - 1;
    v = in_emb[indeg[b*N_ + n]*HID_ + c] + out_emb[outdeg[b*N_ + n]*HID_ + c];
    const int* xr = x + (b*N_ + n)*9;
#pragma unroll
    for (int e = 0; e < 9; ++e) v += atom_emb[(long)xr[e]*HID_ + c];
  }
  h[idx] = v;
}

// ============================================================
// LayerNorm (768) fp32 in -> bf16 out
// ============================================================
__global__ __launch_bounds__(256) void ln_kernel(
    const float* __restrict__ in, const float* __restrict__ g,
    const float* __restrict__ bta, bf16* __restrict__ out)
{
  int row = blockIdx.x;
  int tid = threadIdx.x;
  const float* xr = in + (long)row * HID_;
  float x0 = xr[tid], x1 = xr[tid + 256], x2 = xr[tid + 512];
  float s = x0 + x1 + x2;
  float ss = x0*x0 + x1*x1 + x2*x2;
  for (int off = 32; off > 0; off >>= 1) {
    s  += __shfl_xor(s, off);
    ss += __shfl_xor(ss, off);
  }
  __shared__ float rs[4], rss[4];
  int w = tid / 64;
  if ((tid & 63) == 0) { rs[w] = s; rss[w] = ss; }
  __syncthreads();
  s  = rs[0] + rs[1] + rs[2] + rs[3];
  ss = rss[0] + rss[1] + rss[2] + rss[3];
  float mean = s * (1.0f/768.0f);
  float var  = ss * (1.0f/768.0f) - mean*mean;
  float rstd = rsqrtf(var + 1e-5f);
  bf16* orow = out + (long)row * HID_;
  orow[tid]       = __float2bfloat16((x0 - mean)*rstd*g[tid]       + bta[tid]);
  orow[tid + 256] = __float2bfloat16((x1 - mean)*rstd*g[tid + 256] + bta[tid + 256]);
  orow[tid + 512] = __float2bfloat16((x2 - mean)*rstd*g[tid + 512] + bta[tid + 512]);
}

// ============================================================
// weight convert: W[K][N] fp32 -> Out[N][K] bf16 (*scale)
// ============================================================
__global__ __launch_bounds__(256) void wconv_kernel(
    const float* __restrict__ W, bf16* __restrict__ Out,
    int K, int N, float scale)
{
  __shared__ float tile[32][33];
  int bx = blockIdx.x * 32;
  int by = blockIdx.y * 32;
  int tx = threadIdx.x & 31, ty = threadIdx.x >> 5;
#pragma unroll
  for (int r = 0; r < 32; r += 8)
    tile[ty + r][tx] = W[(long)(by + ty + r)*N + bx + tx];
  __syncthreads();
#pragma unroll
  for (int r = 0; r < 32; r += 8)
    Out[(long)(bx + ty + r)*K + by + tx] = __float2bfloat16(tile[tx][ty + r] * scale);
}

__global__ __launch_bounds__(256) void qkvconv_kernel(
    const float* __restrict__ wq, const float* __restrict__ wk,
    const float* __restrict__ wv, bf16* __restrict__ Out, float scale)
{
  const float* W = blockIdx.z == 0 ? wq : blockIdx.z == 1 ? wk : wv;
  float sc = blockIdx.z == 0 ? scale : 1.0f;
  __shared__ float tile[32][33];
  int bx = blockIdx.x * 32;
  int by = blockIdx.y * 32;
  int tx = threadIdx.x & 31, ty = threadIdx.x >> 5;
#pragma unroll
  for (int r = 0; r < 32; r += 8)
    tile[ty + r][tx] = W[(long)(by + ty + r)*768 + bx + tx];
  __syncthreads();
  bf16* O = Out + (long)blockIdx.z * 768 * 768;
#pragma unroll
  for (int r = 0; r < 32; r += 8)
    O[(long)(bx + ty + r)*768 + by + tx] = __float2bfloat16(tile[tx][ty + r] * sc);
}

__global__ __launch_bounds__(256) void biasqkv_kernel(
    const float* __restrict__ bq, const float* __restrict__ bk,
    const float* __restrict__ bv, float* __restrict__ bqkv, float scale)
{
  int idx = blockIdx.x * 256 + threadIdx.x;
  if (idx >= L_*2304) return;
  int l = idx / 2304, n = idx % 2304;
  int p = n / 768, nn = n % 768;
  float v = (p == 0) ? bq[l*768 + nn]*scale : (p == 1) ? bk[l*768 + nn] : bv[l*768 + nn];
  bqkv[idx] = v;
}

// ============================================================
// bf16 MFMA GEMM (unchanged from round 2, verified)
// ============================================================
__global__ __launch_bounds__(256) void mfma_gemm_kernel(
    const bf16* __restrict__ A, const bf16* __restrict__ Wt,
    const float* __restrict__ bias, const float* __restrict__ resid,
    void* __restrict__ Cout, int M, int N, int K, int mode)
{
  __shared__ bf16 Als[128*32];
  __shared__ bf16 Bls[128*32];
  int tid = threadIdx.x;
  int wid = tid >> 6, lane = tid & 63;
  int bm = blockIdx.y * 128, bn = blockIdx.x * 128;
  int wr = wid >> 1, wc = wid & 1;
  int lr = lane & 15, kg = lane >> 4;

  const short8* aptr[4];
  const short8* bptr[4];
#pragma unroll
  for (int m = 0; m < 4; ++m) {
    int row = wr*64 + m*16 + lr;
    aptr[m] = (const short8*)&Als[(row*4 + (kg ^ ((row>>1)&3)))*8];
    int col = wc*64 + m*16 + lr;
    bptr[m] = (const short8*)&Bls[(col*4 + (kg ^ ((col>>1)&3)))*8];
  }

  f32x4 acc[4][4];
#pragma unroll
  for (int m = 0; m < 4; ++m)
#pragma unroll
    for (int n = 0; n < 4; ++n)
      acc[m][n] = (f32x4){0.0f, 0.0f, 0.0f, 0.0f};

  for (int k0 = 0; k0 < K; k0 += 32) {
#pragma unroll
    for (int it = 0; it < 2; ++it) {
      int c = it*256 + wid*64 + lane;
      int row = c >> 2, kc = c & 3;
      int kcs = kc ^ ((row >> 1) & 3);
      int grow = bm + row; if (grow >= M) grow = M - 1;
      gload_lds16(A + (long)grow*K + k0 + kcs*8, &Als[(it*256 + wid*64)*8]);
      gload_lds16(Wt + (long)(bn + row)*K + k0 + kcs*8, &Bls[(it*256 + wid*64)*8]);
    }
    __syncthreads();
    short8 av[4], bv4[4];
#pragma unroll
    for (int m = 0; m < 4; ++m) av[m] = *aptr[m];
#pragma unroll
    for (int n = 0; n < 4; ++n) bv4[n] = *bptr[n];
#pragma unroll
    for (int m = 0; m < 4; ++m)
#pragma unroll
      for (int n = 0; n < 4; ++n)
        acc[m][n] = __builtin_amdgcn_mfma_f32_16x16x32_bf16(av[m], bv4[n], acc[m][n], 0, 0, 0);
    __syncthreads();
  }

#pragma unroll
  for (int n = 0; n < 4; ++n) {
    int col = bn + wc*64 + n*16 + lr;
    float bcol = bias[col];
#pragma unroll
    for (int m = 0; m < 4; ++m) {
      f32x4 a = acc[m][n];
#pragma unroll
      for (int i = 0; i < 4; ++i) {
        int row = bm + wr*64 + m*16 + kg*4 + i;
        if (row < M) {
          float v = a[i] + bcol;
          if (mode == 1) v = 0.5f * v * (1.0f + erff(v * 0.70710678118654752f));
          if (mode == 2)
            ((float*)Cout)[(long)row*N + col] = v + resid[(long)row*N + col];
          else
            ((bf16*)Cout)[(long)row*N + col] = __float2bfloat16(v);
        }
      }
    }
  }
}

// ============================================================
// MFMA fused attention per (b, head)
// 4 waves; wave w handles 16-row q-tiles {w, w+4, w+8}
// QK^T: 9 mfma_16x16x32 (D=24 padded to 32); softmax in C-frags;
// P -> LDS bf16 (chunk-XOR swizzle); PV: 10 mfma vs transposed V.
// ============================================================
__global__ __launch_bounds__(256) void attn_kernel(
    const bf16* __restrict__ qkv, const float* __restrict__ gab,
    bf16* __restrict__ ob)
{
  int bh = blockIdx.x;
  int b = bh >> 5, hh = bh & 31;
  __shared__ bf16 ql[SP_*32];
  __shared__ bf16 kl[SP_*32];
  __shared__ bf16 vt[32*KP_];
  __shared__ bf16 pl[4][16*KP_];
  int tid = threadIdx.x;
  int wv = tid >> 6, lane = tid & 63;
  const short8 z8 = (short8){0,0,0,0,0,0,0,0};

  // zero vt (incl. padding)
  for (int idx = tid; idx < 32*KP_/8; idx += 256)
    *(short8*)&vt[idx*8] = z8;
  // stage q/k rows (zero-padded), chunk-swizzled
  const bf16* qbase = qkv + (long)b*S_*2304 + hh*24;
  for (int u = tid; u < SP_*4; u += 256) {
    int row = u >> 2, c8 = u & 3;
    short8 qv = z8, kv = z8;
    if (row < S_ && c8 < 3) {
      qv = *(const short8*)(qbase + (long)row*2304 + c8*8);
      kv = *(const short8*)(qbase + (long)row*2304 + 768 + c8*8);
    }
    int cs = c8 ^ ((row >> 1) & 3);
    *(short8*)&ql[row*32 + cs*8] = qv;
    *(short8*)&kl[row*32 + cs*8] = kv;
  }
  __syncthreads();
  // stage v transposed: vt[c][kj]
  for (int u = tid; u < S_*24; u += 256) {
    int kj = u / 24, c = u % 24;
    bf16 val = qbase[(long)kj*2304 + 1536 + c];
    int ch = (kj >> 3) ^ ((c >> 1) & 3);
    vt[c*KP_ + ch*8 + (kj & 7)] = val;
  }
  __syncthreads();

  int l15 = lane & 15, l4 = lane >> 4;

  // hoist V B-frags: 5 k-chunks x 2 n-tiles
  short8 bvf[5][2];
#pragma unroll
  for (int kc = 0; kc < 5; ++kc)
#pragma unroll
    for (int ntc = 0; ntc < 2; ++ntc) {
      int col = ntc*16 + l15;
      int ch = (kc*4 + l4) ^ ((col >> 1) & 3);
      bvf[kc][ntc] = *(const short8*)&vt[col*KP_ + ch*8];
    }

  // zero own pl region once (covers kj padding 144..159)
  bf16* plw = pl[wv];
  for (int idx = lane; idx < 16*KP_/8; idx += 64)
    *(short8*)&plw[idx*8] = z8;

  const float* gb = gab + (long)(b*H_ + hh)*S_*S_;

  for (int mf = wv; mf < 9; mf += 4) {
    int qb0 = mf * 16;
    // Q A-frag
    int qrow = qb0 + l15;
    int qch = l4 ^ ((qrow >> 1) & 3);
    short8 aq = *(const short8*)&ql[qrow*32 + qch*8];
    // QK^T
    f32x4 sc[9];
#pragma unroll
    for (int nt = 0; nt < 9; ++nt) {
      int krow = nt*16 + l15;
      int kch = l4 ^ ((krow >> 1) & 3);
      short8 bk = *(const short8*)&kl[krow*32 + kch*8];
      sc[nt] = __builtin_amdgcn_mfma_f32_16x16x32_bf16(aq, bk, (f32x4){0,0,0,0}, 0, 0, 0);
    }
    // add gab + mask; row max
    float mx[4] = {-1e30f,-1e30f,-1e30f,-1e30f};
#pragma unroll
    for (int nt = 0; nt < 9; ++nt) {
      int kj = nt*16 + l15;
      int kjc = kj < S_ ? kj : 0;
#pragma unroll
      for (int i = 0; i < 4; ++i) {
        int q = qb0 + l4*4 + i;
        int qc = q < S_ ? q : 0;
        float v = sc[nt][i] + gb[(long)qc*S_ + kjc];
        if (kj >= S_) v = -1e30f;
        sc[nt][i] = v;
        mx[i] = fmaxf(mx[i], v);
      }
    }
#pragma unroll
    for (int i = 0; i < 4; ++i) {
      mx[i] = fmaxf(mx[i], __shfl_xor(mx[i], 1));
      mx[i] = fmaxf(mx[i], __shfl_xor(mx[i], 2));
      mx[i] = fmaxf(mx[i], __shfl_xor(mx[i], 4));
      mx[i] = fmaxf(mx[i], __shfl_xor(mx[i], 8));
    }
    float sum[4] = {0.f,0.f,0.f,0.f};
#pragma unroll
    for (int nt = 0; nt < 9; ++nt)
#pragma unroll
      for (int i = 0; i < 4; ++i) {
        float e = __expf(sc[nt][i] - mx[i]);
        sc[nt][i] = e;
        sum[i] += e;
      }
#pragma unroll
    for (int i = 0; i < 4; ++i) {
      sum[i] += __shfl_xor(sum[i], 1);
      sum[i] += __shfl_xor(sum[i], 2);
      sum[i] += __shfl_xor(sum[i], 4);
      sum[i] += __shfl_xor(sum[i], 8);
    }
    // write P (bf16) to own pl, swizzled
#pragma unroll
    for (int nt = 0; nt < 9; ++nt) {
      int kj = nt*16 + l15;
#pragma unroll
      for (int i = 0; i < 4; ++i) {
        int q = l4*4 + i;
        int ch = (kj >> 3) ^ ((q >> 1) & 3);
        plw[q*KP_ + ch*8 + (kj & 7)] = __float2bfloat16(sc[nt][i]);
      }
    }
    // PV (wave-local LDS, in-order: no barrier needed)
    f32x4 av[2] = {(f32x4){0,0,0,0}, (f32x4){0,0,0,0}};
#pragma unroll
    for (int kc = 0; kc < 5; ++kc) {
      int ch = (kc*4 + l4) ^ ((l15 >> 1) & 3);
      short8 ap = *(const short8*)&plw[l15*KP_ + ch*8];
#pragma unroll
      for (int ntc = 0; ntc < 2; ++ntc)
        av[ntc] = __builtin_amdgcn_mfma_f32_16x16x32_bf16(ap, bvf[kc][ntc], av[ntc], 0, 0, 0);
    }
    // epilogue
#pragma unroll
    for (int ntc = 0; ntc < 2; ++ntc) {
      int c = ntc*16 + l15;
      if (c < 24) {
#pragma unroll
        for (int i = 0; i < 4; ++i) {
          int q = qb0 + l4*4 + i;
          if (q < S_)
            ob[(long)(b*S_ + q)*768 + hh*24 + c] = __float2bfloat16(av[ntc][i] / sum[i]);
        }
      }
    }
  }
}

// ============================================================
// final: LN(h[b,0,:]) @ proj_w + proj_b -> out[b]
// ============================================================
__global__ __launch_bounds__(256) void final_kernel(
    const float* __restrict__ h, const float* __restrict__ fg,
    const float* __restrict__ fb, const float* __restrict__ pw,
    const float* __restrict__ pb, float* __restrict__ out)
{
  int b = blockIdx.x;
  int tid = threadIdx.x;
  const float* xr = h + (long)b * S_ * HID_;
  float x0 = xr[tid], x1 = xr[tid + 256], x2 = xr[tid + 512];
  float s = x0 + x1 + x2;
  float ss = x0*x0 + x1*x1 + x2*x2;
  for (int off = 32; off > 0; off >>= 1) {
    s  += __shfl_xor(s, off);
    ss += __shfl_xor(ss, off);
  }
  __shared__ float rs[4], rss[4], rd[4];
  int w = tid / 64;
  if ((tid & 63) == 0) { rs[w] = s; rss[w] = ss; }
  __syncthreads();
  s  = rs[0] + rs[1] + rs[2] + rs[3];
  ss = rss[0] + rss[1] + rss[2] + rss[3];
  float mean = s * (1.0f/768.0f);
  float var  = ss * (1.0f/768.0f) - mean*mean;
  float rstd = rsqrtf(var + 1e-5f);
  float d0 = ((x0 - mean)*rstd*fg[tid]       + fb[tid])       * pw[tid];
  float d1 = ((x1 - mean)*rstd*fg[tid + 256] + fb[tid + 256]) * pw[tid + 256];
  float d2 = ((x2 - mean)*rstd*fg[tid + 512] + fb[tid + 512]) * pw[tid + 512];
  float pd = d0 + d1 + d2;
  for (int off = 32; off > 0; off >>= 1) pd += __shfl_xor(pd, off);
  if ((tid & 63) == 0) rd[w] = pd;
  __syncthreads();
  if (tid == 0) out[b] = rd[0] + rd[1] + rd[2] + rd[3] + pb[0];
}

// ============================================================
extern "C" void kernel_launch(void* const* d_in, const int* in_sizes, int n_in,
                              void* d_out, int out_size, void* d_ws, size_t ws_size,
                              hipStream_t stream)
{
  const float* attn_bias   = (const float*)d_in[0];
  const int*   spatial_pos = (const int*)d_in[1];
  const int*   x           = (const int*)d_in[2];
  const int*   in_degree   = (const int*)d_in[3];
  const int*   out_degree  = (const int*)d_in[4];
  const int*   edge_input  = (const int*)d_in[5];
  const float* atom_emb    = (const float*)d_in[6];
  const float* edge_emb    = (const float*)d_in[7];
  const float* edge_dis    = (const float*)d_in[8];
  const float* spatial_emb = (const float*)d_in[9];
  const float* in_deg_emb  = (const float*)d_in[10];
  const float* out_deg_emb = (const float*)d_in[11];
  const float* graph_token = (const float*)d_in[12];
  const float* gt_vd       = (const float*)d_in[13];
  const float* ln1_g = (const float*)d_in[14];
  const float* ln1_b = (const float*)d_in[15];
  const float* wq = (const float*)d_in[16];
  const float* bq = (const float*)d_in[17];
  const float* wk = (const float*)d_in[18];
  const float* bk = (const float*)d_in[19];
  const float* wv = (const float*)d_in[20];
  const float* bv = (const float*)d_in[21];
  const float* wo = (const float*)d_in[22];
  const float* bo = (const float*)d_in[23];
  const float* ln2_g = (const float*)d_in[24];
  const float* ln2_b = (const float*)d_in[25];
  const float* w1 = (const float*)d_in[26];
  const float* b1 = (const float*)d_in[27];
  const float* w2 = (const float*)d_in[28];
  const float* b2 = (const float*)d_in[29];
  const float* final_g = (const float*)d_in[30];
  const float* final_b = (const float*)d_in[31];
  const float* proj_w  = (const float*)d_in[32];
  const float* proj_b  = (const float*)d_in[33];

  float* out = (float*)d_out;

  const float scale = 0.20412414523193154f;  // 24^-0.5
  const long GAB_N = (long)B_*H_*S_*S_;      // 8,520,192

  char* p = (char*)d_ws;
  float* gab  = (float*)p;  p += GAB_N*4;
  float* h    = (float*)p;  p += (long)M_*HID_*4;
  bf16*  y    = (bf16*)p;   p += (long)M_*HID_*2;
  bf16*  qkv  = (bf16*)p;   // ffn aliases qkv+ob
  bf16*  ffn  = qkv;
  p += (long)M_*2304*2;
  bf16*  ob   = (bf16*)p;   p += (long)M_*HID_*2;
  float* Ftab = (float*)p;  p += (long)5*1537*32*4;
  float* bqkv = (float*)p;  p += (long)L_*2304*4;
  bf16*  wbuf = (bf16*)p;

  // per-layer bf16 weight block (elements)
  const size_t WQKV_E = (size_t)2304*768;
  const size_t WO_E   = (size_t)768*768;
  const size_t W1_E   = (size_t)3072*768;
  const size_t W2_E   = (size_t)768*3072;
  const size_t WL_E   = WQKV_E + WO_E + W1_E + W2_E;   // 7,077,888
  size_t base_bytes = (size_t)(p - (char*)d_ws);
  bool full = ws_size >= base_bytes + (size_t)L_ * WL_E * 2;

  // ---- setup ----
  gab_base_kernel<<<(int)((GAB_N + 255)/256), 256, 0, stream>>>(
      attn_bias, spatial_pos, spatial_emb, gt_vd, gab);
  ftab_kernel<<<(5*1537 + 7)/8, 256, 0, stream>>>(edge_emb, edge_dis, Ftab);
  edge_kernel<<<B_*N_, 256, 0, stream>>>(edge_input, Ftab, spatial_pos, gab);
  nodefeat_kernel<<<(M_*HID_ + 255)/256, 256, 0, stream>>>(
      x, in_degree, out_degree, atom_emb, in_deg_emb, out_deg_emb, graph_token, h);
  biasqkv_kernel<<<(L_*2304 + 255)/256, 256, 0, stream>>>(bq, bk, bv, bqkv, scale);

  dim3 gQKV(2304/128, (M_ + 127)/128);
  dim3 gO  (768/128,  (M_ + 127)/128);
  dim3 gF1 (3072/128, (M_ + 127)/128);
  dim3 cQKV(768/32, 768/32, 3);
  dim3 cO  (768/32, 768/32);
  dim3 cW1 (3072/32, 768/32);
  dim3 cW2 (768/32, 3072/32);

  auto wptr = [&](int l) { return wbuf + (full ? (size_t)l : 0) * WL_E; };
  auto conv = [&](int l) {
    bf16* W = wptr(l);
    qkvconv_kernel<<<cQKV, 256, 0, stream>>>(
        wq + (size_t)l*HID_*HID_, wk + (size_t)l*HID_*HID_, wv + (size_t)l*HID_*HID_,
        W, scale);
    wconv_kernel<<<cO, 256, 0, stream>>>(wo + (size_t)l*HID_*HID_, W + WQKV_E, 768, 768, 1.0f);
    wconv_kernel<<<cW1, 256, 0, stream>>>(w1 + (size_t)l*HID_*FFN_, W + WQKV_E + WO_E, 768, 3072, 1.0f);
    wconv_kernel<<<cW2, 256, 0, stream>>>(w2 + (size_t)l*FFN_*HID_, W + WQKV_E + WO_E + W1_E, 3072, 768, 1.0f);
  };

  if (full)
    for (int l = 0; l < L_; ++l) conv(l);

  for (int l = 0; l < L_; ++l) {
    if (!full) conv(l);
    bf16* W = wptr(l);
    bf16* Wqkvt = W;
    bf16* Wot   = W + WQKV_E;
    bf16* W1t   = W + WQKV_E + WO_E;
    bf16* W2t   = W + WQKV_E + WO_E + W1_E;

    ln_kernel<<<M_, 256, 0, stream>>>(h, ln1_g + l*HID_, ln1_b + l*HID_, y);
    mfma_gemm_kernel<<<gQKV, 256, 0, stream>>>(
        y, Wqkvt, bqkv + l*2304, nullptr, qkv, M_, 2304, 768, 0);
    attn_kernel<<<B_*H_, 256, 0, stream>>>(qkv, gab, ob);
    mfma_gemm_kernel<<<gO, 256, 0, stream>>>(
        ob, Wot, bo + l*HID_, h, h, M_, 768, 768, 2);
    ln_kernel<<<M_, 256, 0, stream>>>(h, ln2_g + l*HID_, ln2_b + l*HID_, y);
    mfma_gemm_kernel<<<gF1, 256, 0, stream>>>(
        y, W1t, b1 + l*FFN_, nullptr, ffn, M_, 3072, 768, 1);
    mfma_gemm_kernel<<<gO, 256, 0, stream>>>(
        ffn, W2t, b2 + l*HID_, h, h, M_, 768, 3072, 2);
  }

  final_kernel<<<B_, 256, 0, stream>>>(h, final_g, final_b, proj_w, proj_b, out);
}

// Round 4
// 2492.729 us; speedup vs baseline: 7.1911x; 1.2328x over previous
//
#include <hip/hip_runtime.h>
#include <hip/hip_bf16.h>
#include <math.h>

#define B_ 16
#define N_ 128
#define S_ 129
#define HID_ 768
#define H_ 32
#define D_ 24
#define FFN_ 3072
#define L_ 12
#define M_ (B_*S_)   // 2064
#define SP_ 144      // padded S for q/k rows (9 x 16)
#define KP_ 160      // padded kj for P rows / vt cols (5 x 32)

typedef __attribute__((ext_vector_type(8))) short short8;
typedef __attribute__((ext_vector_type(4))) float f32x4;
typedef __hip_bfloat16 bf16;

__device__ __forceinline__ void gload_lds16(const void* g, void* l) {
  __builtin_amdgcn_global_load_lds(
      (const __attribute__((address_space(1))) void*)g,
      (__attribute__((address_space(3))) void*)l, 16, 0, 0);
}

// ============================================================
// gab base: gab[b,hh,qi,kj] = 2*ab + spatial(qi>0,kj>0) + t(qi==0||kj==0)
// ============================================================
__global__ __launch_bounds__(256) void gab_base_kernel(
    const float* __restrict__ ab, const int* __restrict__ spos,
    const float* __restrict__ spemb, const float* __restrict__ gtvd,
    float* __restrict__ gab)
{
  int idx = blockIdx.x * 256 + threadIdx.x;
  if (idx >= B_*H_*S_*S_) return;
  int kj = idx % S_;
  int qi = (idx / S_) % S_;
  int hh = (idx / (S_*S_)) % H_;
  int b  = idx / (S_*S_*H_);
  float v = 2.0f * ab[(b*S_ + qi)*S_ + kj];
  if (qi > 0 && kj > 0)
    v += spemb[spos[(b*N_ + (qi-1))*N_ + (kj-1)]*H_ + hh];
  if (qi == 0 || kj == 0) v += gtvd[hh];
  gab[idx] = v;
}

// ============================================================
// F table: F[d][idx][hh] = (1/3) * sum_hp eemb[idx][hp] * edis[d][hp][hh]
// ============================================================
__global__ __launch_bounds__(256) void ftab_kernel(
    const float* __restrict__ eemb, const float* __restrict__ edis,
    float* __restrict__ F)
{
  __shared__ float em[8][32];
  int tid = threadIdx.x;
  int jl = tid >> 5, hh = tid & 31;
  int p = blockIdx.x * 8 + jl;
  bool valid = p < 5*1537;
  int d = valid ? p / 1537 : 0;
  int idx = valid ? p % 1537 : 0;
  em[jl][hh] = eemb[idx*32 + hh];   // wave-local write/read, no barrier
  float acc = 0.f;
#pragma unroll
  for (int hp = 0; hp < 32; ++hp)
    acc += em[jl][hp] * edis[d*1024 + hp*32 + hh];
  if (valid) F[(long)p*32 + hh] = acc * (1.0f/3.0f);
}

// ============================================================
// edge encoding: block = (b,i) row; 15 F-gathers + adds per cell;
// coalesced gab RMW via LDS transpose
// ============================================================
__global__ __launch_bounds__(256) void edge_kernel(
    const int* __restrict__ eidx, const float* __restrict__ F,
    const int* __restrict__ spos, float* __restrict__ gab)
{
  __shared__ float outj[128][33];
  int tid = threadIdx.x;
  int jl = tid >> 5, hh = tid & 31;
  int bi = blockIdx.x;
  int b = bi >> 7, i = bi & 127;
  for (int ch = 0; ch < 16; ++ch) {
    int j = ch*8 + jl;
    const int* er = eidx + ((long)((b*N_ + i)*N_ + j)) * 15;
    float acc = 0.f;
#pragma unroll
    for (int t = 0; t < 15; ++t) {
      int d = t / 3;
      acc += F[((long)(d*1537 + er[t]))*32 + hh];
    }
    int sp0 = spos[(b*N_ + i)*N_ + j];
    int sp = (sp0 == 0) ? 1 : sp0;
    if (sp > 1) sp -= 1;
    if (sp > 5) sp = 5;
    outj[j][hh] = acc / (float)sp;
  }
  __syncthreads();
  for (int it = 0; it < 16; ++it) {
    int r = it*2 + (tid >> 7);
    int c = tid & 127;
    long g = ((long)(b*H_ + r)*S_ + (i+1))*S_ + 1 + c;
    gab[g] += outj[c][r];
  }
}

// ============================================================
// node features -> h (B,S,HID) fp32
// ============================================================
__global__ __launch_bounds__(256) void nodefeat_kernel(
    const int* __restrict__ x, const int* __restrict__ indeg,
    const int* __restrict__ outdeg, const float* __restrict__ atom_emb,
    const float* __restrict__ in_emb, const float* __restrict__ out_emb,
    const float* __restrict__ gtok, float* __restrict__ h)
{
  int idx = blockIdx.x * 256 + threadIdx.x;
  if (idx >= M_*HID_) return;
  int c = idx % HID_;
  int s = (idx / HID_) % S_;
  int b = idx / (HID_*S_);
  float v;
  if (s == 0) {
    v = gtok[c];
  } else {
    int n = s - 1;
    v = in_emb[indeg[b*N_ + n]*HID_ + c] + out_emb[outdeg[b*N_ + n]*HID_ + c];
    const int* xr = x + (b*N_ + n)*9;
#pragma unroll
    for (int e = 0; e < 9; ++e) v += atom_emb[(long)xr[e]*HID_ + c];
  }
  h[idx] = v;
}

// ============================================================
// LayerNorm (768) fp32 in -> bf16 out
// ============================================================
__global__ __launch_bounds__(256) void ln_kernel(
    const float* __restrict__ in, const float* __restrict__ g,
    const float* __restrict__ bta, bf16* __restrict__ out)
{
  int row = blockIdx.x;
  int tid = threadIdx.x;
  const float* xr = in + (long)row * HID_;
  float x0 = xr[tid], x1 = xr[tid + 256], x2 = xr[tid + 512];
  float s = x0 + x1 + x2;
  float ss = x0*x0 + x1*x1 + x2*x2;
  for (int off = 32; off > 0; off >>= 1) {
    s  += __shfl_xor(s, off);
    ss += __shfl_xor(ss, off);
  }
  __shared__ float rs[4], rss[4];
  int w = tid / 64;
  if ((tid & 63) == 0) { rs[w] = s; rss[w] = ss; }
  __syncthreads();
  s  = rs[0] + rs[1] + rs[2] + rs[3];
  ss = rss[0] + rss[1] + rss[2] + rss[3];
  float mean = s * (1.0f/768.0f);
  float var  = ss * (1.0f/768.0f) - mean*mean;
  float rstd = rsqrtf(var + 1e-5f);
  bf16* orow = out + (long)row * HID_;
  orow[tid]       = __float2bfloat16((x0 - mean)*rstd*g[tid]       + bta[tid]);
  orow[tid + 256] = __float2bfloat16((x1 - mean)*rstd*g[tid + 256] + bta[tid + 256]);
  orow[tid + 512] = __float2bfloat16((x2 - mean)*rstd*g[tid + 512] + bta[tid + 512]);
}

// ============================================================
// weight convert: W[K][N] fp32 -> Out[N][K] bf16 (*scale)
// ============================================================
__global__ __launch_bounds__(256) void wconv_kernel(
    const float* __restrict__ W, bf16* __restrict__ Out,
    int K, int N, float scale)
{
  __shared__ float tile[32][33];
  int bx = blockIdx.x * 32;
  int by = blockIdx.y * 32;
  int tx = threadIdx.x & 31, ty = threadIdx.x >> 5;
#pragma unroll
  for (int r = 0; r < 32; r += 8)
    tile[ty + r][tx] = W[(long)(by + ty + r)*N + bx + tx];
  __syncthreads();
#pragma unroll
  for (int r = 0; r < 32; r += 8)
    Out[(long)(bx + ty + r)*K + by + tx] = __float2bfloat16(tile[tx][ty + r] * scale);
}

__global__ __launch_bounds__(256) void qkvconv_kernel(
    const float* __restrict__ wq, const float* __restrict__ wk,
    const float* __restrict__ wv, bf16* __restrict__ Out, float scale)
{
  const float* W = blockIdx.z == 0 ? wq : blockIdx.z == 1 ? wk : wv;
  float sc = blockIdx.z == 0 ? scale : 1.0f;
  __shared__ float tile[32][33];
  int bx = blockIdx.x * 32;
  int by = blockIdx.y * 32;
  int tx = threadIdx.x & 31, ty = threadIdx.x >> 5;
#pragma unroll
  for (int r = 0; r < 32; r += 8)
    tile[ty + r][tx] = W[(long)(by + ty + r)*768 + bx + tx];
  __syncthreads();
  bf16* O = Out + (long)blockIdx.z * 768 * 768;
#pragma unroll
  for (int r = 0; r < 32; r += 8)
    O[(long)(bx + ty + r)*768 + by + tx] = __float2bfloat16(tile[tx][ty + r] * sc);
}

__global__ __launch_bounds__(256) void biasqkv_kernel(
    const float* __restrict__ bq, const float* __restrict__ bk,
    const float* __restrict__ bv, float* __restrict__ bqkv, float scale)
{
  int idx = blockIdx.x * 256 + threadIdx.x;
  if (idx >= L_*2304) return;
  int l = idx / 2304, n = idx % 2304;
  int p = n / 768, nn = n % 768;
  float v = (p == 0) ? bq[l*768 + nn]*scale : (p == 1) ? bk[l*768 + nn] : bv[l*768 + nn];
  bqkv[idx] = v;
}

// ============================================================
// bf16 MFMA GEMM, 2-phase double-buffered (T3 minimum recipe):
// issue STAGE(t+1) before compute(t); ONE barrier per K-step
// (compiler emits vmcnt(0)+lgkmcnt(0) at that barrier = per-tile drain,
// load latency hidden under ds_read+MFMA of current tile).
// BM=128, BN template (128 or 64), BK=32, 4 waves.
// mode 0: bf16 out; 1: gelu->bf16; 2: +resid->fp32
// ============================================================
template<int BN_T>
__device__ __forceinline__ void stage_tiles(
    const bf16* __restrict__ A, const bf16* __restrict__ Wt,
    bf16* Als, bf16* Bls, int bm, int bn, int k0, int M, int K, int tid)
{
#pragma unroll
  for (int it = 0; it < 2; ++it) {
    int c = it*256 + tid;
    int row = c >> 2, kc = c & 3;
    int kcs = kc ^ ((row >> 1) & 3);
    int grow = bm + row; if (grow >= M) grow = M - 1;
    gload_lds16(A + (long)grow*K + k0 + kcs*8, Als + (it*256 + (tid & ~63))*8);
  }
  if constexpr (BN_T == 128) {
#pragma unroll
    for (int it = 0; it < 2; ++it) {
      int c = it*256 + tid;
      int row = c >> 2, kc = c & 3;
      int kcs = kc ^ ((row >> 1) & 3);
      gload_lds16(Wt + (long)(bn + row)*K + k0 + kcs*8, Bls + (it*256 + (tid & ~63))*8);
    }
  } else {
    int row = tid >> 2, kc = tid & 3;
    int kcs = kc ^ ((row >> 1) & 3);
    gload_lds16(Wt + (long)(bn + row)*K + k0 + kcs*8, Bls + (tid & ~63)*8);
  }
}

template<int BN_T>
__global__ __launch_bounds__(256) void mfma_gemm_t(
    const bf16* __restrict__ A, const bf16* __restrict__ Wt,
    const float* __restrict__ bias, const float* __restrict__ resid,
    void* __restrict__ Cout, int M, int N, int K, int mode)
{
  constexpr int NF  = BN_T / 32;     // n-frags per wave: 128->4, 64->2
  constexpr int ASZ = 128*32;
  constexpr int BSZ = BN_T*32;
  __shared__ bf16 Als[2*ASZ];
  __shared__ bf16 Bls[2*BSZ];
  int tid = threadIdx.x;
  int wid = tid >> 6, lane = tid & 63;
  int bm = blockIdx.y * 128, bn = blockIdx.x * BN_T;
  int wr = wid >> 1, wc = wid & 1;
  int lr = lane & 15, kg = lane >> 4;

  int aoff[4], boff[NF];
#pragma unroll
  for (int m = 0; m < 4; ++m) {
    int row = wr*64 + m*16 + lr;
    aoff[m] = (row*4 + (kg ^ ((row>>1)&3)))*8;
  }
#pragma unroll
  for (int n = 0; n < NF; ++n) {
    int col = wc*(BN_T/2) + n*16 + lr;
    boff[n] = (col*4 + (kg ^ ((col>>1)&3)))*8;
  }

  f32x4 acc[4][NF];
#pragma unroll
  for (int m = 0; m < 4; ++m)
#pragma unroll
    for (int n = 0; n < NF; ++n)
      acc[m][n] = (f32x4){0.0f, 0.0f, 0.0f, 0.0f};

  int nt = K >> 5;
  stage_tiles<BN_T>(A, Wt, Als, Bls, bm, bn, 0, M, K, tid);
  __syncthreads();
  for (int t = 0; t < nt; ++t) {
    int cur = t & 1;
    bf16* Acur = Als + cur*ASZ;
    bf16* Bcur = Bls + cur*BSZ;
    if (t + 1 < nt)
      stage_tiles<BN_T>(A, Wt, Als + (cur^1)*ASZ, Bls + (cur^1)*BSZ,
                        bm, bn, (t+1)*32, M, K, tid);
    short8 av[4], bv4[NF];
#pragma unroll
    for (int m = 0; m < 4; ++m) av[m] = *(const short8*)(Acur + aoff[m]);
#pragma unroll
    for (int n = 0; n < NF; ++n) bv4[n] = *(const short8*)(Bcur + boff[n]);
#pragma unroll
    for (int m = 0; m < 4; ++m)
#pragma unroll
      for (int n = 0; n < NF; ++n)
        acc[m][n] = __builtin_amdgcn_mfma_f32_16x16x32_bf16(av[m], bv4[n], acc[m][n], 0, 0, 0);
    __syncthreads();
  }

#pragma unroll
  for (int n = 0; n < NF; ++n) {
    int col = bn + wc*(BN_T/2) + n*16 + lr;
    float bcol = bias[col];
#pragma unroll
    for (int m = 0; m < 4; ++m) {
      f32x4 a = acc[m][n];
#pragma unroll
      for (int i = 0; i < 4; ++i) {
        int row = bm + wr*64 + m*16 + kg*4 + i;
        if (row < M) {
          float v = a[i] + bcol;
          if (mode == 1) v = 0.5f * v * (1.0f + erff(v * 0.70710678118654752f));
          if (mode == 2)
            ((float*)Cout)[(long)row*N + col] = v + resid[(long)row*N + col];
          else
            ((bf16*)Cout)[(long)row*N + col] = __float2bfloat16(v);
        }
      }
    }
  }
}

// ============================================================
// MFMA fused attention per (b, head) — unchanged (verified round 3)
// ============================================================
__global__ __launch_bounds__(256) void attn_kernel(
    const bf16* __restrict__ qkv, const float* __restrict__ gab,
    bf16* __restrict__ ob)
{
  int bh = blockIdx.x;
  int b = bh >> 5, hh = bh & 31;
  __shared__ bf16 ql[SP_*32];
  __shared__ bf16 kl[SP_*32];
  __shared__ bf16 vt[32*KP_];
  __shared__ bf16 pl[4][16*KP_];
  int tid = threadIdx.x;
  int wv = tid >> 6, lane = tid & 63;
  const short8 z8 = (short8){0,0,0,0,0,0,0,0};

  for (int idx = tid; idx < 32*KP_/8; idx += 256)
    *(short8*)&vt[idx*8] = z8;
  const bf16* qbase = qkv + (long)b*S_*2304 + hh*24;
  for (int u = tid; u < SP_*4; u += 256) {
    int row = u >> 2, c8 = u & 3;
    short8 qv = z8, kv = z8;
    if (row < S_ && c8 < 3) {
      qv = *(const short8*)(qbase + (long)row*2304 + c8*8);
      kv = *(const short8*)(qbase + (long)row*2304 + 768 + c8*8);
    }
    int cs = c8 ^ ((row >> 1) & 3);
    *(short8*)&ql[row*32 + cs*8] = qv;
    *(short8*)&kl[row*32 + cs*8] = kv;
  }
  __syncthreads();
  for (int u = tid; u < S_*24; u += 256) {
    int kj = u / 24, c = u % 24;
    bf16 val = qbase[(long)kj*2304 + 1536 + c];
    int ch = (kj >> 3) ^ ((c >> 1) & 3);
    vt[c*KP_ + ch*8 + (kj & 7)] = val;
  }
  __syncthreads();

  int l15 = lane & 15, l4 = lane >> 4;

  short8 bvf[5][2];
#pragma unroll
  for (int kc = 0; kc < 5; ++kc)
#pragma unroll
    for (int ntc = 0; ntc < 2; ++ntc) {
      int col = ntc*16 + l15;
      int ch = (kc*4 + l4) ^ ((col >> 1) & 3);
      bvf[kc][ntc] = *(const short8*)&vt[col*KP_ + ch*8];
    }

  bf16* plw = pl[wv];
  for (int idx = lane; idx < 16*KP_/8; idx += 64)
    *(short8*)&plw[idx*8] = z8;

  const float* gb = gab + (long)(b*H_ + hh)*S_*S_;

  for (int mf = wv; mf < 9; mf += 4) {
    int qb0 = mf * 16;
    int qrow = qb0 + l15;
    int qch = l4 ^ ((qrow >> 1) & 3);
    short8 aq = *(const short8*)&ql[qrow*32 + qch*8];
    f32x4 sc[9];
#pragma unroll
    for (int nt = 0; nt < 9; ++nt) {
      int krow = nt*16 + l15;
      int kch = l4 ^ ((krow >> 1) & 3);
      short8 bk = *(const short8*)&kl[krow*32 + kch*8];
      sc[nt] = __builtin_amdgcn_mfma_f32_16x16x32_bf16(aq, bk, (f32x4){0,0,0,0}, 0, 0, 0);
    }
    float mx[4] = {-1e30f,-1e30f,-1e30f,-1e30f};
#pragma unroll
    for (int nt = 0; nt < 9; ++nt) {
      int kj = nt*16 + l15;
      int kjc = kj < S_ ? kj : 0;
#pragma unroll
      for (int i = 0; i < 4; ++i) {
        int q = qb0 + l4*4 + i;
        int qc = q < S_ ? q : 0;
        float v = sc[nt][i] + gb[(long)qc*S_ + kjc];
        if (kj >= S_) v = -1e30f;
        sc[nt][i] = v;
        mx[i] = fmaxf(mx[i], v);
      }
    }
#pragma unroll
    for (int i = 0; i < 4; ++i) {
      mx[i] = fmaxf(mx[i], __shfl_xor(mx[i], 1));
      mx[i] = fmaxf(mx[i], __shfl_xor(mx[i], 2));
      mx[i] = fmaxf(mx[i], __shfl_xor(mx[i], 4));
      mx[i] = fmaxf(mx[i], __shfl_xor(mx[i], 8));
    }
    float sum[4] = {0.f,0.f,0.f,0.f};
#pragma unroll
    for (int nt = 0; nt < 9; ++nt)
#pragma unroll
      for (int i = 0; i < 4; ++i) {
        float e = __expf(sc[nt][i] - mx[i]);
        sc[nt][i] = e;
        sum[i] += e;
      }
#pragma unroll
    for (int i = 0; i < 4; ++i) {
      sum[i] += __shfl_xor(sum[i], 1);
      sum[i] += __shfl_xor(sum[i], 2);
      sum[i] += __shfl_xor(sum[i], 4);
      sum[i] += __shfl_xor(sum[i], 8);
    }
#pragma unroll
    for (int nt = 0; nt < 9; ++nt) {
      int kj = nt*16 + l15;
#pragma unroll
      for (int i = 0; i < 4; ++i) {
        int q = l4*4 + i;
        int ch = (kj >> 3) ^ ((q >> 1) & 3);
        plw[q*KP_ + ch*8 + (kj & 7)] = __float2bfloat16(sc[nt][i]);
      }
    }
    f32x4 av[2] = {(f32x4){0,0,0,0}, (f32x4){0,0,0,0}};
#pragma unroll
    for (int kc = 0; kc < 5; ++kc) {
      int ch = (kc*4 + l4) ^ ((l15 >> 1) & 3);
      short8 ap = *(const short8*)&plw[l15*KP_ + ch*8];
#pragma unroll
      for (int ntc = 0; ntc < 2; ++ntc)
        av[ntc] = __builtin_amdgcn_mfma_f32_16x16x32_bf16(ap, bvf[kc][ntc], av[ntc], 0, 0, 0);
    }
#pragma unroll
    for (int ntc = 0; ntc < 2; ++ntc) {
      int c = ntc*16 + l15;
      if (c < 24) {
#pragma unroll
        for (int i = 0; i < 4; ++i) {
          int q = qb0 + l4*4 + i;
          if (q < S_)
            ob[(long)(b*S_ + q)*768 + hh*24 + c] = __float2bfloat16(av[ntc][i] / sum[i]);
        }
      }
    }
  }
}

// ============================================================
// final: LN(h[b,0,:]) @ proj_w + proj_b -> out[b]
// ============================================================
__global__ __launch_bounds__(256) void final_kernel(
    const float* __restrict__ h, const float* __restrict__ fg,
    const float* __restrict__ fb, const float* __restrict__ pw,
    const float* __restrict__ pb, float* __restrict__ out)
{
  int b = blockIdx.x;
  int tid = threadIdx.x;
  const float* xr = h + (long)b * S_ * HID_;
  float x0 = xr[tid], x1 = xr[tid + 256], x2 = xr[tid + 512];
  float s = x0 + x1 + x2;
  float ss = x0*x0 + x1*x1 + x2*x2;
  for (int off = 32; off > 0; off >>= 1) {
    s  += __shfl_xor(s, off);
    ss += __shfl_xor(ss, off);
  }
  __shared__ float rs[4], rss[4], rd[4];
  int w = tid / 64;
  if ((tid & 63) == 0) { rs[w] = s; rss[w] = ss; }
  __syncthreads();
  s  = rs[0] + rs[1] + rs[2] + rs[3];
  ss = rss[0] + rss[1] + rss[2] + rss[3];
  float mean = s * (1.0f/768.0f);
  float var  = ss * (1.0f/768.0f) - mean*mean;
  float rstd = rsqrtf(var + 1e-5f);
  float d0 = ((x0 - mean)*rstd*fg[tid]       + fb[tid])       * pw[tid];
  float d1 = ((x1 - mean)*rstd*fg[tid + 256] + fb[tid + 256]) * pw[tid + 256];
  float d2 = ((x2 - mean)*rstd*fg[tid + 512] + fb[tid + 512]) * pw[tid + 512];
  float pd = d0 + d1 + d2;
  for (int off = 32; off > 0; off >>= 1) pd += __shfl_xor(pd, off);
  if ((tid & 63) == 0) rd[w] = pd;
  __syncthreads();
  if (tid == 0) out[b] = rd[0] + rd[1] + rd[2] + rd[3] + pb[0];
}

// ============================================================
extern "C" void kernel_launch(void* const* d_in, const int* in_sizes, int n_in,
                              void* d_out, int out_size, void* d_ws, size_t ws_size,
                              hipStream_t stream)
{
  const float* attn_bias   = (const float*)d_in[0];
  const int*   spatial_pos = (const int*)d_in[1];
  const int*   x           = (const int*)d_in[2];
  const int*   in_degree   = (const int*)d_in[3];
  const int*   out_degree  = (const int*)d_in[4];
  const int*   edge_input  = (const int*)d_in[5];
  const float* atom_emb    = (const float*)d_in[6];
  const float* edge_emb    = (const float*)d_in[7];
  const float* edge_dis    = (const float*)d_in[8];
  const float* spatial_emb = (const float*)d_in[9];
  const float* in_deg_emb  = (const float*)d_in[10];
  const float* out_deg_emb = (const float*)d_in[11];
  const float* graph_token = (const float*)d_in[12];
  const float* gt_vd       = (const float*)d_in[13];
  const float* ln1_g = (const float*)d_in[14];
  const float* ln1_b = (const float*)d_in[15];
  const float* wq = (const float*)d_in[16];
  const float* bq = (const float*)d_in[17];
  const float* wk = (const float*)d_in[18];
  const float* bk = (const float*)d_in[19];
  const float* wv = (const float*)d_in[20];
  const float* bv = (const float*)d_in[21];
  const float* wo = (const float*)d_in[22];
  const float* bo = (const float*)d_in[23];
  const float* ln2_g = (const float*)d_in[24];
  const float* ln2_b = (const float*)d_in[25];
  const float* w1 = (const float*)d_in[26];
  const float* b1 = (const float*)d_in[27];
  const float* w2 = (const float*)d_in[28];
  const float* b2 = (const float*)d_in[29];
  const float* final_g = (const float*)d_in[30];
  const float* final_b = (const float*)d_in[31];
  const float* proj_w  = (const float*)d_in[32];
  const float* proj_b  = (const float*)d_in[33];

  float* out = (float*)d_out;

  const float scale = 0.20412414523193154f;  // 24^-0.5
  const long GAB_N = (long)B_*H_*S_*S_;      // 8,520,192

  char* p = (char*)d_ws;
  float* gab  = (float*)p;  p += GAB_N*4;
  float* h    = (float*)p;  p += (long)M_*HID_*4;
  bf16*  y    = (bf16*)p;   p += (long)M_*HID_*2;
  bf16*  qkv  = (bf16*)p;   // ffn aliases qkv+ob
  bf16*  ffn  = qkv;
  p += (long)M_*2304*2;
  bf16*  ob   = (bf16*)p;   p += (long)M_*HID_*2;
  float* Ftab = (float*)p;  p += (long)5*1537*32*4;
  float* bqkv = (float*)p;  p += (long)L_*2304*4;
  bf16*  wbuf = (bf16*)p;

  const size_t WQKV_E = (size_t)2304*768;
  const size_t WO_E   = (size_t)768*768;
  const size_t W1_E   = (size_t)3072*768;
  const size_t W2_E   = (size_t)768*3072;
  const size_t WL_E   = WQKV_E + WO_E + W1_E + W2_E;   // 7,077,888
  size_t base_bytes = (size_t)(p - (char*)d_ws);
  bool full = ws_size >= base_bytes + (size_t)L_ * WL_E * 2;

  // ---- setup ----
  gab_base_kernel<<<(int)((GAB_N + 255)/256), 256, 0, stream>>>(
      attn_bias, spatial_pos, spatial_emb, gt_vd, gab);
  ftab_kernel<<<(5*1537 + 7)/8, 256, 0, stream>>>(edge_emb, edge_dis, Ftab);
  edge_kernel<<<B_*N_, 256, 0, stream>>>(edge_input, Ftab, spatial_pos, gab);
  nodefeat_kernel<<<(M_*HID_ + 255)/256, 256, 0, stream>>>(
      x, in_degree, out_degree, atom_emb, in_deg_emb, out_deg_emb, graph_token, h);
  biasqkv_kernel<<<(L_*2304 + 255)/256, 256, 0, stream>>>(bq, bk, bv, bqkv, scale);

  dim3 gQKV(2304/128, (M_ + 127)/128);   // 18 x 17
  dim3 gO64(768/64,   (M_ + 127)/128);   // 12 x 17
  dim3 gF1 (3072/128, (M_ + 127)/128);   // 24 x 17
  dim3 cQKV(768/32, 768/32, 3);
  dim3 cO  (768/32, 768/32);
  dim3 cW1 (3072/32, 768/32);
  dim3 cW2 (768/32, 3072/32);

  auto wptr = [&](int l) { return wbuf + (full ? (size_t)l : 0) * WL_E; };
  auto conv = [&](int l) {
    bf16* W = wptr(l);
    qkvconv_kernel<<<cQKV, 256, 0, stream>>>(
        wq + (size_t)l*HID_*HID_, wk + (size_t)l*HID_*HID_, wv + (size_t)l*HID_*HID_,
        W, scale);
    wconv_kernel<<<cO, 256, 0, stream>>>(wo + (size_t)l*HID_*HID_, W + WQKV_E, 768, 768, 1.0f);
    wconv_kernel<<<cW1, 256, 0, stream>>>(w1 + (size_t)l*HID_*FFN_, W + WQKV_E + WO_E, 768, 3072, 1.0f);
    wconv_kernel<<<cW2, 256, 0, stream>>>(w2 + (size_t)l*FFN_*HID_, W + WQKV_E + WO_E + W1_E, 3072, 768, 1.0f);
  };

  if (full)
    for (int l = 0; l < L_; ++l) conv(l);

  for (int l = 0; l < L_; ++l) {
    if (!full) conv(l);
    bf16* W = wptr(l);
    bf16* Wqkvt = W;
    bf16* Wot   = W + WQKV_E;
    bf16* W1t   = W + WQKV_E + WO_E;
    bf16* W2t   = W + WQKV_E + WO_E + W1_E;

    ln_kernel<<<M_, 256, 0, stream>>>(h, ln1_g + l*HID_, ln1_b + l*HID_, y);
    mfma_gemm_t<128><<<gQKV, 256, 0, stream>>>(
        y, Wqkvt, bqkv + l*2304, nullptr, qkv, M_, 2304, 768, 0);
    attn_kernel<<<B_*H_, 256, 0, stream>>>(qkv, gab, ob);
    mfma_gemm_t<64><<<gO64, 256, 0, stream>>>(
        ob, Wot, bo + l*HID_, h, h, M_, 768, 768, 2);
    ln_kernel<<<M_, 256, 0, stream>>>(h, ln2_g + l*HID_, ln2_b + l*HID_, y);
    mfma_gemm_t<128><<<gF1, 256, 0, stream>>>(
        y, W1t, b1 + l*FFN_, nullptr, ffn, M_, 3072, 768, 1);
    mfma_gemm_t<64><<<gO64, 256, 0, stream>>>(
        ffn, W2t, b2 + l*HID_, h, h, M_, 768, 3072, 2);
  }

  final_kernel<<<B_, 256, 0, stream>>>(h, final_g, final_b, proj_w, proj_b, out);
}

// Round 5
// 2400.278 us; speedup vs baseline: 7.4681x; 1.0385x over previous
//
#include <hip/hip_runtime.h>
#include <hip/hip_bf16.h>
#include <math.h>

#define B_ 16
#define N_ 128
#define S_ 129
#define HID_ 768
#define H_ 32
#define D_ 24
#define FFN_ 3072
#define L_ 12
#define M_ (B_*S_)   // 2064
#define SP_ 144      // padded S for q/k rows (9 x 16)
#define KP_ 160      // padded kj for P rows / vt cols (5 x 32)

typedef __attribute__((ext_vector_type(8))) short short8;
typedef __attribute__((ext_vector_type(4))) float f32x4;
typedef __hip_bfloat16 bf16;

#define VMCNT(n) asm volatile("s_waitcnt vmcnt(" #n ")" ::: "memory")
#define LDS_FENCE() asm volatile("" ::: "memory")

__device__ __forceinline__ void gload_lds16(const void* g, void* l) {
  __builtin_amdgcn_global_load_lds(
      (const __attribute__((address_space(1))) void*)g,
      (__attribute__((address_space(3))) void*)l, 16, 0, 0);
}

__device__ __forceinline__ float gld(const float* p) { return *p; }
__device__ __forceinline__ float gld(const bf16* p)  { return __bfloat162float(*p); }

// ============================================================
// gab base: gab[b,hh,qi,kj] = 2*ab + spatial(qi>0,kj>0) + t(qi==0||kj==0)
// ============================================================
__global__ __launch_bounds__(256) void gab_base_kernel(
    const float* __restrict__ ab, const int* __restrict__ spos,
    const float* __restrict__ spemb, const float* __restrict__ gtvd,
    float* __restrict__ gab)
{
  int idx = blockIdx.x * 256 + threadIdx.x;
  if (idx >= B_*H_*S_*S_) return;
  int kj = idx % S_;
  int qi = (idx / S_) % S_;
  int hh = (idx / (S_*S_)) % H_;
  int b  = idx / (S_*S_*H_);
  float v = 2.0f * ab[(b*S_ + qi)*S_ + kj];
  if (qi > 0 && kj > 0)
    v += spemb[spos[(b*N_ + (qi-1))*N_ + (kj-1)]*H_ + hh];
  if (qi == 0 || kj == 0) v += gtvd[hh];
  gab[idx] = v;
}

// ============================================================
// F table: F[d][idx][hh] = (1/3) * sum_hp eemb[idx][hp] * edis[d][hp][hh]
// ============================================================
__global__ __launch_bounds__(256) void ftab_kernel(
    const float* __restrict__ eemb, const float* __restrict__ edis,
    float* __restrict__ F)
{
  __shared__ float em[8][32];
  int tid = threadIdx.x;
  int jl = tid >> 5, hh = tid & 31;
  int p = blockIdx.x * 8 + jl;
  bool valid = p < 5*1537;
  int d = valid ? p / 1537 : 0;
  int idx = valid ? p % 1537 : 0;
  em[jl][hh] = eemb[idx*32 + hh];   // wave-local write/read, no barrier
  float acc = 0.f;
#pragma unroll
  for (int hp = 0; hp < 32; ++hp)
    acc += em[jl][hp] * edis[d*1024 + hp*32 + hh];
  if (valid) F[(long)p*32 + hh] = acc * (1.0f/3.0f);
}

// ============================================================
// edge encoding: block = (b,i) row; 15 F-gathers + adds per cell;
// coalesced gab RMW via LDS transpose
// ============================================================
__global__ __launch_bounds__(256) void edge_kernel(
    const int* __restrict__ eidx, const float* __restrict__ F,
    const int* __restrict__ spos, float* __restrict__ gab)
{
  __shared__ float outj[128][33];
  int tid = threadIdx.x;
  int jl = tid >> 5, hh = tid & 31;
  int bi = blockIdx.x;
  int b = bi >> 7, i = bi & 127;
  for (int ch = 0; ch < 16; ++ch) {
    int j = ch*8 + jl;
    const int* er = eidx + ((long)((b*N_ + i)*N_ + j)) * 15;
    float acc = 0.f;
#pragma unroll
    for (int t = 0; t < 15; ++t) {
      int d = t / 3;
      acc += F[((long)(d*1537 + er[t]))*32 + hh];
    }
    int sp0 = spos[(b*N_ + i)*N_ + j];
    int sp = (sp0 == 0) ? 1 : sp0;
    if (sp > 1) sp -= 1;
    if (sp > 5) sp = 5;
    outj[j][hh] = acc / (float)sp;
  }
  __syncthreads();
  for (int it = 0; it < 16; ++it) {
    int r = it*2 + (tid >> 7);
    int c = tid & 127;
    long g = ((long)(b*H_ + r)*S_ + (i+1))*S_ + 1 + c;
    gab[g] += outj[c][r];
  }
}

// ============================================================
// gab fp32 -> bf16 convert (4 elems/thread)
// ============================================================
__global__ __launch_bounds__(256) void gabconv_kernel(
    const float* __restrict__ gab, bf16* __restrict__ gabh, long n4)
{
  long i = ((long)blockIdx.x * 256 + threadIdx.x);
  if (i >= n4) return;
  float4 v = *(const float4*)(gab + i*4);
  bf16* o = gabh + i*4;
  o[0] = __float2bfloat16(v.x);
  o[1] = __float2bfloat16(v.y);
  o[2] = __float2bfloat16(v.z);
  o[3] = __float2bfloat16(v.w);
}

// ============================================================
// node features -> h (B,S,HID) fp32
// ============================================================
__global__ __launch_bounds__(256) void nodefeat_kernel(
    const int* __restrict__ x, const int* __restrict__ indeg,
    const int* __restrict__ outdeg, const float* __restrict__ atom_emb,
    const float* __restrict__ in_emb, const float* __restrict__ out_emb,
    const float* __restrict__ gtok, float* __restrict__ h)
{
  int idx = blockIdx.x * 256 + threadIdx.x;
  if (idx >= M_*HID_) return;
  int c = idx % HID_;
  int s = (idx / HID_) % S_;
  int b = idx / (HID_*S_);
  float v;
  if (s == 0) {
    v = gtok[c];
  } else {
    int n = s - 1;
    v = in_emb[indeg[b*N_ + n]*HID_ + c] + out_emb[outdeg[b*N_ + n]*HID_ + c];
    const int* xr = x + (b*N_ + n)*9;
#pragma unroll
    for (int e = 0; e < 9; ++e) v += atom_emb[(long)xr[e]*HID_ + c];
  }
  h[idx] = v;
}

// ============================================================
// LayerNorm (768) fp32 in -> bf16 out
// ============================================================
__global__ __launch_bounds__(256) void ln_kernel(
    const float* __restrict__ in, const float* __restrict__ g,
    const float* __restrict__ bta, bf16* __restrict__ out)
{
  int row = blockIdx.x;
  int tid = threadIdx.x;
  const float* xr = in + (long)row * HID_;
  float x0 = xr[tid], x1 = xr[tid + 256], x2 = xr[tid + 512];
  float s = x0 + x1 + x2;
  float ss = x0*x0 + x1*x1 + x2*x2;
  for (int off = 32; off > 0; off >>= 1) {
    s  += __shfl_xor(s, off);
    ss += __shfl_xor(ss, off);
  }
  __shared__ float rs[4], rss[4];
  int w = tid / 64;
  if ((tid & 63) == 0) { rs[w] = s; rss[w] = ss; }
  __syncthreads();
  s  = rs[0] + rs[1] + rs[2] + rs[3];
  ss = rss[0] + rss[1] + rss[2] + rss[3];
  float mean = s * (1.0f/768.0f);
  float var  = ss * (1.0f/768.0f) - mean*mean;
  float rstd = rsqrtf(var + 1e-5f);
  bf16* orow = out + (long)row * HID_;
  orow[tid]       = __float2bfloat16((x0 - mean)*rstd*g[tid]       + bta[tid]);
  orow[tid + 256] = __float2bfloat16((x1 - mean)*rstd*g[tid + 256] + bta[tid + 256]);
  orow[tid + 512] = __float2bfloat16((x2 - mean)*rstd*g[tid + 512] + bta[tid + 512]);
}

// ============================================================
// weight convert: W[K][N] fp32 -> Out[N][K] bf16 (*scale)
// ============================================================
__global__ __launch_bounds__(256) void wconv_kernel(
    const float* __restrict__ W, bf16* __restrict__ Out,
    int K, int N, float scale)
{
  __shared__ float tile[32][33];
  int bx = blockIdx.x * 32;
  int by = blockIdx.y * 32;
  int tx = threadIdx.x & 31, ty = threadIdx.x >> 5;
#pragma unroll
  for (int r = 0; r < 32; r += 8)
    tile[ty + r][tx] = W[(long)(by + ty + r)*N + bx + tx];
  __syncthreads();
#pragma unroll
  for (int r = 0; r < 32; r += 8)
    Out[(long)(bx + ty + r)*K + by + tx] = __float2bfloat16(tile[tx][ty + r] * scale);
}

__global__ __launch_bounds__(256) void qkvconv_kernel(
    const float* __restrict__ wq, const float* __restrict__ wk,
    const float* __restrict__ wv, bf16* __restrict__ Out, float scale)
{
  const float* W = blockIdx.z == 0 ? wq : blockIdx.z == 1 ? wk : wv;
  float sc = blockIdx.z == 0 ? scale : 1.0f;
  __shared__ float tile[32][33];
  int bx = blockIdx.x * 32;
  int by = blockIdx.y * 32;
  int tx = threadIdx.x & 31, ty = threadIdx.x >> 5;
#pragma unroll
  for (int r = 0; r < 32; r += 8)
    tile[ty + r][tx] = W[(long)(by + ty + r)*768 + bx + tx];
  __syncthreads();
  bf16* O = Out + (long)blockIdx.z * 768 * 768;
#pragma unroll
  for (int r = 0; r < 32; r += 8)
    O[(long)(bx + ty + r)*768 + by + tx] = __float2bfloat16(tile[tx][ty + r] * sc);
}

__global__ __launch_bounds__(256) void biasqkv_kernel(
    const float* __restrict__ bq, const float* __restrict__ bk,
    const float* __restrict__ bv, float* __restrict__ bqkv, float scale)
{
  int idx = blockIdx.x * 256 + threadIdx.x;
  if (idx >= L_*2304) return;
  int l = idx / 2304, n = idx % 2304;
  int p = n / 768, nn = n % 768;
  float v = (p == 0) ? bq[l*768 + nn]*scale : (p == 1) ? bk[l*768 + nn] : bv[l*768 + nn];
  bqkv[idx] = v;
}

// ============================================================
// bf16 MFMA GEMM, depth-3 ring pipeline with COUNTED vmcnt (T3+T4):
// prologue stages 3 K-tiles; steady state keeps 2 stages in flight
// (s_waitcnt vmcnt(2G), never 0 mid-loop); raw s_barrier pairs,
// compiler fences around the LDS-read/MFMA section.
// BM=128, BN template (128 or 64), BK=32, 4 waves.
// mode 0: bf16 out; 1: gelu->bf16; 2: +resid->fp32
// ============================================================
template<int BN_T>
__device__ __forceinline__ void stage_tiles(
    const bf16* __restrict__ A, const bf16* __restrict__ Wt,
    bf16* Als, bf16* Bls, int bm, int bn, int k0, int M, int K, int tid)
{
#pragma unroll
  for (int it = 0; it < 2; ++it) {
    int c = it*256 + tid;
    int row = c >> 2, kc = c & 3;
    int kcs = kc ^ ((row >> 1) & 3);
    int grow = bm + row; if (grow >= M) grow = M - 1;
    gload_lds16(A + (long)grow*K + k0 + kcs*8, Als + (it*256 + (tid & ~63))*8);
  }
  if constexpr (BN_T == 128) {
#pragma unroll
    for (int it = 0; it < 2; ++it) {
      int c = it*256 + tid;
      int row = c >> 2, kc = c & 3;
      int kcs = kc ^ ((row >> 1) & 3);
      gload_lds16(Wt + (long)(bn + row)*K + k0 + kcs*8, Bls + (it*256 + (tid & ~63))*8);
    }
  } else {
    int row = tid >> 2, kc = tid & 3;
    int kcs = kc ^ ((row >> 1) & 3);
    gload_lds16(Wt + (long)(bn + row)*K + k0 + kcs*8, Bls + (tid & ~63)*8);
  }
}

template<int BN_T>
__global__ __launch_bounds__(256) void mfma_gemm_t(
    const bf16* __restrict__ A, const bf16* __restrict__ Wt,
    const float* __restrict__ bias, const float* __restrict__ resid,
    void* __restrict__ Cout, int M, int N, int K, int mode)
{
  constexpr int NF  = BN_T / 32;     // n-frags per wave: 128->4, 64->2
  constexpr int ASZ = 128*32;
  constexpr int BSZ = BN_T*32;
  constexpr int G   = (BN_T == 128) ? 4 : 3;   // gload_lds per thread per stage
  __shared__ bf16 Als[3*ASZ];
  __shared__ bf16 Bls[3*BSZ];
  int tid = threadIdx.x;
  int wid = tid >> 6, lane = tid & 63;
  int bm = blockIdx.y * 128, bn = blockIdx.x * BN_T;
  int wr = wid >> 1, wc = wid & 1;
  int lr = lane & 15, kg = lane >> 4;

  int aoff[4], boff[NF];
#pragma unroll
  for (int m = 0; m < 4; ++m) {
    int row = wr*64 + m*16 + lr;
    aoff[m] = (row*4 + (kg ^ ((row>>1)&3)))*8;
  }
#pragma unroll
  for (int n = 0; n < NF; ++n) {
    int col = wc*(BN_T/2) + n*16 + lr;
    boff[n] = (col*4 + (kg ^ ((col>>1)&3)))*8;
  }

  f32x4 acc[4][NF];
#pragma unroll
  for (int m = 0; m < 4; ++m)
#pragma unroll
    for (int n = 0; n < NF; ++n)
      acc[m][n] = (f32x4){0.0f, 0.0f, 0.0f, 0.0f};

  int nt = K >> 5;   // always >= 24 here
  stage_tiles<BN_T>(A, Wt, Als,         Bls,         bm, bn,  0, M, K, tid);
  stage_tiles<BN_T>(A, Wt, Als + ASZ,   Bls + BSZ,   bm, bn, 32, M, K, tid);
  stage_tiles<BN_T>(A, Wt, Als + 2*ASZ, Bls + 2*BSZ, bm, bn, 64, M, K, tid);

  int cur = 0;
  for (int t = 0; t < nt; ++t) {
    int ahead = nt - 1 - t; if (ahead > 2) ahead = 2;
    if (ahead == 2)      { if constexpr (G == 4) VMCNT(8); else VMCNT(6); }
    else if (ahead == 1) { if constexpr (G == 4) VMCNT(4); else VMCNT(3); }
    else                 { VMCNT(0); }
    __builtin_amdgcn_s_barrier();
    LDS_FENCE();
    bf16* Acur = Als + cur*ASZ;
    bf16* Bcur = Bls + cur*BSZ;
    short8 av[4], bv4[NF];
#pragma unroll
    for (int m = 0; m < 4; ++m) av[m] = *(const short8*)(Acur + aoff[m]);
#pragma unroll
    for (int n = 0; n < NF; ++n) bv4[n] = *(const short8*)(Bcur + boff[n]);
#pragma unroll
    for (int m = 0; m < 4; ++m)
#pragma unroll
      for (int n = 0; n < NF; ++n)
        acc[m][n] = __builtin_amdgcn_mfma_f32_16x16x32_bf16(av[m], bv4[n], acc[m][n], 0, 0, 0);
    LDS_FENCE();
    __builtin_amdgcn_s_barrier();
    if (t + 3 < nt)
      stage_tiles<BN_T>(A, Wt, Als + cur*ASZ, Bls + cur*BSZ,
                        bm, bn, (t+3)*32, M, K, tid);
    cur = (cur == 2) ? 0 : cur + 1;
  }

#pragma unroll
  for (int n = 0; n < NF; ++n) {
    int col = bn + wc*(BN_T/2) + n*16 + lr;
    float bcol = bias[col];
#pragma unroll
    for (int m = 0; m < 4; ++m) {
      f32x4 a = acc[m][n];
#pragma unroll
      for (int i = 0; i < 4; ++i) {
        int row = bm + wr*64 + m*16 + kg*4 + i;
        if (row < M) {
          float v = a[i] + bcol;
          if (mode == 1) v = 0.5f * v * (1.0f + erff(v * 0.70710678118654752f));
          if (mode == 2)
            ((float*)Cout)[(long)row*N + col] = v + resid[(long)row*N + col];
          else
            ((bf16*)Cout)[(long)row*N + col] = __float2bfloat16(v);
        }
      }
    }
  }
}

// ============================================================
// MFMA fused attention per (b, head) — gab dtype templated
// ============================================================
template<typename GT>
__global__ __launch_bounds__(256) void attn_kernel(
    const bf16* __restrict__ qkv, const GT* __restrict__ gab,
    bf16* __restrict__ ob)
{
  int bh = blockIdx.x;
  int b = bh >> 5, hh = bh & 31;
  __shared__ bf16 ql[SP_*32];
  __shared__ bf16 kl[SP_*32];
  __shared__ bf16 vt[32*KP_];
  __shared__ bf16 pl[4][16*KP_];
  int tid = threadIdx.x;
  int wv = tid >> 6, lane = tid & 63;
  const short8 z8 = (short8){0,0,0,0,0,0,0,0};

  for (int idx = tid; idx < 32*KP_/8; idx += 256)
    *(short8*)&vt[idx*8] = z8;
  const bf16* qbase = qkv + (long)b*S_*2304 + hh*24;
  for (int u = tid; u < SP_*4; u += 256) {
    int row = u >> 2, c8 = u & 3;
    short8 qv = z8, kv = z8;
    if (row < S_ && c8 < 3) {
      qv = *(const short8*)(qbase + (long)row*2304 + c8*8);
      kv = *(const short8*)(qbase + (long)row*2304 + 768 + c8*8);
    }
    int cs = c8 ^ ((row >> 1) & 3);
    *(short8*)&ql[row*32 + cs*8] = qv;
    *(short8*)&kl[row*32 + cs*8] = kv;
  }
  __syncthreads();
  for (int u = tid; u < S_*24; u += 256) {
    int kj = u / 24, c = u % 24;
    bf16 val = qbase[(long)kj*2304 + 1536 + c];
    int ch = (kj >> 3) ^ ((c >> 1) & 3);
    vt[c*KP_ + ch*8 + (kj & 7)] = val;
  }
  __syncthreads();

  int l15 = lane & 15, l4 = lane >> 4;

  short8 bvf[5][2];
#pragma unroll
  for (int kc = 0; kc < 5; ++kc)
#pragma unroll
    for (int ntc = 0; ntc < 2; ++ntc) {
      int col = ntc*16 + l15;
      int ch = (kc*4 + l4) ^ ((col >> 1) & 3);
      bvf[kc][ntc] = *(const short8*)&vt[col*KP_ + ch*8];
    }

  bf16* plw = pl[wv];
  for (int idx = lane; idx < 16*KP_/8; idx += 64)
    *(short8*)&plw[idx*8] = z8;

  const GT* gb = gab + (long)(b*H_ + hh)*S_*S_;

  for (int mf = wv; mf < 9; mf += 4) {
    int qb0 = mf * 16;
    int qrow = qb0 + l15;
    int qch = l4 ^ ((qrow >> 1) & 3);
    short8 aq = *(const short8*)&ql[qrow*32 + qch*8];
    f32x4 sc[9];
#pragma unroll
    for (int nt = 0; nt < 9; ++nt) {
      int krow = nt*16 + l15;
      int kch = l4 ^ ((krow >> 1) & 3);
      short8 bk = *(const short8*)&kl[krow*32 + kch*8];
      sc[nt] = __builtin_amdgcn_mfma_f32_16x16x32_bf16(aq, bk, (f32x4){0,0,0,0}, 0, 0, 0);
    }
    float mx[4] = {-1e30f,-1e30f,-1e30f,-1e30f};
#pragma unroll
    for (int nt = 0; nt < 9; ++nt) {
      int kj = nt*16 + l15;
      int kjc = kj < S_ ? kj : 0;
#pragma unroll
      for (int i = 0; i < 4; ++i) {
        int q = qb0 + l4*4 + i;
        int qc = q < S_ ? q : 0;
        float v = sc[nt][i] + gld(&gb[(long)qc*S_ + kjc]);
        if (kj >= S_) v = -1e30f;
        sc[nt][i] = v;
        mx[i] = fmaxf(mx[i], v);
      }
    }
#pragma unroll
    for (int i = 0; i < 4; ++i) {
      mx[i] = fmaxf(mx[i], __shfl_xor(mx[i], 1));
      mx[i] = fmaxf(mx[i], __shfl_xor(mx[i], 2));
      mx[i] = fmaxf(mx[i], __shfl_xor(mx[i], 4));
      mx[i] = fmaxf(mx[i], __shfl_xor(mx[i], 8));
    }
    float sum[4] = {0.f,0.f,0.f,0.f};
#pragma unroll
    for (int nt = 0; nt < 9; ++nt)
#pragma unroll
      for (int i = 0; i < 4; ++i) {
        float e = __expf(sc[nt][i] - mx[i]);
        sc[nt][i] = e;
        sum[i] += e;
      }
#pragma unroll
    for (int i = 0; i < 4; ++i) {
      sum[i] += __shfl_xor(sum[i], 1);
      sum[i] += __shfl_xor(sum[i], 2);
      sum[i] += __shfl_xor(sum[i], 4);
      sum[i] += __shfl_xor(sum[i], 8);
    }
#pragma unroll
    for (int nt = 0; nt < 9; ++nt) {
      int kj = nt*16 + l15;
#pragma unroll
      for (int i = 0; i < 4; ++i) {
        int q = l4*4 + i;
        int ch = (kj >> 3) ^ ((q >> 1) & 3);
        plw[q*KP_ + ch*8 + (kj & 7)] = __float2bfloat16(sc[nt][i]);
      }
    }
    f32x4 av[2] = {(f32x4){0,0,0,0}, (f32x4){0,0,0,0}};
#pragma unroll
    for (int kc = 0; kc < 5; ++kc) {
      int ch = (kc*4 + l4) ^ ((l15 >> 1) & 3);
      short8 ap = *(const short8*)&plw[l15*KP_ + ch*8];
#pragma unroll
      for (int ntc = 0; ntc < 2; ++ntc)
        av[ntc] = __builtin_amdgcn_mfma_f32_16x16x32_bf16(ap, bvf[kc][ntc], av[ntc], 0, 0, 0);
    }
#pragma unroll
    for (int ntc = 0; ntc < 2; ++ntc) {
      int c = ntc*16 + l15;
      if (c < 24) {
#pragma unroll
        for (int i = 0; i < 4; ++i) {
          int q = qb0 + l4*4 + i;
          if (q < S_)
            ob[(long)(b*S_ + q)*768 + hh*24 + c] = __float2bfloat16(av[ntc][i] / sum[i]);
        }
      }
    }
  }
}

// ============================================================
// final: LN(h[b,0,:]) @ proj_w + proj_b -> out[b]
// ============================================================
__global__ __launch_bounds__(256) void final_kernel(
    const float* __restrict__ h, const float* __restrict__ fg,
    const float* __restrict__ fb, const float* __restrict__ pw,
    const float* __restrict__ pb, float* __restrict__ out)
{
  int b = blockIdx.x;
  int tid = threadIdx.x;
  const float* xr = h + (long)b * S_ * HID_;
  float x0 = xr[tid], x1 = xr[tid + 256], x2 = xr[tid + 512];
  float s = x0 + x1 + x2;
  float ss = x0*x0 + x1*x1 + x2*x2;
  for (int off = 32; off > 0; off >>= 1) {
    s  += __shfl_xor(s, off);
    ss += __shfl_xor(ss, off);
  }
  __shared__ float rs[4], rss[4], rd[4];
  int w = tid / 64;
  if ((tid & 63) == 0) { rs[w] = s; rss[w] = ss; }
  __syncthreads();
  s  = rs[0] + rs[1] + rs[2] + rs[3];
  ss = rss[0] + rss[1] + rss[2] + rss[3];
  float mean = s * (1.0f/768.0f);
  float var  = ss * (1.0f/768.0f) - mean*mean;
  float rstd = rsqrtf(var + 1e-5f);
  float d0 = ((x0 - mean)*rstd*fg[tid]       + fb[tid])       * pw[tid];
  float d1 = ((x1 - mean)*rstd*fg[tid + 256] + fb[tid + 256]) * pw[tid + 256];
  float d2 = ((x2 - mean)*rstd*fg[tid + 512] + fb[tid + 512]) * pw[tid + 512];
  float pd = d0 + d1 + d2;
  for (int off = 32; off > 0; off >>= 1) pd += __shfl_xor(pd, off);
  if ((tid & 63) == 0) rd[w] = pd;
  __syncthreads();
  if (tid == 0) out[b] = rd[0] + rd[1] + rd[2] + rd[3] + pb[0];
}

// ============================================================
extern "C" void kernel_launch(void* const* d_in, const int* in_sizes, int n_in,
                              void* d_out, int out_size, void* d_ws, size_t ws_size,
                              hipStream_t stream)
{
  const float* attn_bias   = (const float*)d_in[0];
  const int*   spatial_pos = (const int*)d_in[1];
  const int*   x           = (const int*)d_in[2];
  const int*   in_degree   = (const int*)d_in[3];
  const int*   out_degree  = (const int*)d_in[4];
  const int*   edge_input  = (const int*)d_in[5];
  const float* atom_emb    = (const float*)d_in[6];
  const float* edge_emb    = (const float*)d_in[7];
  const float* edge_dis    = (const float*)d_in[8];
  const float* spatial_emb = (const float*)d_in[9];
  const float* in_deg_emb  = (const float*)d_in[10];
  const float* out_deg_emb = (const float*)d_in[11];
  const float* graph_token = (const float*)d_in[12];
  const float* gt_vd       = (const float*)d_in[13];
  const float* ln1_g = (const float*)d_in[14];
  const float* ln1_b = (const float*)d_in[15];
  const float* wq = (const float*)d_in[16];
  const float* bq = (const float*)d_in[17];
  const float* wk = (const float*)d_in[18];
  const float* bk = (const float*)d_in[19];
  const float* wv = (const float*)d_in[20];
  const float* bv = (const float*)d_in[21];
  const float* wo = (const float*)d_in[22];
  const float* bo = (const float*)d_in[23];
  const float* ln2_g = (const float*)d_in[24];
  const float* ln2_b = (const float*)d_in[25];
  const float* w1 = (const float*)d_in[26];
  const float* b1 = (const float*)d_in[27];
  const float* w2 = (const float*)d_in[28];
  const float* b2 = (const float*)d_in[29];
  const float* final_g = (const float*)d_in[30];
  const float* final_b = (const float*)d_in[31];
  const float* proj_w  = (const float*)d_in[32];
  const float* proj_b  = (const float*)d_in[33];

  float* out = (float*)d_out;

  const float scale = 0.20412414523193154f;  // 24^-0.5
  const long GAB_N = (long)B_*H_*S_*S_;      // 8,520,192

  char* p = (char*)d_ws;
  float* gab  = (float*)p;  p += GAB_N*4;
  float* h    = (float*)p;  p += (long)M_*HID_*4;
  bf16*  y    = (bf16*)p;   p += (long)M_*HID_*2;
  bf16*  qkv  = (bf16*)p;   // ffn aliases qkv+ob
  bf16*  ffn  = qkv;
  p += (long)M_*2304*2;
  bf16*  ob   = (bf16*)p;   p += (long)M_*HID_*2;
  float* Ftab = (float*)p;  p += (long)5*1537*32*4;
  float* bqkv = (float*)p;  p += (long)L_*2304*4;

  const size_t WQKV_E = (size_t)2304*768;
  const size_t WO_E   = (size_t)768*768;
  const size_t W1_E   = (size_t)3072*768;
  const size_t W2_E   = (size_t)768*3072;
  const size_t WL_E   = WQKV_E + WO_E + W1_E + W2_E;   // 7,077,888

  // optional bf16 gab (attn fast path), then weight buffer
  size_t off0 = (size_t)(p - (char*)d_ws);
  bool g16 = ws_size >= off0 + (size_t)GAB_N*2 + WL_E*2;
  bf16* gabh = (bf16*)p;
  if (g16) p += GAB_N*2;
  bf16* wbuf = (bf16*)p;
  size_t base_bytes = (size_t)(p - (char*)d_ws);
  bool full = ws_size >= base_bytes + (size_t)L_ * WL_E * 2;

  // ---- setup ----
  gab_base_kernel<<<(int)((GAB_N + 255)/256), 256, 0, stream>>>(
      attn_bias, spatial_pos, spatial_emb, gt_vd, gab);
  ftab_kernel<<<(5*1537 + 7)/8, 256, 0, stream>>>(edge_emb, edge_dis, Ftab);
  edge_kernel<<<B_*N_, 256, 0, stream>>>(edge_input, Ftab, spatial_pos, gab);
  if (g16) {
    long n4 = GAB_N/4;
    gabconv_kernel<<<(int)((n4 + 255)/256), 256, 0, stream>>>(gab, gabh, n4);
  }
  nodefeat_kernel<<<(M_*HID_ + 255)/256, 256, 0, stream>>>(
      x, in_degree, out_degree, atom_emb, in_deg_emb, out_deg_emb, graph_token, h);
  biasqkv_kernel<<<(L_*2304 + 255)/256, 256, 0, stream>>>(bq, bk, bv, bqkv, scale);

  dim3 gQKV(2304/128, (M_ + 127)/128);   // 18 x 17
  dim3 gO64(768/64,   (M_ + 127)/128);   // 12 x 17
  dim3 gF1 (3072/128, (M_ + 127)/128);   // 24 x 17
  dim3 cQKV(768/32, 768/32, 3);
  dim3 cO  (768/32, 768/32);
  dim3 cW1 (3072/32, 768/32);
  dim3 cW2 (768/32, 3072/32);

  auto wptr = [&](int l) { return wbuf + (full ? (size_t)l : 0) * WL_E; };
  auto conv = [&](int l) {
    bf16* W = wptr(l);
    qkvconv_kernel<<<cQKV, 256, 0, stream>>>(
        wq + (size_t)l*HID_*HID_, wk + (size_t)l*HID_*HID_, wv + (size_t)l*HID_*HID_,
        W, scale);
    wconv_kernel<<<cO, 256, 0, stream>>>(wo + (size_t)l*HID_*HID_, W + WQKV_E, 768, 768, 1.0f);
    wconv_kernel<<<cW1, 256, 0, stream>>>(w1 + (size_t)l*HID_*FFN_, W + WQKV_E + WO_E, 768, 3072, 1.0f);
    wconv_kernel<<<cW2, 256, 0, stream>>>(w2 + (size_t)l*FFN_*HID_, W + WQKV_E + WO_E + W1_E, 3072, 768, 1.0f);
  };

  if (full)
    for (int l = 0; l < L_; ++l) conv(l);

  for (int l = 0; l < L_; ++l) {
    if (!full) conv(l);
    bf16* W = wptr(l);
    bf16* Wqkvt = W;
    bf16* Wot   = W + WQKV_E;
    bf16* W1t   = W + WQKV_E + WO_E;
    bf16* W2t   = W + WQKV_E + WO_E + W1_E;

    ln_kernel<<<M_, 256, 0, stream>>>(h, ln1_g + l*HID_, ln1_b + l*HID_, y);
    mfma_gemm_t<128><<<gQKV, 256, 0, stream>>>(
        y, Wqkvt, bqkv + l*2304, nullptr, qkv, M_, 2304, 768, 0);
    if (g16)
      attn_kernel<bf16><<<B_*H_, 256, 0, stream>>>(qkv, gabh, ob);
    else
      attn_kernel<float><<<B_*H_, 256, 0, stream>>>(qkv, gab, ob);
    mfma_gemm_t<64><<<gO64, 256, 0, stream>>>(
        ob, Wot, bo + l*HID_, h, h, M_, 768, 768, 2);
    ln_kernel<<<M_, 256, 0, stream>>>(h, ln2_g + l*HID_, ln2_b + l*HID_, y);
    mfma_gemm_t<128><<<gF1, 256, 0, stream>>>(
        y, W1t, b1 + l*FFN_, nullptr, ffn, M_, 3072, 768, 1);
    mfma_gemm_t<64><<<gO64, 256, 0, stream>>>(
        ffn, W2t, b2 + l*HID_, h, h, M_, 768, 3072, 2);
  }

  final_kernel<<<B_, 256, 0, stream>>>(h, final_g, final_b, proj_w, proj_b, out);
}

// Round 6
// 2070.531 us; speedup vs baseline: 8.6575x; 1.1593x over previous
//
#include <hip/hip_runtime.h>
#include <hip/hip_bf16.h>
#include <math.h>

#define B_ 16
#define N_ 128
#define S_ 129
#define HID_ 768
#define H_ 32
#define D_ 24
#define FFN_ 3072
#define L_ 12
#define M_ (B_*S_)   // 2064
#define SP_ 144      // padded S for q/k rows (9 x 16)
#define KP_ 160      // padded kj for P rows / vt cols (5 x 32)

#define WQKV_E ((size_t)2304*768)
#define WO_E   ((size_t)768*768)
#define W1_E   ((size_t)3072*768)
#define W2_E   ((size_t)768*3072)
#define WL_E_  (WQKV_E + WO_E + W1_E + W2_E)   // 7,077,888

typedef __attribute__((ext_vector_type(8))) short short8;
typedef __attribute__((ext_vector_type(4))) float f32x4;
typedef __hip_bfloat16 bf16;

#define VMCNT(n) asm volatile("s_waitcnt vmcnt(" #n ")" ::: "memory")
#define LDS_FENCE() asm volatile("" ::: "memory")

__device__ __forceinline__ void gload_lds16(const void* g, void* l) {
  __builtin_amdgcn_global_load_lds(
      (const __attribute__((address_space(1))) void*)g,
      (__attribute__((address_space(3))) void*)l, 16, 0, 0);
}

__device__ __forceinline__ float gld(const float* p) { return *p; }
__device__ __forceinline__ float gld(const bf16* p)  { return __bfloat162float(*p); }

// ============================================================
// gab base
// ============================================================
__global__ __launch_bounds__(256) void gab_base_kernel(
    const float* __restrict__ ab, const int* __restrict__ spos,
    const float* __restrict__ spemb, const float* __restrict__ gtvd,
    float* __restrict__ gab)
{
  int idx = blockIdx.x * 256 + threadIdx.x;
  if (idx >= B_*H_*S_*S_) return;
  int kj = idx % S_;
  int qi = (idx / S_) % S_;
  int hh = (idx / (S_*S_)) % H_;
  int b  = idx / (S_*S_*H_);
  float v = 2.0f * ab[(b*S_ + qi)*S_ + kj];
  if (qi > 0 && kj > 0)
    v += spemb[spos[(b*N_ + (qi-1))*N_ + (kj-1)]*H_ + hh];
  if (qi == 0 || kj == 0) v += gtvd[hh];
  gab[idx] = v;
}

// ============================================================
// F table
// ============================================================
__global__ __launch_bounds__(256) void ftab_kernel(
    const float* __restrict__ eemb, const float* __restrict__ edis,
    float* __restrict__ F)
{
  __shared__ float em[8][32];
  int tid = threadIdx.x;
  int jl = tid >> 5, hh = tid & 31;
  int p = blockIdx.x * 8 + jl;
  bool valid = p < 5*1537;
  int d = valid ? p / 1537 : 0;
  int idx = valid ? p % 1537 : 0;
  em[jl][hh] = eemb[idx*32 + hh];
  float acc = 0.f;
#pragma unroll
  for (int hp = 0; hp < 32; ++hp)
    acc += em[jl][hp] * edis[d*1024 + hp*32 + hh];
  if (valid) F[(long)p*32 + hh] = acc * (1.0f/3.0f);
}

// ============================================================
// edge encoding
// ============================================================
__global__ __launch_bounds__(256) void edge_kernel(
    const int* __restrict__ eidx, const float* __restrict__ F,
    const int* __restrict__ spos, float* __restrict__ gab)
{
  __shared__ float outj[128][33];
  int tid = threadIdx.x;
  int jl = tid >> 5, hh = tid & 31;
  int bi = blockIdx.x;
  int b = bi >> 7, i = bi & 127;
  for (int ch = 0; ch < 16; ++ch) {
    int j = ch*8 + jl;
    const int* er = eidx + ((long)((b*N_ + i)*N_ + j)) * 15;
    float acc = 0.f;
#pragma unroll
    for (int t = 0; t < 15; ++t) {
      int d = t / 3;
      acc += F[((long)(d*1537 + er[t]))*32 + hh];
    }
    int sp0 = spos[(b*N_ + i)*N_ + j];
    int sp = (sp0 == 0) ? 1 : sp0;
    if (sp > 1) sp -= 1;
    if (sp > 5) sp = 5;
    outj[j][hh] = acc / (float)sp;
  }
  __syncthreads();
  for (int it = 0; it < 16; ++it) {
    int r = it*2 + (tid >> 7);
    int c = tid & 127;
    long g = ((long)(b*H_ + r)*S_ + (i+1))*S_ + 1 + c;
    gab[g] += outj[c][r];
  }
}

// ============================================================
// gab fp32 -> bf16
// ============================================================
__global__ __launch_bounds__(256) void gabconv_kernel(
    const float* __restrict__ gab, bf16* __restrict__ gabh, long n4)
{
  long i = ((long)blockIdx.x * 256 + threadIdx.x);
  if (i >= n4) return;
  float4 v = *(const float4*)(gab + i*4);
  bf16* o = gabh + i*4;
  o[0] = __float2bfloat16(v.x);
  o[1] = __float2bfloat16(v.y);
  o[2] = __float2bfloat16(v.z);
  o[3] = __float2bfloat16(v.w);
}

// ============================================================
// node features
// ============================================================
__global__ __launch_bounds__(256) void nodefeat_kernel(
    const int* __restrict__ x, const int* __restrict__ indeg,
    const int* __restrict__ outdeg, const float* __restrict__ atom_emb,
    const float* __restrict__ in_emb, const float* __restrict__ out_emb,
    const float* __restrict__ gtok, float* __restrict__ h)
{
  int idx = blockIdx.x * 256 + threadIdx.x;
  if (idx >= M_*HID_) return;
  int c = idx % HID_;
  int s = (idx / HID_) % S_;
  int b = idx / (HID_*S_);
  float v;
  if (s == 0) {
    v = gtok[c];
  } else {
    int n = s - 1;
    v = in_emb[indeg[b*N_ + n]*HID_ + c] + out_emb[outdeg[b*N_ + n]*HID_ + c];
    const int* xr = x + (b*N_ + n)*9;
#pragma unroll
    for (int e = 0; e < 9; ++e) v += atom_emb[(long)xr[e]*HID_ + c];
  }
  h[idx] = v;
}

// ============================================================
// LayerNorm fp32 -> bf16
// ============================================================
__global__ __launch_bounds__(256) void ln_kernel(
    const float* __restrict__ in, const float* __restrict__ g,
    const float* __restrict__ bta, bf16* __restrict__ out)
{
  int row = blockIdx.x;
  int tid = threadIdx.x;
  const float* xr = in + (long)row * HID_;
  float x0 = xr[tid], x1 = xr[tid + 256], x2 = xr[tid + 512];
  float s = x0 + x1 + x2;
  float ss = x0*x0 + x1*x1 + x2*x2;
  for (int off = 32; off > 0; off >>= 1) {
    s  += __shfl_xor(s, off);
    ss += __shfl_xor(ss, off);
  }
  __shared__ float rs[4], rss[4];
  int w = tid / 64;
  if ((tid & 63) == 0) { rs[w] = s; rss[w] = ss; }
  __syncthreads();
  s  = rs[0] + rs[1] + rs[2] + rs[3];
  ss = rss[0] + rss[1] + rss[2] + rss[3];
  float mean = s * (1.0f/768.0f);
  float var  = ss * (1.0f/768.0f) - mean*mean;
  float rstd = rsqrtf(var + 1e-5f);
  bf16* orow = out + (long)row * HID_;
  orow[tid]       = __float2bfloat16((x0 - mean)*rstd*g[tid]       + bta[tid]);
  orow[tid + 256] = __float2bfloat16((x1 - mean)*rstd*g[tid + 256] + bta[tid + 256]);
  orow[tid + 512] = __float2bfloat16((x2 - mean)*rstd*g[tid + 512] + bta[tid + 512]);
}

// ============================================================
// weight converts (per-layer fallback versions)
// ============================================================
__global__ __launch_bounds__(256) void wconv_kernel(
    const float* __restrict__ W, bf16* __restrict__ Out,
    int K, int N, float scale)
{
  __shared__ float tile[32][33];
  int bx = blockIdx.x * 32;
  int by = blockIdx.y * 32;
  int tx = threadIdx.x & 31, ty = threadIdx.x >> 5;
#pragma unroll
  for (int r = 0; r < 32; r += 8)
    tile[ty + r][tx] = W[(long)(by + ty + r)*N + bx + tx];
  __syncthreads();
#pragma unroll
  for (int r = 0; r < 32; r += 8)
    Out[(long)(bx + ty + r)*K + by + tx] = __float2bfloat16(tile[tx][ty + r] * scale);
}

__global__ __launch_bounds__(256) void qkvconv_kernel(
    const float* __restrict__ wq, const float* __restrict__ wk,
    const float* __restrict__ wv, bf16* __restrict__ Out, float scale)
{
  const float* W = blockIdx.z == 0 ? wq : blockIdx.z == 1 ? wk : wv;
  float sc = blockIdx.z == 0 ? scale : 1.0f;
  __shared__ float tile[32][33];
  int bx = blockIdx.x * 32;
  int by = blockIdx.y * 32;
  int tx = threadIdx.x & 31, ty = threadIdx.x >> 5;
#pragma unroll
  for (int r = 0; r < 32; r += 8)
    tile[ty + r][tx] = W[(long)(by + ty + r)*768 + bx + tx];
  __syncthreads();
  bf16* O = Out + (long)blockIdx.z * 768 * 768;
#pragma unroll
  for (int r = 0; r < 32; r += 8)
    O[(long)(bx + ty + r)*768 + by + tx] = __float2bfloat16(tile[tx][ty + r] * sc);
}

// batched (all layers) versions
__global__ __launch_bounds__(256) void qkvconv_all_kernel(
    const float* __restrict__ wq, const float* __restrict__ wk,
    const float* __restrict__ wv, bf16* __restrict__ wbuf, float scale)
{
  int z = blockIdx.z;
  int l = z / 3, which = z % 3;
  const float* W = (which == 0 ? wq : which == 1 ? wk : wv) + (size_t)l*768*768;
  float sc = which == 0 ? scale : 1.0f;
  __shared__ float tile[32][33];
  int bx = blockIdx.x * 32;
  int by = blockIdx.y * 32;
  int tx = threadIdx.x & 31, ty = threadIdx.x >> 5;
#pragma unroll
  for (int r = 0; r < 32; r += 8)
    tile[ty + r][tx] = W[(long)(by + ty + r)*768 + bx + tx];
  __syncthreads();
  bf16* O = wbuf + (size_t)l*WL_E_ + (size_t)which*768*768;
#pragma unroll
  for (int r = 0; r < 32; r += 8)
    O[(long)(bx + ty + r)*768 + by + tx] = __float2bfloat16(tile[tx][ty + r] * sc);
}

__global__ __launch_bounds__(256) void wconv_all_kernel(
    const float* __restrict__ Wb, bf16* __restrict__ Ob,
    int K, int N, long inStride, long outStride)
{
  int z = blockIdx.z;
  const float* W = Wb + (size_t)z * inStride;
  bf16* Out = Ob + (size_t)z * outStride;
  __shared__ float tile[32][33];
  int bx = blockIdx.x * 32;
  int by = blockIdx.y * 32;
  int tx = threadIdx.x & 31, ty = threadIdx.x >> 5;
#pragma unroll
  for (int r = 0; r < 32; r += 8)
    tile[ty + r][tx] = W[(long)(by + ty + r)*N + bx + tx];
  __syncthreads();
#pragma unroll
  for (int r = 0; r < 32; r += 8)
    Out[(long)(bx + ty + r)*K + by + tx] = __float2bfloat16(tile[tx][ty + r]);
}

__global__ __launch_bounds__(256) void biasqkv_kernel(
    const float* __restrict__ bq, const float* __restrict__ bk,
    const float* __restrict__ bv, float* __restrict__ bqkv, float scale)
{
  int idx = blockIdx.x * 256 + threadIdx.x;
  if (idx >= L_*2304) return;
  int l = idx / 2304, n = idx % 2304;
  int p = n / 768, nn = n % 768;
  float v = (p == 0) ? bq[l*768 + nn]*scale : (p == 1) ? bk[l*768 + nn] : bv[l*768 + nn];
  bqkv[idx] = v;
}

// ============================================================
// bf16 MFMA GEMM: BM=64, BN=64, BK=32, 4 waves (2x2, 32x32 each).
// Depth-3 ring + counted vmcnt (G=2 loads/thread/stage -> vmcnt 4/2/0).
// blockIdx.z = K-split chunk (koff = z*Klen); lda/ldb = row strides.
// mode 0: bf16 out; 1: gelu->bf16; 2: +resid->fp32; 3: fp32 partial (no bias)
// ============================================================
__device__ __forceinline__ void stage64(
    const bf16* __restrict__ A, const bf16* __restrict__ Wt,
    bf16* Als, bf16* Bls, int bm, int bn, long ka, int M, int lda, int ldb, int tid)
{
  int row = tid >> 2, kc = tid & 3;
  int kcs = kc ^ ((row >> 1) & 3);
  int grow = bm + row; if (grow >= M) grow = M - 1;
  gload_lds16(A + (long)grow*lda + ka + kcs*8, Als + (tid & ~63)*8);
  gload_lds16(Wt + (long)(bn + row)*ldb + ka + kcs*8, Bls + (tid & ~63)*8);
}

__global__ __launch_bounds__(256) void gemm64_kernel(
    const bf16* __restrict__ A, const bf16* __restrict__ Wt,
    const float* __restrict__ bias, const float* __restrict__ resid,
    void* __restrict__ Cout, int M, int N, int Klen, int lda, int ldb, int mode)
{
  constexpr int ASZ = 64*32;
  __shared__ bf16 Als[3*ASZ];
  __shared__ bf16 Bls[3*ASZ];
  int tid = threadIdx.x;
  int wid = tid >> 6, lane = tid & 63;
  int bm = blockIdx.y * 64, bn = blockIdx.x * 64;
  long koff = (long)blockIdx.z * Klen;
  int wr = wid >> 1, wc = wid & 1;
  int lr = lane & 15, kg = lane >> 4;

  int aoff[2], boff[2];
#pragma unroll
  for (int m = 0; m < 2; ++m) {
    int row = wr*32 + m*16 + lr;
    aoff[m] = (row*4 + (kg ^ ((row>>1)&3)))*8;
  }
#pragma unroll
  for (int n = 0; n < 2; ++n) {
    int col = wc*32 + n*16 + lr;
    boff[n] = (col*4 + (kg ^ ((col>>1)&3)))*8;
  }

  f32x4 acc[2][2];
#pragma unroll
  for (int m = 0; m < 2; ++m)
#pragma unroll
    for (int n = 0; n < 2; ++n)
      acc[m][n] = (f32x4){0.0f, 0.0f, 0.0f, 0.0f};

  int nt = Klen >> 5;   // >= 24 for all call sites
  stage64(A, Wt, Als,         Bls,         bm, bn, koff,      M, lda, ldb, tid);
  stage64(A, Wt, Als + ASZ,   Bls + ASZ,   bm, bn, koff + 32, M, lda, ldb, tid);
  stage64(A, Wt, Als + 2*ASZ, Bls + 2*ASZ, bm, bn, koff + 64, M, lda, ldb, tid);

  int cur = 0;
  for (int t = 0; t < nt; ++t) {
    int ahead = nt - 1 - t; if (ahead > 2) ahead = 2;
    if (ahead == 2)      VMCNT(4);
    else if (ahead == 1) VMCNT(2);
    else                 VMCNT(0);
    __builtin_amdgcn_s_barrier();
    LDS_FENCE();
    bf16* Acur = Als + cur*ASZ;
    bf16* Bcur = Bls + cur*ASZ;
    short8 av[2], bv2[2];
#pragma unroll
    for (int m = 0; m < 2; ++m) av[m] = *(const short8*)(Acur + aoff[m]);
#pragma unroll
    for (int n = 0; n < 2; ++n) bv2[n] = *(const short8*)(Bcur + boff[n]);
#pragma unroll
    for (int m = 0; m < 2; ++m)
#pragma unroll
      for (int n = 0; n < 2; ++n)
        acc[m][n] = __builtin_amdgcn_mfma_f32_16x16x32_bf16(av[m], bv2[n], acc[m][n], 0, 0, 0);
    LDS_FENCE();
    __builtin_amdgcn_s_barrier();
    if (t + 3 < nt)
      stage64(A, Wt, Als + cur*ASZ, Bls + cur*ASZ,
              bm, bn, koff + (long)(t+3)*32, M, lda, ldb, tid);
    cur = (cur == 2) ? 0 : cur + 1;
  }

#pragma unroll
  for (int n = 0; n < 2; ++n) {
    int col = bn + wc*32 + n*16 + lr;
    float bcol = (mode == 3) ? 0.0f : bias[col];
#pragma unroll
    for (int m = 0; m < 2; ++m) {
      f32x4 a = acc[m][n];
#pragma unroll
      for (int i = 0; i < 4; ++i) {
        int row = bm + wr*32 + m*16 + kg*4 + i;
        if (row < M) {
          float v = a[i] + bcol;
          if (mode == 1) v = 0.5f * v * (1.0f + erff(v * 0.70710678118654752f));
          if (mode == 2)
            ((float*)Cout)[(long)row*N + col] = v + resid[(long)row*N + col];
          else if (mode == 3)
            ((float*)Cout + (size_t)blockIdx.z*M*N)[(long)row*N + col] = v;
          else
            ((bf16*)Cout)[(long)row*N + col] = __float2bfloat16(v);
        }
      }
    }
  }
}

// ============================================================
// split-K combine: h += b2 + sum_z part[z]
// ============================================================
__global__ __launch_bounds__(256) void combine_kernel(
    const float* __restrict__ part, const float* __restrict__ b2,
    float* __restrict__ h)
{
  const long MN = (long)M_*768;
  long i = (long)blockIdx.x * 256 + threadIdx.x;
  if (i >= MN/4) return;
  float4 a  = *(const float4*)(h + i*4);
  float4 p0 = *(const float4*)(part + i*4);
  float4 p1 = *(const float4*)(part + MN + i*4);
  float4 p2 = *(const float4*)(part + 2*MN + i*4);
  float4 p3 = *(const float4*)(part + 3*MN + i*4);
  int n = (int)((i*4) % 768);
  float4 bv = *(const float4*)(b2 + n);
  float4 r;
  r.x = a.x + bv.x + p0.x + p1.x + p2.x + p3.x;
  r.y = a.y + bv.y + p0.y + p1.y + p2.y + p3.y;
  r.z = a.z + bv.z + p0.z + p1.z + p2.z + p3.z;
  r.w = a.w + bv.w + p0.w + p1.w + p2.w + p3.w;
  *(float4*)(h + i*4) = r;
}

// ============================================================
// MFMA fused attention per (b, head, q-group): grid (B*H, 3)
// wave wv of group zz owns q-tile mf = zz*4 + wv (one tile per wave)
// ============================================================
template<typename GT>
__global__ __launch_bounds__(256) void attn_kernel(
    const bf16* __restrict__ qkv, const GT* __restrict__ gab,
    bf16* __restrict__ ob)
{
  int bh = blockIdx.x;
  int zz = blockIdx.y;
  int b = bh >> 5, hh = bh & 31;
  __shared__ bf16 ql[SP_*32];
  __shared__ bf16 kl[SP_*32];
  __shared__ bf16 vt[32*KP_];
  __shared__ bf16 pl[4][16*KP_];
  int tid = threadIdx.x;
  int wv = tid >> 6, lane = tid & 63;
  const short8 z8 = (short8){0,0,0,0,0,0,0,0};

  for (int idx = tid; idx < 32*KP_/8; idx += 256)
    *(short8*)&vt[idx*8] = z8;
  const bf16* qbase = qkv + (long)b*S_*2304 + hh*24;
  for (int u = tid; u < SP_*4; u += 256) {
    int row = u >> 2, c8 = u & 3;
    short8 qv = z8, kv = z8;
    if (row < S_ && c8 < 3) {
      qv = *(const short8*)(qbase + (long)row*2304 + c8*8);
      kv = *(const short8*)(qbase + (long)row*2304 + 768 + c8*8);
    }
    int cs = c8 ^ ((row >> 1) & 3);
    *(short8*)&ql[row*32 + cs*8] = qv;
    *(short8*)&kl[row*32 + cs*8] = kv;
  }
  __syncthreads();
  for (int u = tid; u < S_*24; u += 256) {
    int kj = u / 24, c = u % 24;
    bf16 val = qbase[(long)kj*2304 + 1536 + c];
    int ch = (kj >> 3) ^ ((c >> 1) & 3);
    vt[c*KP_ + ch*8 + (kj & 7)] = val;
  }
  __syncthreads();

  int l15 = lane & 15, l4 = lane >> 4;
  int mf = zz*4 + wv;
  if (mf >= 9) return;

  short8 bvf[5][2];
#pragma unroll
  for (int kc = 0; kc < 5; ++kc)
#pragma unroll
    for (int ntc = 0; ntc < 2; ++ntc) {
      int col = ntc*16 + l15;
      int ch = (kc*4 + l4) ^ ((col >> 1) & 3);
      bvf[kc][ntc] = *(const short8*)&vt[col*KP_ + ch*8];
    }

  bf16* plw = pl[wv];
  for (int idx = lane; idx < 16*KP_/8; idx += 64)
    *(short8*)&plw[idx*8] = z8;

  const GT* gb = gab + (long)(b*H_ + hh)*S_*S_;

  {
    int qb0 = mf * 16;
    int qrow = qb0 + l15;
    int qch = l4 ^ ((qrow >> 1) & 3);
    short8 aq = *(const short8*)&ql[qrow*32 + qch*8];
    f32x4 sc[9];
#pragma unroll
    for (int nt = 0; nt < 9; ++nt) {
      int krow = nt*16 + l15;
      int kch = l4 ^ ((krow >> 1) & 3);
      short8 bk = *(const short8*)&kl[krow*32 + kch*8];
      sc[nt] = __builtin_amdgcn_mfma_f32_16x16x32_bf16(aq, bk, (f32x4){0,0,0,0}, 0, 0, 0);
    }
    float mx[4] = {-1e30f,-1e30f,-1e30f,-1e30f};
#pragma unroll
    for (int nt = 0; nt < 9; ++nt) {
      int kj = nt*16 + l15;
      int kjc = kj < S_ ? kj : 0;
#pragma unroll
      for (int i = 0; i < 4; ++i) {
        int q = qb0 + l4*4 + i;
        int qc = q < S_ ? q : 0;
        float v = sc[nt][i] + gld(&gb[(long)qc*S_ + kjc]);
        if (kj >= S_) v = -1e30f;
        sc[nt][i] = v;
        mx[i] = fmaxf(mx[i], v);
      }
    }
#pragma unroll
    for (int i = 0; i < 4; ++i) {
      mx[i] = fmaxf(mx[i], __shfl_xor(mx[i], 1));
      mx[i] = fmaxf(mx[i], __shfl_xor(mx[i], 2));
      mx[i] = fmaxf(mx[i], __shfl_xor(mx[i], 4));
      mx[i] = fmaxf(mx[i], __shfl_xor(mx[i], 8));
    }
    float sum[4] = {0.f,0.f,0.f,0.f};
#pragma unroll
    for (int nt = 0; nt < 9; ++nt)
#pragma unroll
      for (int i = 0; i < 4; ++i) {
        float e = __expf(sc[nt][i] - mx[i]);
        sc[nt][i] = e;
        sum[i] += e;
      }
#pragma unroll
    for (int i = 0; i < 4; ++i) {
      sum[i] += __shfl_xor(sum[i], 1);
      sum[i] += __shfl_xor(sum[i], 2);
      sum[i] += __shfl_xor(sum[i], 4);
      sum[i] += __shfl_xor(sum[i], 8);
    }
#pragma unroll
    for (int nt = 0; nt < 9; ++nt) {
      int kj = nt*16 + l15;
#pragma unroll
      for (int i = 0; i < 4; ++i) {
        int q = l4*4 + i;
        int ch = (kj >> 3) ^ ((q >> 1) & 3);
        plw[q*KP_ + ch*8 + (kj & 7)] = __float2bfloat16(sc[nt][i]);
      }
    }
    f32x4 av[2] = {(f32x4){0,0,0,0}, (f32x4){0,0,0,0}};
#pragma unroll
    for (int kc = 0; kc < 5; ++kc) {
      int ch = (kc*4 + l4) ^ ((l15 >> 1) & 3);
      short8 ap = *(const short8*)&plw[l15*KP_ + ch*8];
#pragma unroll
      for (int ntc = 0; ntc < 2; ++ntc)
        av[ntc] = __builtin_amdgcn_mfma_f32_16x16x32_bf16(ap, bvf[kc][ntc], av[ntc], 0, 0, 0);
    }
#pragma unroll
    for (int ntc = 0; ntc < 2; ++ntc) {
      int c = ntc*16 + l15;
      if (c < 24) {
#pragma unroll
        for (int i = 0; i < 4; ++i) {
          int q = qb0 + l4*4 + i;
          if (q < S_)
            ob[(long)(b*S_ + q)*768 + hh*24 + c] = __float2bfloat16(av[ntc][i] / sum[i]);
        }
      }
    }
  }
}

// ============================================================
// final
// ============================================================
__global__ __launch_bounds__(256) void final_kernel(
    const float* __restrict__ h, const float* __restrict__ fg,
    const float* __restrict__ fb, const float* __restrict__ pw,
    const float* __restrict__ pb, float* __restrict__ out)
{
  int b = blockIdx.x;
  int tid = threadIdx.x;
  const float* xr = h + (long)b * S_ * HID_;
  float x0 = xr[tid], x1 = xr[tid + 256], x2 = xr[tid + 512];
  float s = x0 + x1 + x2;
  float ss = x0*x0 + x1*x1 + x2*x2;
  for (int off = 32; off > 0; off >>= 1) {
    s  += __shfl_xor(s, off);
    ss += __shfl_xor(ss, off);
  }
  __shared__ float rs[4], rss[4], rd[4];
  int w = tid / 64;
  if ((tid & 63) == 0) { rs[w] = s; rss[w] = ss; }
  __syncthreads();
  s  = rs[0] + rs[1] + rs[2] + rs[3];
  ss = rss[0] + rss[1] + rss[2] + rss[3];
  float mean = s * (1.0f/768.0f);
  float var  = ss * (1.0f/768.0f) - mean*mean;
  float rstd = rsqrtf(var + 1e-5f);
  float d0 = ((x0 - mean)*rstd*fg[tid]       + fb[tid])       * pw[tid];
  float d1 = ((x1 - mean)*rstd*fg[tid + 256] + fb[tid + 256]) * pw[tid + 256];
  float d2 = ((x2 - mean)*rstd*fg[tid + 512] + fb[tid + 512]) * pw[tid + 512];
  float pd = d0 + d1 + d2;
  for (int off = 32; off > 0; off >>= 1) pd += __shfl_xor(pd, off);
  if ((tid & 63) == 0) rd[w] = pd;
  __syncthreads();
  if (tid == 0) out[b] = rd[0] + rd[1] + rd[2] + rd[3] + pb[0];
}

// ============================================================
extern "C" void kernel_launch(void* const* d_in, const int* in_sizes, int n_in,
                              void* d_out, int out_size, void* d_ws, size_t ws_size,
                              hipStream_t stream)
{
  const float* attn_bias   = (const float*)d_in[0];
  const int*   spatial_pos = (const int*)d_in[1];
  const int*   x           = (const int*)d_in[2];
  const int*   in_degree   = (const int*)d_in[3];
  const int*   out_degree  = (const int*)d_in[4];
  const int*   edge_input  = (const int*)d_in[5];
  const float* atom_emb    = (const float*)d_in[6];
  const float* edge_emb    = (const float*)d_in[7];
  const float* edge_dis    = (const float*)d_in[8];
  const float* spatial_emb = (const float*)d_in[9];
  const float* in_deg_emb  = (const float*)d_in[10];
  const float* out_deg_emb = (const float*)d_in[11];
  const float* graph_token = (const float*)d_in[12];
  const float* gt_vd       = (const float*)d_in[13];
  const float* ln1_g = (const float*)d_in[14];
  const float* ln1_b = (const float*)d_in[15];
  const float* wq = (const float*)d_in[16];
  const float* bq = (const float*)d_in[17];
  const float* wk = (const float*)d_in[18];
  const float* bk = (const float*)d_in[19];
  const float* wv = (const float*)d_in[20];
  const float* bv = (const float*)d_in[21];
  const float* wo = (const float*)d_in[22];
  const float* bo = (const float*)d_in[23];
  const float* ln2_g = (const float*)d_in[24];
  const float* ln2_b = (const float*)d_in[25];
  const float* w1 = (const float*)d_in[26];
  const float* b1 = (const float*)d_in[27];
  const float* w2 = (const float*)d_in[28];
  const float* b2 = (const float*)d_in[29];
  const float* final_g = (const float*)d_in[30];
  const float* final_b = (const float*)d_in[31];
  const float* proj_w  = (const float*)d_in[32];
  const float* proj_b  = (const float*)d_in[33];

  float* out = (float*)d_out;

  const float scale = 0.20412414523193154f;  // 24^-0.5
  const long GAB_N = (long)B_*H_*S_*S_;      // 8,520,192
  const size_t PART_B = (size_t)4 * M_ * 768 * 4;   // 25.4 MB

  char* dws = (char*)d_ws;
  char* p = dws;
  float* gab  = (float*)p;  p += GAB_N*4;
  float* h    = (float*)p;  p += (long)M_*HID_*4;
  bf16*  y    = (bf16*)p;   p += (long)M_*HID_*2;
  bf16*  qkv  = (bf16*)p;   // ffn aliases qkv+ob
  bf16*  ffn  = qkv;
  p += (long)M_*2304*2;
  bf16*  ob   = (bf16*)p;   p += (long)M_*HID_*2;
  float* Ftab = (float*)p;  p += (long)5*1537*32*4;
  float* bqkv = (float*)p;  p += (long)L_*2304*4;

  // optional split-K partial buffer
  float* part = (float*)p;
  bool psplit = ws_size >= (size_t)(p - dws) + PART_B + WL_E_*2;
  if (psplit) p += PART_B;
  // optional bf16 gab
  bf16* gabh = (bf16*)p;
  bool g16 = ws_size >= (size_t)(p - dws) + (size_t)GAB_N*2 + WL_E_*2;
  if (g16) p += GAB_N*2;
  // weight buffer
  bf16* wbuf = (bf16*)p;
  bool full = ws_size >= (size_t)(p - dws) + (size_t)L_ * WL_E_ * 2;

  // ---- setup ----
  gab_base_kernel<<<(int)((GAB_N + 255)/256), 256, 0, stream>>>(
      attn_bias, spatial_pos, spatial_emb, gt_vd, gab);
  ftab_kernel<<<(5*1537 + 7)/8, 256, 0, stream>>>(edge_emb, edge_dis, Ftab);
  edge_kernel<<<B_*N_, 256, 0, stream>>>(edge_input, Ftab, spatial_pos, gab);
  if (g16) {
    long n4 = GAB_N/4;
    gabconv_kernel<<<(int)((n4 + 255)/256), 256, 0, stream>>>(gab, gabh, n4);
  }
  nodefeat_kernel<<<(M_*HID_ + 255)/256, 256, 0, stream>>>(
      x, in_degree, out_degree, atom_emb, in_deg_emb, out_deg_emb, graph_token, h);
  biasqkv_kernel<<<(L_*2304 + 255)/256, 256, 0, stream>>>(bq, bk, bv, bqkv, scale);

  // weight conversion
  if (full) {
    qkvconv_all_kernel<<<dim3(24,24,3*L_), 256, 0, stream>>>(wq, wk, wv, wbuf, scale);
    wconv_all_kernel<<<dim3(24,24,L_), 256, 0, stream>>>(
        wo, wbuf + WQKV_E, 768, 768, (long)768*768, (long)WL_E_);
    wconv_all_kernel<<<dim3(96,24,L_), 256, 0, stream>>>(
        w1, wbuf + WQKV_E + WO_E, 768, 3072, (long)768*3072, (long)WL_E_);
    wconv_all_kernel<<<dim3(24,96,L_), 256, 0, stream>>>(
        w2, wbuf + WQKV_E + WO_E + W1_E, 3072, 768, (long)3072*768, (long)WL_E_);
  }

  const int MT = (M_ + 63)/64;               // 33
  dim3 gQKV(2304/64, MT);                    // 36 x 33
  dim3 gO  (768/64,  MT);                    // 12 x 33
  dim3 gF1 (3072/64, MT);                    // 48 x 33
  dim3 gF2 (768/64,  MT, 4);                 // 12 x 33 x 4 (split-K)
  dim3 cQKV(768/32, 768/32, 3);
  dim3 cO  (768/32, 768/32);
  dim3 cW1 (3072/32, 768/32);
  dim3 cW2 (768/32, 3072/32);

  auto wptr = [&](int l) { return wbuf + (full ? (size_t)l : 0) * WL_E_; };
  auto conv = [&](int l) {
    bf16* W = wptr(l);
    qkvconv_kernel<<<cQKV, 256, 0, stream>>>(
        wq + (size_t)l*HID_*HID_, wk + (size_t)l*HID_*HID_, wv + (size_t)l*HID_*HID_,
        W, scale);
    wconv_kernel<<<cO, 256, 0, stream>>>(wo + (size_t)l*HID_*HID_, W + WQKV_E, 768, 768, 1.0f);
    wconv_kernel<<<cW1, 256, 0, stream>>>(w1 + (size_t)l*HID_*FFN_, W + WQKV_E + WO_E, 768, 3072, 1.0f);
    wconv_kernel<<<cW2, 256, 0, stream>>>(w2 + (size_t)l*FFN_*HID_, W + WQKV_E + WO_E + W1_E, 3072, 768, 1.0f);
  };

  for (int l = 0; l < L_; ++l) {
    if (!full) conv(l);
    bf16* W = wptr(l);
    bf16* Wqkvt = W;
    bf16* Wot   = W + WQKV_E;
    bf16* W1t   = W + WQKV_E + WO_E;
    bf16* W2t   = W + WQKV_E + WO_E + W1_E;

    ln_kernel<<<M_, 256, 0, stream>>>(h, ln1_g + l*HID_, ln1_b + l*HID_, y);
    gemm64_kernel<<<gQKV, 256, 0, stream>>>(
        y, Wqkvt, bqkv + l*2304, nullptr, qkv, M_, 2304, 768, 768, 768, 0);
    if (g16)
      attn_kernel<bf16><<<dim3(B_*H_, 3), 256, 0, stream>>>(qkv, gabh, ob);
    else
      attn_kernel<float><<<dim3(B_*H_, 3), 256, 0, stream>>>(qkv, gab, ob);
    gemm64_kernel<<<gO, 256, 0, stream>>>(
        ob, Wot, bo + l*HID_, h, h, M_, 768, 768, 768, 768, 2);
    ln_kernel<<<M_, 256, 0, stream>>>(h, ln2_g + l*HID_, ln2_b + l*HID_, y);
    gemm64_kernel<<<gF1, 256, 0, stream>>>(
        y, W1t, b1 + l*FFN_, nullptr, ffn, M_, 3072, 768, 768, 768, 1);
    if (psplit) {
      gemm64_kernel<<<gF2, 256, 0, stream>>>(
          ffn, W2t, nullptr, nullptr, part, M_, 768, 768, 3072, 3072, 3);
      combine_kernel<<<(int)(((long)M_*768/4 + 255)/256), 256, 0, stream>>>(
          part, b2 + l*HID_, h);
    } else {
      gemm64_kernel<<<gO, 256, 0, stream>>>(
          ffn, W2t, b2 + l*HID_, h, h, M_, 768, 3072, 3072, 3072, 2);
    }
  }

  final_kernel<<<B_, 256, 0, stream>>>(h, final_g, final_b, proj_w, proj_b, out);
}

// Round 7
// 2036.196 us; speedup vs baseline: 8.8035x; 1.0169x over previous
//
#include <hip/hip_runtime.h>
#include <hip/hip_bf16.h>
#include <math.h>

#define B_ 16
#define N_ 128
#define S_ 129
#define HID_ 768
#define H_ 32
#define D_ 24
#define FFN_ 3072
#define L_ 12
#define M_ (B_*S_)   // 2064
#define SP_ 144      // padded S for q/k rows (9 x 16)
#define KP_ 160      // padded kj for P rows / vt cols (5 x 32)

#define WQKV_E ((size_t)2304*768)
#define WO_E   ((size_t)768*768)
#define W1_E   ((size_t)3072*768)
#define W2_E   ((size_t)768*3072)
#define WL_E_  (WQKV_E + WO_E + W1_E + W2_E)   // 7,077,888

typedef __attribute__((ext_vector_type(8))) short short8;
typedef __attribute__((ext_vector_type(4))) float f32x4;
typedef __hip_bfloat16 bf16;

#define VMCNT(n) asm volatile("s_waitcnt vmcnt(" #n ")" ::: "memory")
#define LDS_FENCE() asm volatile("" ::: "memory")

__device__ __forceinline__ void gload_lds16(const void* g, void* l) {
  __builtin_amdgcn_global_load_lds(
      (const __attribute__((address_space(1))) void*)g,
      (__attribute__((address_space(3))) void*)l, 16, 0, 0);
}

__device__ __forceinline__ float gld(const float* p) { return *p; }
__device__ __forceinline__ float gld(const bf16* p)  { return __bfloat162float(*p); }

// ============================================================
// gab base
// ============================================================
__global__ __launch_bounds__(256) void gab_base_kernel(
    const float* __restrict__ ab, const int* __restrict__ spos,
    const float* __restrict__ spemb, const float* __restrict__ gtvd,
    float* __restrict__ gab)
{
  int idx = blockIdx.x * 256 + threadIdx.x;
  if (idx >= B_*H_*S_*S_) return;
  int kj = idx % S_;
  int qi = (idx / S_) % S_;
  int hh = (idx / (S_*S_)) % H_;
  int b  = idx / (S_*S_*H_);
  float v = 2.0f * ab[(b*S_ + qi)*S_ + kj];
  if (qi > 0 && kj > 0)
    v += spemb[spos[(b*N_ + (qi-1))*N_ + (kj-1)]*H_ + hh];
  if (qi == 0 || kj == 0) v += gtvd[hh];
  gab[idx] = v;
}

// ============================================================
// F table -> bf16: F[d][idx][hh] = bf16((1/3) * sum_hp eemb[idx][hp]*edis[d][hp][hh])
// ============================================================
__global__ __launch_bounds__(256) void ftab_kernel(
    const float* __restrict__ eemb, const float* __restrict__ edis,
    bf16* __restrict__ F)
{
  __shared__ float em[8][32];
  int tid = threadIdx.x;
  int jl = tid >> 5, hh = tid & 31;
  int p = blockIdx.x * 8 + jl;
  bool valid = p < 5*1537;
  int d = valid ? p / 1537 : 0;
  int idx = valid ? p % 1537 : 0;
  em[jl][hh] = eemb[idx*32 + hh];
  float acc = 0.f;
#pragma unroll
  for (int hp = 0; hp < 32; ++hp)
    acc += em[jl][hp] * edis[d*1024 + hp*32 + hh];
  if (valid) F[(long)p*32 + hh] = __float2bfloat16(acc * (1.0f/3.0f));
}

// ============================================================
// edge encoding (bf16 F gathers)
// ============================================================
__global__ __launch_bounds__(256) void edge_kernel(
    const int* __restrict__ eidx, const bf16* __restrict__ F,
    const int* __restrict__ spos, float* __restrict__ gab)
{
  __shared__ float outj[128][33];
  int tid = threadIdx.x;
  int jl = tid >> 5, hh = tid & 31;
  int bi = blockIdx.x;
  int b = bi >> 7, i = bi & 127;
  for (int ch = 0; ch < 16; ++ch) {
    int j = ch*8 + jl;
    const int* er = eidx + ((long)((b*N_ + i)*N_ + j)) * 15;
    float acc = 0.f;
#pragma unroll
    for (int t = 0; t < 15; ++t) {
      int d = t / 3;
      acc += __bfloat162float(F[((long)(d*1537 + er[t]))*32 + hh]);
    }
    int sp0 = spos[(b*N_ + i)*N_ + j];
    int sp = (sp0 == 0) ? 1 : sp0;
    if (sp > 1) sp -= 1;
    if (sp > 5) sp = 5;
    outj[j][hh] = acc / (float)sp;
  }
  __syncthreads();
  for (int it = 0; it < 16; ++it) {
    int r = it*2 + (tid >> 7);
    int c = tid & 127;
    long g = ((long)(b*H_ + r)*S_ + (i+1))*S_ + 1 + c;
    gab[g] += outj[c][r];
  }
}

// ============================================================
// gab fp32 -> bf16
// ============================================================
__global__ __launch_bounds__(256) void gabconv_kernel(
    const float* __restrict__ gab, bf16* __restrict__ gabh, long n4)
{
  long i = ((long)blockIdx.x * 256 + threadIdx.x);
  if (i >= n4) return;
  float4 v = *(const float4*)(gab + i*4);
  bf16* o = gabh + i*4;
  o[0] = __float2bfloat16(v.x);
  o[1] = __float2bfloat16(v.y);
  o[2] = __float2bfloat16(v.z);
  o[3] = __float2bfloat16(v.w);
}

// ============================================================
// node features
// ============================================================
__global__ __launch_bounds__(256) void nodefeat_kernel(
    const int* __restrict__ x, const int* __restrict__ indeg,
    const int* __restrict__ outdeg, const float* __restrict__ atom_emb,
    const float* __restrict__ in_emb, const float* __restrict__ out_emb,
    const float* __restrict__ gtok, float* __restrict__ h)
{
  int idx = blockIdx.x * 256 + threadIdx.x;
  if (idx >= M_*HID_) return;
  int c = idx % HID_;
  int s = (idx / HID_) % S_;
  int b = idx / (HID_*S_);
  float v;
  if (s == 0) {
    v = gtok[c];
  } else {
    int n = s - 1;
    v = in_emb[indeg[b*N_ + n]*HID_ + c] + out_emb[outdeg[b*N_ + n]*HID_ + c];
    const int* xr = x + (b*N_ + n)*9;
#pragma unroll
    for (int e = 0; e < 9; ++e) v += atom_emb[(long)xr[e]*HID_ + c];
  }
  h[idx] = v;
}

// ============================================================
// LayerNorm fp32 -> bf16 (standalone)
// ============================================================
__global__ __launch_bounds__(256) void ln_kernel(
    const float* __restrict__ in, const float* __restrict__ g,
    const float* __restrict__ bta, bf16* __restrict__ out)
{
  int row = blockIdx.x;
  int tid = threadIdx.x;
  const float* xr = in + (long)row * HID_;
  float x0 = xr[tid], x1 = xr[tid + 256], x2 = xr[tid + 512];
  float s = x0 + x1 + x2;
  float ss = x0*x0 + x1*x1 + x2*x2;
  for (int off = 32; off > 0; off >>= 1) {
    s  += __shfl_xor(s, off);
    ss += __shfl_xor(ss, off);
  }
  __shared__ float rs[4], rss[4];
  int w = tid / 64;
  if ((tid & 63) == 0) { rs[w] = s; rss[w] = ss; }
  __syncthreads();
  s  = rs[0] + rs[1] + rs[2] + rs[3];
  ss = rss[0] + rss[1] + rss[2] + rss[3];
  float mean = s * (1.0f/768.0f);
  float var  = ss * (1.0f/768.0f) - mean*mean;
  float rstd = rsqrtf(var + 1e-5f);
  bf16* orow = out + (long)row * HID_;
  orow[tid]       = __float2bfloat16((x0 - mean)*rstd*g[tid]       + bta[tid]);
  orow[tid + 256] = __float2bfloat16((x1 - mean)*rstd*g[tid + 256] + bta[tid + 256]);
  orow[tid + 512] = __float2bfloat16((x2 - mean)*rstd*g[tid + 512] + bta[tid + 512]);
}

// ============================================================
// fused: h += bias + sum_z part[z]; y = bf16(LN(h))
// ============================================================
template<int NZ>
__global__ __launch_bounds__(256) void addln_kernel(
    const float* __restrict__ part, const float* __restrict__ bias,
    const float* __restrict__ g, const float* __restrict__ bta,
    float* __restrict__ h, bf16* __restrict__ y)
{
  int row = blockIdx.x;
  int tid = threadIdx.x;
  const long MN = (long)M_*HID_;
  float* hr = h + (long)row*HID_;
  float v[3];
#pragma unroll
  for (int j = 0; j < 3; ++j) {
    int c = tid + j*256;
    float a = hr[c] + bias[c];
    const float* pp = part + (long)row*HID_ + c;
#pragma unroll
    for (int z = 0; z < NZ; ++z) a += pp[(long)z*MN];
    v[j] = a;
    hr[c] = a;
  }
  float s = v[0] + v[1] + v[2];
  float ss = v[0]*v[0] + v[1]*v[1] + v[2]*v[2];
  for (int off = 32; off > 0; off >>= 1) {
    s  += __shfl_xor(s, off);
    ss += __shfl_xor(ss, off);
  }
  __shared__ float rs[4], rss[4];
  int w = tid / 64;
  if ((tid & 63) == 0) { rs[w] = s; rss[w] = ss; }
  __syncthreads();
  s  = rs[0] + rs[1] + rs[2] + rs[3];
  ss = rss[0] + rss[1] + rss[2] + rss[3];
  float mean = s * (1.0f/768.0f);
  float var  = ss * (1.0f/768.0f) - mean*mean;
  float rstd = rsqrtf(var + 1e-5f);
  bf16* yr = y + (long)row*HID_;
#pragma unroll
  for (int j = 0; j < 3; ++j) {
    int c = tid + j*256;
    yr[c] = __float2bfloat16((v[j] - mean)*rstd*g[c] + bta[c]);
  }
}

// ============================================================
// weight converts
// ============================================================
__global__ __launch_bounds__(256) void wconv_kernel(
    const float* __restrict__ W, bf16* __restrict__ Out,
    int K, int N, float scale)
{
  __shared__ float tile[32][33];
  int bx = blockIdx.x * 32;
  int by = blockIdx.y * 32;
  int tx = threadIdx.x & 31, ty = threadIdx.x >> 5;
#pragma unroll
  for (int r = 0; r < 32; r += 8)
    tile[ty + r][tx] = W[(long)(by + ty + r)*N + bx + tx];
  __syncthreads();
#pragma unroll
  for (int r = 0; r < 32; r += 8)
    Out[(long)(bx + ty + r)*K + by + tx] = __float2bfloat16(tile[tx][ty + r] * scale);
}

__global__ __launch_bounds__(256) void qkvconv_kernel(
    const float* __restrict__ wq, const float* __restrict__ wk,
    const float* __restrict__ wv, bf16* __restrict__ Out, float scale)
{
  const float* W = blockIdx.z == 0 ? wq : blockIdx.z == 1 ? wk : wv;
  float sc = blockIdx.z == 0 ? scale : 1.0f;
  __shared__ float tile[32][33];
  int bx = blockIdx.x * 32;
  int by = blockIdx.y * 32;
  int tx = threadIdx.x & 31, ty = threadIdx.x >> 5;
#pragma unroll
  for (int r = 0; r < 32; r += 8)
    tile[ty + r][tx] = W[(long)(by + ty + r)*768 + bx + tx];
  __syncthreads();
  bf16* O = Out + (long)blockIdx.z * 768 * 768;
#pragma unroll
  for (int r = 0; r < 32; r += 8)
    O[(long)(bx + ty + r)*768 + by + tx] = __float2bfloat16(tile[tx][ty + r] * sc);
}

__global__ __launch_bounds__(256) void qkvconv_all_kernel(
    const float* __restrict__ wq, const float* __restrict__ wk,
    const float* __restrict__ wv, bf16* __restrict__ wbuf, float scale)
{
  int z = blockIdx.z;
  int l = z / 3, which = z % 3;
  const float* W = (which == 0 ? wq : which == 1 ? wk : wv) + (size_t)l*768*768;
  float sc = which == 0 ? scale : 1.0f;
  __shared__ float tile[32][33];
  int bx = blockIdx.x * 32;
  int by = blockIdx.y * 32;
  int tx = threadIdx.x & 31, ty = threadIdx.x >> 5;
#pragma unroll
  for (int r = 0; r < 32; r += 8)
    tile[ty + r][tx] = W[(long)(by + ty + r)*768 + bx + tx];
  __syncthreads();
  bf16* O = wbuf + (size_t)l*WL_E_ + (size_t)which*768*768;
#pragma unroll
  for (int r = 0; r < 32; r += 8)
    O[(long)(bx + ty + r)*768 + by + tx] = __float2bfloat16(tile[tx][ty + r] * sc);
}

__global__ __launch_bounds__(256) void wconv_all_kernel(
    const float* __restrict__ Wb, bf16* __restrict__ Ob,
    int K, int N, long inStride, long outStride)
{
  int z = blockIdx.z;
  const float* W = Wb + (size_t)z * inStride;
  bf16* Out = Ob + (size_t)z * outStride;
  __shared__ float tile[32][33];
  int bx = blockIdx.x * 32;
  int by = blockIdx.y * 32;
  int tx = threadIdx.x & 31, ty = threadIdx.x >> 5;
#pragma unroll
  for (int r = 0; r < 32; r += 8)
    tile[ty + r][tx] = W[(long)(by + ty + r)*N + bx + tx];
  __syncthreads();
#pragma unroll
  for (int r = 0; r < 32; r += 8)
    Out[(long)(bx + ty + r)*K + by + tx] = __float2bfloat16(tile[tx][ty + r]);
}

__global__ __launch_bounds__(256) void biasqkv_kernel(
    const float* __restrict__ bq, const float* __restrict__ bk,
    const float* __restrict__ bv, float* __restrict__ bqkv, float scale)
{
  int idx = blockIdx.x * 256 + threadIdx.x;
  if (idx >= L_*2304) return;
  int l = idx / 2304, n = idx % 2304;
  int p = n / 768, nn = n % 768;
  float v = (p == 0) ? bq[l*768 + nn]*scale : (p == 1) ? bk[l*768 + nn] : bv[l*768 + nn];
  bqkv[idx] = v;
}

// ============================================================
// bf16 MFMA GEMM: BM=64, BN=64, BK=64, 4 waves (2x2, 32x32 each).
// Ring-3 + counted vmcnt (G=4 loads/thread/stage -> vmcnt 8/4/0).
// 3-bit XOR swizzle: chunk ^= (row&7)  (8x 16B chunks per 128B row -> 2-way reads)
// XCD-bijective block swizzle (m204).
// blockIdx.z = K-split chunk; lda/ldb = row strides.
// mode 0: bf16 out; 1: gelu->bf16; 2: +resid->fp32; 3: fp32 partial (no bias)
// ============================================================
__device__ __forceinline__ void stage64k(
    const bf16* __restrict__ A, const bf16* __restrict__ Wt,
    bf16* Als, bf16* Bls, int bm, int bn, long ka, int M, int lda, int ldb, int tid)
{
  int r0 = tid >> 3, c = tid & 7;
#pragma unroll
  for (int p = 0; p < 2; ++p) {
    int row = p*32 + r0;
    int cs = c ^ (row & 7);
    int grow = bm + row; if (grow >= M) grow = M - 1;
    gload_lds16(A + (long)grow*lda + ka + cs*8, Als + (p*256 + (tid & ~63))*8);
    gload_lds16(Wt + (long)(bn + row)*ldb + ka + cs*8, Bls + (p*256 + (tid & ~63))*8);
  }
}

__global__ __launch_bounds__(256) void gemm64_kernel(
    const bf16* __restrict__ A, const bf16* __restrict__ Wt,
    const float* __restrict__ bias, const float* __restrict__ resid,
    void* __restrict__ Cout, int M, int N, int Klen, int lda, int ldb, int mode)
{
  constexpr int ASZ = 64*64;    // elems per stage per matrix
  __shared__ bf16 Als[3*ASZ];
  __shared__ bf16 Bls[3*ASZ];
  int tid = threadIdx.x;
  int wid = tid >> 6, lane = tid & 63;

  // XCD-bijective swizzle of the xy-plane
  int gx = gridDim.x;
  int nwg = gx * gridDim.y;
  int id = blockIdx.y * gx + blockIdx.x;
  int q = nwg >> 3, r = nwg & 7;
  int xcd = id & 7, off = id >> 3;
  int swz = (xcd < r) ? (xcd*(q+1) + off) : (r*(q+1) + (xcd - r)*q + off);
  int bm = (swz / gx) * 64, bn = (swz % gx) * 64;

  long koff = (long)blockIdx.z * Klen;
  int wr = wid >> 1, wc = wid & 1;
  int lr = lane & 15, kg = lane >> 4;

  int aoff[2][2], boff[2][2];
#pragma unroll
  for (int m = 0; m < 2; ++m) {
    int row = wr*32 + m*16 + lr;
#pragma unroll
    for (int hf = 0; hf < 2; ++hf) {
      int chunk = hf*4 + kg;
      aoff[m][hf] = (row*8 + (chunk ^ (row & 7)))*8;
    }
  }
#pragma unroll
  for (int n = 0; n < 2; ++n) {
    int col = wc*32 + n*16 + lr;
#pragma unroll
    for (int hf = 0; hf < 2; ++hf) {
      int chunk = hf*4 + kg;
      boff[n][hf] = (col*8 + (chunk ^ (col & 7)))*8;
    }
  }

  f32x4 acc[2][2];
#pragma unroll
  for (int m = 0; m < 2; ++m)
#pragma unroll
    for (int n = 0; n < 2; ++n)
      acc[m][n] = (f32x4){0.0f, 0.0f, 0.0f, 0.0f};

  int nt = Klen >> 6;   // >= 6 for all call sites
  stage64k(A, Wt, Als,         Bls,         bm, bn, koff,       M, lda, ldb, tid);
  stage64k(A, Wt, Als + ASZ,   Bls + ASZ,   bm, bn, koff + 64,  M, lda, ldb, tid);
  stage64k(A, Wt, Als + 2*ASZ, Bls + 2*ASZ, bm, bn, koff + 128, M, lda, ldb, tid);

  int cur = 0;
  for (int t = 0; t < nt; ++t) {
    int ahead = nt - 1 - t; if (ahead > 2) ahead = 2;
    if (ahead == 2)      VMCNT(8);
    else if (ahead == 1) VMCNT(4);
    else                 VMCNT(0);
    __builtin_amdgcn_s_barrier();
    LDS_FENCE();
    bf16* Acur = Als + cur*ASZ;
    bf16* Bcur = Bls + cur*ASZ;
    short8 av[2][2], bv2[2][2];
#pragma unroll
    for (int m = 0; m < 2; ++m)
#pragma unroll
      for (int hf = 0; hf < 2; ++hf) av[m][hf] = *(const short8*)(Acur + aoff[m][hf]);
#pragma unroll
    for (int n = 0; n < 2; ++n)
#pragma unroll
      for (int hf = 0; hf < 2; ++hf) bv2[n][hf] = *(const short8*)(Bcur + boff[n][hf]);
#pragma unroll
    for (int hf = 0; hf < 2; ++hf)
#pragma unroll
      for (int m = 0; m < 2; ++m)
#pragma unroll
        for (int n = 0; n < 2; ++n)
          acc[m][n] = __builtin_amdgcn_mfma_f32_16x16x32_bf16(av[m][hf], bv2[n][hf], acc[m][n], 0, 0, 0);
    LDS_FENCE();
    __builtin_amdgcn_s_barrier();
    if (t + 3 < nt)
      stage64k(A, Wt, Als + cur*ASZ, Bls + cur*ASZ,
               bm, bn, koff + (long)(t+3)*64, M, lda, ldb, tid);
    cur = (cur == 2) ? 0 : cur + 1;
  }

#pragma unroll
  for (int n = 0; n < 2; ++n) {
    int col = bn + wc*32 + n*16 + lr;
    float bcol = (mode == 3) ? 0.0f : bias[col];
#pragma unroll
    for (int m = 0; m < 2; ++m) {
      f32x4 a = acc[m][n];
#pragma unroll
      for (int i = 0; i < 4; ++i) {
        int row = bm + wr*32 + m*16 + kg*4 + i;
        if (row < M) {
          float v = a[i] + bcol;
          if (mode == 1) v = 0.5f * v * (1.0f + erff(v * 0.70710678118654752f));
          if (mode == 2)
            ((float*)Cout)[(long)row*N + col] = v + resid[(long)row*N + col];
          else if (mode == 3)
            ((float*)Cout + (size_t)blockIdx.z*M*N)[(long)row*N + col] = v;
          else
            ((bf16*)Cout)[(long)row*N + col] = __float2bfloat16(v);
        }
      }
    }
  }
}

// ============================================================
// MFMA fused attention per (b, head, q-group): grid (B*H, 3)
// ============================================================
template<typename GT>
__global__ __launch_bounds__(256) void attn_kernel(
    const bf16* __restrict__ qkv, const GT* __restrict__ gab,
    bf16* __restrict__ ob)
{
  int bh = blockIdx.x;
  int zz = blockIdx.y;
  int b = bh >> 5, hh = bh & 31;
  __shared__ bf16 ql[SP_*32];
  __shared__ bf16 kl[SP_*32];
  __shared__ bf16 vt[32*KP_];
  __shared__ bf16 pl[4][16*KP_];
  int tid = threadIdx.x;
  int wv = tid >> 6, lane = tid & 63;
  const short8 z8 = (short8){0,0,0,0,0,0,0,0};

  for (int idx = tid; idx < 32*KP_/8; idx += 256)
    *(short8*)&vt[idx*8] = z8;
  const bf16* qbase = qkv + (long)b*S_*2304 + hh*24;
  for (int u = tid; u < SP_*4; u += 256) {
    int row = u >> 2, c8 = u & 3;
    short8 qv = z8, kv = z8;
    if (row < S_ && c8 < 3) {
      qv = *(const short8*)(qbase + (long)row*2304 + c8*8);
      kv = *(const short8*)(qbase + (long)row*2304 + 768 + c8*8);
    }
    int cs = c8 ^ ((row >> 1) & 3);
    *(short8*)&ql[row*32 + cs*8] = qv;
    *(short8*)&kl[row*32 + cs*8] = kv;
  }
  __syncthreads();
  for (int u = tid; u < S_*24; u += 256) {
    int kj = u / 24, c = u % 24;
    bf16 val = qbase[(long)kj*2304 + 1536 + c];
    int ch = (kj >> 3) ^ ((c >> 1) & 3);
    vt[c*KP_ + ch*8 + (kj & 7)] = val;
  }
  __syncthreads();

  int l15 = lane & 15, l4 = lane >> 4;
  int mf = zz*4 + wv;
  if (mf >= 9) return;

  short8 bvf[5][2];
#pragma unroll
  for (int kc = 0; kc < 5; ++kc)
#pragma unroll
    for (int ntc = 0; ntc < 2; ++ntc) {
      int col = ntc*16 + l15;
      int ch = (kc*4 + l4) ^ ((col >> 1) & 3);
      bvf[kc][ntc] = *(const short8*)&vt[col*KP_ + ch*8];
    }

  bf16* plw = pl[wv];
  for (int idx = lane; idx < 16*KP_/8; idx += 64)
    *(short8*)&plw[idx*8] = z8;

  const GT* gb = gab + (long)(b*H_ + hh)*S_*S_;

  {
    int qb0 = mf * 16;
    int qrow = qb0 + l15;
    int qch = l4 ^ ((qrow >> 1) & 3);
    short8 aq = *(const short8*)&ql[qrow*32 + qch*8];
    f32x4 sc[9];
#pragma unroll
    for (int nt = 0; nt < 9; ++nt) {
      int krow = nt*16 + l15;
      int kch = l4 ^ ((krow >> 1) & 3);
      short8 bk = *(const short8*)&kl[krow*32 + kch*8];
      sc[nt] = __builtin_amdgcn_mfma_f32_16x16x32_bf16(aq, bk, (f32x4){0,0,0,0}, 0, 0, 0);
    }
    float mx[4] = {-1e30f,-1e30f,-1e30f,-1e30f};
#pragma unroll
    for (int nt = 0; nt < 9; ++nt) {
      int kj = nt*16 + l15;
      int kjc = kj < S_ ? kj : 0;
#pragma unroll
      for (int i = 0; i < 4; ++i) {
        int q = qb0 + l4*4 + i;
        int qc = q < S_ ? q : 0;
        float v = sc[nt][i] + gld(&gb[(long)qc*S_ + kjc]);
        if (kj >= S_) v = -1e30f;
        sc[nt][i] = v;
        mx[i] = fmaxf(mx[i], v);
      }
    }
#pragma unroll
    for (int i = 0; i < 4; ++i) {
      mx[i] = fmaxf(mx[i], __shfl_xor(mx[i], 1));
      mx[i] = fmaxf(mx[i], __shfl_xor(mx[i], 2));
      mx[i] = fmaxf(mx[i], __shfl_xor(mx[i], 4));
      mx[i] = fmaxf(mx[i], __shfl_xor(mx[i], 8));
    }
    float sum[4] = {0.f,0.f,0.f,0.f};
#pragma unroll
    for (int nt = 0; nt < 9; ++nt)
#pragma unroll
      for (int i = 0; i < 4; ++i) {
        float e = __expf(sc[nt][i] - mx[i]);
        sc[nt][i] = e;
        sum[i] += e;
      }
#pragma unroll
    for (int i = 0; i < 4; ++i) {
      sum[i] += __shfl_xor(sum[i], 1);
      sum[i] += __shfl_xor(sum[i], 2);
      sum[i] += __shfl_xor(sum[i], 4);
      sum[i] += __shfl_xor(sum[i], 8);
    }
#pragma unroll
    for (int nt = 0; nt < 9; ++nt) {
      int kj = nt*16 + l15;
#pragma unroll
      for (int i = 0; i < 4; ++i) {
        int q = l4*4 + i;
        int ch = (kj >> 3) ^ ((q >> 1) & 3);
        plw[q*KP_ + ch*8 + (kj & 7)] = __float2bfloat16(sc[nt][i]);
      }
    }
    f32x4 av[2] = {(f32x4){0,0,0,0}, (f32x4){0,0,0,0}};
#pragma unroll
    for (int kc = 0; kc < 5; ++kc) {
      int ch = (kc*4 + l4) ^ ((l15 >> 1) & 3);
      short8 ap = *(const short8*)&plw[l15*KP_ + ch*8];
#pragma unroll
      for (int ntc = 0; ntc < 2; ++ntc)
        av[ntc] = __builtin_amdgcn_mfma_f32_16x16x32_bf16(ap, bvf[kc][ntc], av[ntc], 0, 0, 0);
    }
#pragma unroll
    for (int ntc = 0; ntc < 2; ++ntc) {
      int c = ntc*16 + l15;
      if (c < 24) {
#pragma unroll
        for (int i = 0; i < 4; ++i) {
          int q = qb0 + l4*4 + i;
          if (q < S_)
            ob[(long)(b*S_ + q)*768 + hh*24 + c] = __float2bfloat16(av[ntc][i] / sum[i]);
        }
      }
    }
  }
}

// ============================================================
// final
// ============================================================
__global__ __launch_bounds__(256) void final_kernel(
    const float* __restrict__ h, const float* __restrict__ fg,
    const float* __restrict__ fb, const float* __restrict__ pw,
    const float* __restrict__ pb, float* __restrict__ out)
{
  int b = blockIdx.x;
  int tid = threadIdx.x;
  const float* xr = h + (long)b * S_ * HID_;
  float x0 = xr[tid], x1 = xr[tid + 256], x2 = xr[tid + 512];
  float s = x0 + x1 + x2;
  float ss = x0*x0 + x1*x1 + x2*x2;
  for (int off = 32; off > 0; off >>= 1) {
    s  += __shfl_xor(s, off);
    ss += __shfl_xor(ss, off);
  }
  __shared__ float rs[4], rss[4], rd[4];
  int w = tid / 64;
  if ((tid & 63) == 0) { rs[w] = s; rss[w] = ss; }
  __syncthreads();
  s  = rs[0] + rs[1] + rs[2] + rs[3];
  ss = rss[0] + rss[1] + rss[2] + rss[3];
  float mean = s * (1.0f/768.0f);
  float var  = ss * (1.0f/768.0f) - mean*mean;
  float rstd = rsqrtf(var + 1e-5f);
  float d0 = ((x0 - mean)*rstd*fg[tid]       + fb[tid])       * pw[tid];
  float d1 = ((x1 - mean)*rstd*fg[tid + 256] + fb[tid + 256]) * pw[tid + 256];
  float d2 = ((x2 - mean)*rstd*fg[tid + 512] + fb[tid + 512]) * pw[tid + 512];
  float pd = d0 + d1 + d2;
  for (int off = 32; off > 0; off >>= 1) pd += __shfl_xor(pd, off);
  if ((tid & 63) == 0) rd[w] = pd;
  __syncthreads();
  if (tid == 0) out[b] = rd[0] + rd[1] + rd[2] + rd[3] + pb[0];
}

// ============================================================
extern "C" void kernel_launch(void* const* d_in, const int* in_sizes, int n_in,
                              void* d_out, int out_size, void* d_ws, size_t ws_size,
                              hipStream_t stream)
{
  const float* attn_bias   = (const float*)d_in[0];
  const int*   spatial_pos = (const int*)d_in[1];
  const int*   x           = (const int*)d_in[2];
  const int*   in_degree   = (const int*)d_in[3];
  const int*   out_degree  = (const int*)d_in[4];
  const int*   edge_input  = (const int*)d_in[5];
  const float* atom_emb    = (const float*)d_in[6];
  const float* edge_emb    = (const float*)d_in[7];
  const float* edge_dis    = (const float*)d_in[8];
  const float* spatial_emb = (const float*)d_in[9];
  const float* in_deg_emb  = (const float*)d_in[10];
  const float* out_deg_emb = (const float*)d_in[11];
  const float* graph_token = (const float*)d_in[12];
  const float* gt_vd       = (const float*)d_in[13];
  const float* ln1_g = (const float*)d_in[14];
  const float* ln1_b = (const float*)d_in[15];
  const float* wq = (const float*)d_in[16];
  const float* bq = (const float*)d_in[17];
  const float* wk = (const float*)d_in[18];
  const float* bk = (const float*)d_in[19];
  const float* wv = (const float*)d_in[20];
  const float* bv = (const float*)d_in[21];
  const float* wo = (const float*)d_in[22];
  const float* bo = (const float*)d_in[23];
  const float* ln2_g = (const float*)d_in[24];
  const float* ln2_b = (const float*)d_in[25];
  const float* w1 = (const float*)d_in[26];
  const float* b1 = (const float*)d_in[27];
  const float* w2 = (const float*)d_in[28];
  const float* b2 = (const float*)d_in[29];
  const float* final_g = (const float*)d_in[30];
  const float* final_b = (const float*)d_in[31];
  const float* proj_w  = (const float*)d_in[32];
  const float* proj_b  = (const float*)d_in[33];

  float* out = (float*)d_out;

  const float scale = 0.20412414523193154f;  // 24^-0.5
  const long GAB_N = (long)B_*H_*S_*S_;      // 8,520,192
  const size_t PART_B = (size_t)4 * M_ * 768 * 4;   // 25.4 MB

  char* dws = (char*)d_ws;
  char* p = dws;
  float* gab  = (float*)p;  p += GAB_N*4;
  float* h    = (float*)p;  p += (long)M_*HID_*4;
  bf16*  y    = (bf16*)p;   p += (long)M_*HID_*2;
  bf16*  qkv  = (bf16*)p;   // ffn aliases qkv+ob
  bf16*  ffn  = qkv;
  p += (long)M_*2304*2;
  bf16*  ob   = (bf16*)p;   p += (long)M_*HID_*2;
  bf16*  Ftab = (bf16*)p;   p += (long)5*1537*32*4;   // over-alloc (fp32 slot)
  float* bqkv = (float*)p;  p += (long)L_*2304*4;

  // optional split-K partial buffer
  float* part = (float*)p;
  bool psplit = ws_size >= (size_t)(p - dws) + PART_B + WL_E_*2;
  if (psplit) p += PART_B;
  // optional bf16 gab
  bf16* gabh = (bf16*)p;
  bool g16 = ws_size >= (size_t)(p - dws) + (size_t)GAB_N*2 + WL_E_*2;
  if (g16) p += GAB_N*2;
  // weight buffer
  bf16* wbuf = (bf16*)p;
  bool full = ws_size >= (size_t)(p - dws) + (size_t)L_ * WL_E_ * 2;

  // ---- setup ----
  gab_base_kernel<<<(int)((GAB_N + 255)/256), 256, 0, stream>>>(
      attn_bias, spatial_pos, spatial_emb, gt_vd, gab);
  ftab_kernel<<<(5*1537 + 7)/8, 256, 0, stream>>>(edge_emb, edge_dis, Ftab);
  edge_kernel<<<B_*N_, 256, 0, stream>>>(edge_input, Ftab, spatial_pos, gab);
  if (g16) {
    long n4 = GAB_N/4;
    gabconv_kernel<<<(int)((n4 + 255)/256), 256, 0, stream>>>(gab, gabh, n4);
  }
  nodefeat_kernel<<<(M_*HID_ + 255)/256, 256, 0, stream>>>(
      x, in_degree, out_degree, atom_emb, in_deg_emb, out_deg_emb, graph_token, h);
  biasqkv_kernel<<<(L_*2304 + 255)/256, 256, 0, stream>>>(bq, bk, bv, bqkv, scale);

  if (full) {
    qkvconv_all_kernel<<<dim3(24,24,3*L_), 256, 0, stream>>>(wq, wk, wv, wbuf, scale);
    wconv_all_kernel<<<dim3(24,24,L_), 256, 0, stream>>>(
        wo, wbuf + WQKV_E, 768, 768, (long)768*768, (long)WL_E_);
    wconv_all_kernel<<<dim3(96,24,L_), 256, 0, stream>>>(
        w1, wbuf + WQKV_E + WO_E, 768, 3072, (long)768*3072, (long)WL_E_);
    wconv_all_kernel<<<dim3(24,96,L_), 256, 0, stream>>>(
        w2, wbuf + WQKV_E + WO_E + W1_E, 3072, 768, (long)3072*768, (long)WL_E_);
  }

  const int MT = (M_ + 63)/64;               // 33
  dim3 gQKV(2304/64, MT);                    // 36 x 33
  dim3 gO  (768/64,  MT);                    // 12 x 33
  dim3 gO2 (768/64,  MT, 2);                 // split-K2 (O-proj)
  dim3 gF1 (3072/64, MT);                    // 48 x 33
  dim3 gF2 (768/64,  MT, 4);                 // split-K4 (FFN2)
  dim3 cQKV(768/32, 768/32, 3);
  dim3 cO  (768/32, 768/32);
  dim3 cW1 (3072/32, 768/32);
  dim3 cW2 (768/32, 3072/32);

  auto wptr = [&](int l) { return wbuf + (full ? (size_t)l : 0) * WL_E_; };
  auto conv = [&](int l) {
    bf16* W = wptr(l);
    qkvconv_kernel<<<cQKV, 256, 0, stream>>>(
        wq + (size_t)l*HID_*HID_, wk + (size_t)l*HID_*HID_, wv + (size_t)l*HID_*HID_,
        W, scale);
    wconv_kernel<<<cO, 256, 0, stream>>>(wo + (size_t)l*HID_*HID_, W + WQKV_E, 768, 768, 1.0f);
    wconv_kernel<<<cW1, 256, 0, stream>>>(w1 + (size_t)l*HID_*FFN_, W + WQKV_E + WO_E, 768, 3072, 1.0f);
    wconv_kernel<<<cW2, 256, 0, stream>>>(w2 + (size_t)l*FFN_*HID_, W + WQKV_E + WO_E + W1_E, 3072, 768, 1.0f);
  };

  if (psplit)   // layer-0 ln1; subsequent ln1 fused into addln
    ln_kernel<<<M_, 256, 0, stream>>>(h, ln1_g, ln1_b, y);

  for (int l = 0; l < L_; ++l) {
    if (!full) conv(l);
    bf16* W = wptr(l);
    bf16* Wqkvt = W;
    bf16* Wot   = W + WQKV_E;
    bf16* W1t   = W + WQKV_E + WO_E;
    bf16* W2t   = W + WQKV_E + WO_E + W1_E;

    if (!psplit)
      ln_kernel<<<M_, 256, 0, stream>>>(h, ln1_g + l*HID_, ln1_b + l*HID_, y);

    gemm64_kernel<<<gQKV, 256, 0, stream>>>(
        y, Wqkvt, bqkv + l*2304, nullptr, qkv, M_, 2304, 768, 768, 768, 0);
    if (g16)
      attn_kernel<bf16><<<dim3(B_*H_, 3), 256, 0, stream>>>(qkv, gabh, ob);
    else
      attn_kernel<float><<<dim3(B_*H_, 3), 256, 0, stream>>>(qkv, gab, ob);

    if (psplit) {
      gemm64_kernel<<<gO2, 256, 0, stream>>>(
          ob, Wot, nullptr, nullptr, part, M_, 768, 384, 768, 768, 3);
      addln_kernel<2><<<M_, 256, 0, stream>>>(
          part, bo + l*HID_, ln2_g + l*HID_, ln2_b + l*HID_, h, y);
    } else {
      gemm64_kernel<<<gO, 256, 0, stream>>>(
          ob, Wot, bo + l*HID_, h, h, M_, 768, 768, 768, 768, 2);
      ln_kernel<<<M_, 256, 0, stream>>>(h, ln2_g + l*HID_, ln2_b + l*HID_, y);
    }

    gemm64_kernel<<<gF1, 256, 0, stream>>>(
        y, W1t, b1 + l*FFN_, nullptr, ffn, M_, 3072, 768, 768, 768, 1);

    if (psplit) {
      gemm64_kernel<<<gF2, 256, 0, stream>>>(
          ffn, W2t, nullptr, nullptr, part, M_, 768, 768, 3072, 3072, 3);
      int ln = (l + 1 < L_) ? l + 1 : 0;   // last layer: y unused afterward
      addln_kernel<4><<<M_, 256, 0, stream>>>(
          part, b2 + l*HID_, ln1_g + ln*HID_, ln1_b + ln*HID_, h, y);
    } else {
      gemm64_kernel<<<gO, 256, 0, stream>>>(
          ffn, W2t, b2 + l*HID_, h, h, M_, 768, 3072, 3072, 3072, 2);
    }
  }

  final_kernel<<<B_, 256, 0, stream>>>(h, final_g, final_b, proj_w, proj_b, out);
}